// Round 12
// baseline (1299.517 us; speedup 1.0000x reference)
//
#include <hip/hip_runtime.h>
#include <cstdint>

// ---------------------------------------------------------------------------
// RWKV7 block (B=4,T=1024,C=2048,H=32,N=64,DFF=8192) for MI355X gfx950.
// R12: gemm2/gemm_up4 -> triple-buffered depth-2 prefetch (vmcnt(6) steady
//      state; loads get 2 K-steps to land). Scan/rest identical to R11.
// ---------------------------------------------------------------------------

typedef __attribute__((ext_vector_type(4))) float f32x4;
typedef __attribute__((ext_vector_type(8))) __bf16 bf16x8;
typedef __attribute__((ext_vector_type(8))) unsigned short us8;

#define DEV __device__ __forceinline__

DEV unsigned short f2b(float f) {
  union { float f; unsigned u; } v; v.f = f;
  unsigned r = v.u + 0x7fffu + ((v.u >> 16) & 1u);
  return (unsigned short)(r >> 16);
}
DEV float b2f(unsigned short u) {
  union { unsigned u; float f; } v; v.u = (unsigned)u << 16;
  return v.f;
}

DEV void gload16(const void* g, void* l) {
  void* gg = const_cast<void*>(g);
  __builtin_amdgcn_global_load_lds(
      (__attribute__((address_space(1))) unsigned int*)gg,
      (__attribute__((address_space(3))) unsigned int*)l, 16, 0, 0);
}

DEV float red8(float v) {  // sum over aligned 8-lane group
  v += __shfl_xor(v, 1);
  v += __shfl_xor(v, 2);
  v += __shfl_xor(v, 4);
  return v;
}

// ------------------------------ weight prep --------------------------------

__global__ void k_transpose(const float* __restrict__ src,
                            unsigned short* __restrict__ dst, int R, int Cc) {
  __shared__ float tile[32][33];
  const int c0 = blockIdx.x * 32, r0 = blockIdx.y * 32;
  const int tx = threadIdx.x, ty = threadIdx.y;  // block (32,8)
  for (int i = ty; i < 32; i += 8)
    tile[i][tx] = src[(size_t)(r0 + i) * Cc + c0 + tx];
  __syncthreads();
  for (int i = ty; i < 32; i += 8)
    dst[(size_t)(c0 + i) * R + r0 + tx] = f2b(tile[tx][i]);
}

// Wcat^T [384][4096]
__global__ void k_wcat(const float* __restrict__ w1, const float* __restrict__ a1,
                       const float* __restrict__ v1, const float* __restrict__ g1,
                       const float* __restrict__ xw, const float* __restrict__ xa,
                       const float* __restrict__ xv, const float* __restrict__ xg,
                       unsigned short* __restrict__ dst) {
  const int i = blockIdx.x * 256 + threadIdx.x;
  if (i >= 384 * 4096) return;
  const int j = i >> 12, c = i & 4095;
  float val = 0.f;
  if (j < 288) {
    const float* W; const float* mix; int jj, D;
    if (j < 64)       { W = w1; mix = xw; jj = j;       D = 64;  }
    else if (j < 128) { W = a1; mix = xa; jj = j - 64;  D = 64;  }
    else if (j < 160) { W = v1; mix = xv; jj = j - 128; D = 32;  }
    else              { W = g1; mix = xg; jj = j - 160; D = 128; }
    const int cc = c & 2047;
    val = W[(size_t)cc * D + jj];
    if (c >= 2048) val *= mix[cc];
  }
  dst[i] = f2b(val);
}

// Wup^T [8192][288] block-diagonal
__global__ void k_wup(const float* __restrict__ w2, const float* __restrict__ a2,
                      const float* __restrict__ v2, const float* __restrict__ g2,
                      unsigned short* __restrict__ dst) {
  const int i = blockIdx.x * 256 + threadIdx.x;
  if (i >= 8192 * 288) return;
  const int n = i / 288, k = i - n * 288;
  const int p = n >> 11, j = n & 2047;
  float val = 0.f;
  if (p == 0)      { if (k < 64)              val = w2[(size_t)k * 2048 + j]; }
  else if (p == 1) { if (k >= 64 && k < 128)  val = a2[(size_t)(k - 64) * 2048 + j]; }
  else if (p == 2) { if (k >= 128 && k < 160) val = v2[(size_t)(k - 128) * 2048 + j]; }
  else             { if (k >= 160)            val = g2[(size_t)(k - 160) * 2048 + j]; }
  dst[i] = f2b(val);
}

// ------------------------------ LN + mix -----------------------------------

DEV void breduce2(float& a, float& b, float* rbuf) {
#pragma unroll
  for (int m = 1; m < 64; m <<= 1) { a += __shfl_xor(a, m); b += __shfl_xor(b, m); }
  const int wid = threadIdx.x >> 6, lane = threadIdx.x & 63;
  if (lane == 0) { rbuf[wid] = a; rbuf[4 + wid] = b; }
  __syncthreads();
  a = rbuf[0] + rbuf[1] + rbuf[2] + rbuf[3];
  b = rbuf[4] + rbuf[5] + rbuf[6] + rbuf[7];
  __syncthreads();
}

__global__ __launch_bounds__(256)
void k_ln1_mix(const float* __restrict__ x, const float* __restrict__ shift,
               const float* __restrict__ lw, const float* __restrict__ lb,
               const float* __restrict__ mr, const float* __restrict__ mk,
               const float* __restrict__ mv,
               unsigned short* __restrict__ A2, unsigned short* __restrict__ xrb,
               unsigned short* __restrict__ xkb, unsigned short* __restrict__ xvb) {
  __shared__ float rbuf[8];
  const int m = blockIdx.x, tid = threadIdx.x;
  const int b = m >> 10, t = m & 1023;
  const float* xt = x + (size_t)m * 2048 + tid * 8;
  const float* xp = (t > 0) ? (x + (size_t)(m - 1) * 2048 + tid * 8)
                            : (shift + (size_t)b * 2048 + tid * 8);
  float vt[8], vp[8];
  *(float4*)&vt[0] = *(const float4*)(xt);
  *(float4*)&vt[4] = *(const float4*)(xt + 4);
  *(float4*)&vp[0] = *(const float4*)(xp);
  *(float4*)&vp[4] = *(const float4*)(xp + 4);
  float st = 0.f, sp = 0.f;
#pragma unroll
  for (int i = 0; i < 8; ++i) { st += vt[i]; sp += vp[i]; }
  breduce2(st, sp, rbuf);
  const float mt_ = st * (1.f / 2048.f), mp_ = sp * (1.f / 2048.f);
  float qt = 0.f, qp = 0.f;
#pragma unroll
  for (int i = 0; i < 8; ++i) {
    float d0 = vt[i] - mt_; qt += d0 * d0;
    float d1 = vp[i] - mp_; qp += d1 * d1;
  }
  breduce2(qt, qp, rbuf);
  const float rt = rsqrtf(qt * (1.f / 2048.f) + 1e-5f);
  const float rp = rsqrtf(qp * (1.f / 2048.f) + 1e-5f);
  const bool lnp = (t > 0);
#pragma unroll
  for (int i = 0; i < 8; ++i) {
    const int c = tid * 8 + i;
    const float wv = lw[c], bv = lb[c];
    const float xn = (vt[i] - mt_) * rt * wv + bv;
    const float pn = lnp ? ((vp[i] - mp_) * rp * wv + bv) : vp[i];
    const float xx = pn - xn;
    A2[(size_t)m * 4096 + c] = f2b(xn);
    A2[(size_t)m * 4096 + 2048 + c] = f2b(xx);
    xrb[(size_t)m * 2048 + c] = f2b(xn + xx * mr[c]);
    xkb[(size_t)m * 2048 + c] = f2b(xn + xx * mk[c]);
    xvb[(size_t)m * 2048 + c] = f2b(xn + xx * mv[c]);
  }
}

__global__ __launch_bounds__(256)
void k_ln2_mix(const float* __restrict__ x1, const float* __restrict__ shift,
               const float* __restrict__ lw, const float* __restrict__ lb,
               const float* __restrict__ mk, unsigned short* __restrict__ xkf) {
  __shared__ float rbuf[8];
  const int m = blockIdx.x, tid = threadIdx.x;
  const int b = m >> 10, t = m & 1023;
  const float* xt = x1 + (size_t)m * 2048 + tid * 8;
  const float* xp = (t > 0) ? (x1 + (size_t)(m - 1) * 2048 + tid * 8)
                            : (shift + (size_t)b * 2048 + tid * 8);
  float vt[8], vp[8];
  *(float4*)&vt[0] = *(const float4*)(xt);
  *(float4*)&vt[4] = *(const float4*)(xt + 4);
  *(float4*)&vp[0] = *(const float4*)(xp);
  *(float4*)&vp[4] = *(const float4*)(xp + 4);
  float st = 0.f, sp = 0.f;
#pragma unroll
  for (int i = 0; i < 8; ++i) { st += vt[i]; sp += vp[i]; }
  breduce2(st, sp, rbuf);
  const float mt_ = st * (1.f / 2048.f), mp_ = sp * (1.f / 2048.f);
  float qt = 0.f, qp = 0.f;
#pragma unroll
  for (int i = 0; i < 8; ++i) {
    float d0 = vt[i] - mt_; qt += d0 * d0;
    float d1 = vp[i] - mp_; qp += d1 * d1;
  }
  breduce2(qt, qp, rbuf);
  const float rt = rsqrtf(qt * (1.f / 2048.f) + 1e-5f);
  const float rp = rsqrtf(qp * (1.f / 2048.f) + 1e-5f);
  const bool lnp = (t > 0);
#pragma unroll
  for (int i = 0; i < 8; ++i) {
    const int c = tid * 8 + i;
    const float wv = lw[c], bv = lb[c];
    const float xn = (vt[i] - mt_) * rt * wv + bv;
    const float pn = lnp ? ((vp[i] - mp_) * rp * wv + bv) : vp[i];
    xkf[(size_t)m * 2048 + c] = f2b(xn + (pn - xn) * mk[c]);
  }
}

// ------------------------------ epilogues ----------------------------------

constexpr int EP_F32 = 0, EP_B16 = 1, EP_RELU2 = 5, EP_ADDF = 6, EP_HACT = 7;

template <int EP>
DEV void ep_store(float acc, long row, long c, long ldc, float* Co,
                  unsigned short* Cob, const float* bias, const float* e0f,
                  const unsigned short* e0b) {
  const long idx = row * ldc + c;
  (void)bias; (void)e0b;
  if constexpr (EP == EP_F32) {
    Co[idx] = acc;
  } else if constexpr (EP == EP_B16) {
    Cob[idx] = f2b(acc);
  } else if constexpr (EP == EP_RELU2) {
    const float r = fmaxf(acc, 0.f);
    Cob[idx] = f2b(r * r);
  } else if constexpr (EP == EP_ADDF) {
    Co[idx] = acc + e0f[idx];
  } else if constexpr (EP == EP_HACT) {
    float vv = acc;
    if (c < 64) vv = tanhf(vv);                      // w path
    else if (c >= 160) vv = 1.f / (1.f + expf(-vv)); // g path
    Cob[idx] = f2b(vv);
  }
}

// ---------------- GEMM v1 (128x128, small/odd shapes) ----------------------

template <int EP>
__global__ __launch_bounds__(256)
void gemm_bt(const unsigned short* __restrict__ A, long lda,
             const unsigned short* __restrict__ Bt, long ldb, long N, long K,
             long ldc, float* __restrict__ Co, unsigned short* __restrict__ Cob,
             const float* __restrict__ bias, const float* __restrict__ e0f,
             const unsigned short* __restrict__ e0b) {
  __shared__ unsigned short As[4096];  // [128][32]
  __shared__ unsigned short Bs[4096];  // [128][32]
  const int tid = threadIdx.x;
  const int wid = tid >> 6, lane = tid & 63;
  const long row0 = (long)blockIdx.x * 128, col0 = (long)blockIdx.y * 128;
  const int wm = (wid >> 1) * 64, wn = (wid & 1) * 64;
  f32x4 acc[4][4] = {};
  const int sr = tid >> 2, sk = (tid & 3) * 8;
  const unsigned short* gA = A + (row0 + sr) * lda + sk;
  const unsigned short* gB = Bt + (col0 + sr) * ldb + sk;
  unsigned short* lA = As + wid * 512;
  unsigned short* lB = Bs + wid * 512;
  const int fr = lane & 15, fk = (lane >> 4) * 8;

  for (long kb = 0; kb < K; kb += 32) {
    gload16(gA + kb, lA);
    gload16(gA + kb + 64 * lda, lA + 2048);
    gload16(gB + kb, lB);
    gload16(gB + kb + 64 * ldb, lB + 2048);
    __syncthreads();
    bf16x8 af[4], bq[4];
#pragma unroll
    for (int mt = 0; mt < 4; ++mt)
      af[mt] = *(const bf16x8*)(As + (wm + mt * 16 + fr) * 32 + fk);
#pragma unroll
    for (int nt = 0; nt < 4; ++nt)
      bq[nt] = *(const bf16x8*)(Bs + (wn + nt * 16 + fr) * 32 + fk);
#pragma unroll
    for (int mt = 0; mt < 4; ++mt)
#pragma unroll
      for (int nt = 0; nt < 4; ++nt)
        acc[mt][nt] = __builtin_amdgcn_mfma_f32_16x16x32_bf16(
            af[mt], bq[nt], acc[mt][nt], 0, 0, 0);
    __syncthreads();
  }
  const int fq = lane >> 4;
#pragma unroll
  for (int mt = 0; mt < 4; ++mt) {
#pragma unroll
    for (int nt = 0; nt < 4; ++nt) {
      const long c = col0 + wn + nt * 16 + fr;
      if (c < N) {
        const long rb = row0 + wm + mt * 16 + fq * 4;
#pragma unroll
        for (int rg = 0; rg < 4; ++rg)
          ep_store<EP>(acc[mt][nt][rg], rb + rg, c, ldc, Co, Cob, bias, e0f, e0b);
      }
    }
  }
}

// ---------------- GEMM v2 (128x256, triple-buffer depth-2 vmcnt) -----------
// BM=128, BN=256, BK=32; 512 thr, 8 waves (2Mx4N). LDS 3 x 24KB (2 blk/CU).
// Steady state: stage tile kt+2, s_waitcnt vmcnt(6) waits only for tile kt
// (issued 2 K-steps earlier -> L2 latency fully covered). XOR-swizzled LDS.

template <int EP>
__global__ __launch_bounds__(512)
void gemm2(const unsigned short* __restrict__ A, long lda,
           const unsigned short* __restrict__ Bt, long ldb, long K, long ldc,
           float* __restrict__ Co, unsigned short* __restrict__ Cob,
           const float* __restrict__ e0f) {
  __shared__ unsigned short As[3][4096];  // 3 x 8KB
  __shared__ unsigned short Bs[3][8192];  // 3 x 16KB
  const int tid = threadIdx.x;
  const int wid = tid >> 6, lane = tid & 63;
  const long row0 = (long)blockIdx.x * 128, col0 = (long)blockIdx.y * 256;
  const int wm = (wid >> 2) * 64, wn = (wid & 3) * 64;
  f32x4 acc[4][4] = {};
  const int srow = tid >> 2;                       // 0..127
  const int scol = 8 * ((tid & 3) ^ (srow & 3));   // swizzled 16B slot
  const unsigned short* gA = A + (row0 + srow) * lda + scol;
  const unsigned short* gB1 = Bt + (col0 + srow) * ldb + scol;
  const unsigned short* gB2 = gB1 + 128 * ldb;
  const int fr = lane & 15, fc = lane >> 4;

#define STAGE2(buf, kb)                                   \
  {                                                       \
    gload16(gA + (kb), &As[buf][0] + wid * 512);          \
    gload16(gB1 + (kb), &Bs[buf][0] + wid * 512);         \
    gload16(gB2 + (kb), &Bs[buf][0] + 4096 + wid * 512);  \
  }

  const int NT = (int)(K >> 5);
  STAGE2(0, 0)
  if (NT > 1) STAGE2(1, 32)
  int cur = 0;
  for (int kt = 0; kt < NT; ++kt) {
    if (kt + 2 < NT) {
      const int nb = (cur + 2 >= 3) ? cur - 1 : cur + 2;
      STAGE2(nb, (long)(kt + 2) * 32)
      asm volatile("s_waitcnt vmcnt(6)" ::: "memory");
    } else if (kt + 1 < NT) {
      asm volatile("s_waitcnt vmcnt(3)" ::: "memory");
    } else {
      asm volatile("s_waitcnt vmcnt(0)" ::: "memory");
    }
    __builtin_amdgcn_s_barrier();
    asm volatile("" ::: "memory");
    bf16x8 af[4], bq[4];
#pragma unroll
    for (int mt = 0; mt < 4; ++mt) {
      const int r = wm + mt * 16 + fr;
      af[mt] = *(const bf16x8*)(&As[cur][0] + r * 32 + ((fc ^ (r & 3)) * 8));
    }
#pragma unroll
    for (int nt = 0; nt < 4; ++nt) {
      const int r = wn + nt * 16 + fr;
      bq[nt] = *(const bf16x8*)(&Bs[cur][0] + r * 32 + ((fc ^ (r & 3)) * 8));
    }
    __builtin_amdgcn_s_setprio(1);
#pragma unroll
    for (int mt = 0; mt < 4; ++mt)
#pragma unroll
      for (int nt = 0; nt < 4; ++nt)
        acc[mt][nt] = __builtin_amdgcn_mfma_f32_16x16x32_bf16(
            af[mt], bq[nt], acc[mt][nt], 0, 0, 0);
    __builtin_amdgcn_s_setprio(0);
    asm volatile("" ::: "memory");
    __builtin_amdgcn_s_barrier();
    cur = (cur + 1 >= 3) ? 0 : cur + 1;
  }
#undef STAGE2
  const int fq = lane >> 4;
#pragma unroll
  for (int mt = 0; mt < 4; ++mt) {
#pragma unroll
    for (int nt = 0; nt < 4; ++nt) {
      const long c = col0 + wn + nt * 16 + fr;
      const long rb = row0 + wm + mt * 16 + fq * 4;
#pragma unroll
      for (int rg = 0; rg < 4; ++rg)
        ep_store<EP>(acc[mt][nt][rg], rb + rg, c, ldc, Co, Cob, nullptr, e0f,
                     nullptr);
    }
  }
}

// ---------------- gemm_up4: Hact[4096][288] @ Wup^T[8192][288] -------------
// Triple-buffer depth-2 like gemm2. Path p = blockIdx.y>>3 block-uniform.

__global__ __launch_bounds__(512)
void gemm_up4(const unsigned short* __restrict__ A,
              const unsigned short* __restrict__ Bt,
              float* __restrict__ whb, unsigned short* __restrict__ abuf,
              unsigned short* __restrict__ vfb, unsigned short* __restrict__ gbuf,
              const float* __restrict__ w0, const float* __restrict__ a0,
              const float* __restrict__ v0,
              const unsigned short* __restrict__ vraw,
              const float* __restrict__ vfirst) {
  __shared__ unsigned short As[3][4096];
  __shared__ unsigned short Bs[3][8192];
  const int tid = threadIdx.x;
  const int wid = tid >> 6, lane = tid & 63;
  const long row0 = (long)blockIdx.x * 128, col0 = (long)blockIdx.y * 256;
  const int wm = (wid >> 2) * 64, wn = (wid & 3) * 64;
  f32x4 acc[4][4] = {};
  const int srow = tid >> 2;
  const int scol = 8 * ((tid & 3) ^ (srow & 3));
  const unsigned short* gA = A + (row0 + srow) * 288 + scol;
  const unsigned short* gB1 = Bt + (col0 + srow) * 288 + scol;
  const unsigned short* gB2 = gB1 + 128 * 288;
  const int fr = lane & 15, fc = lane >> 4;

#define STAGEU(buf, kb)                                   \
  {                                                       \
    gload16(gA + (kb), &As[buf][0] + wid * 512);          \
    gload16(gB1 + (kb), &Bs[buf][0] + wid * 512);         \
    gload16(gB2 + (kb), &Bs[buf][0] + 4096 + wid * 512);  \
  }

  STAGEU(0, 0)
  STAGEU(1, 32)
  int cur = 0;
  for (int kt = 0; kt < 9; ++kt) {
    if (kt + 2 < 9) {
      const int nb = (cur + 2 >= 3) ? cur - 1 : cur + 2;
      STAGEU(nb, (long)(kt + 2) * 32)
      asm volatile("s_waitcnt vmcnt(6)" ::: "memory");
    } else if (kt + 1 < 9) {
      asm volatile("s_waitcnt vmcnt(3)" ::: "memory");
    } else {
      asm volatile("s_waitcnt vmcnt(0)" ::: "memory");
    }
    __builtin_amdgcn_s_barrier();
    asm volatile("" ::: "memory");
    bf16x8 af[4], bq[4];
#pragma unroll
    for (int mt = 0; mt < 4; ++mt) {
      const int r = wm + mt * 16 + fr;
      af[mt] = *(const bf16x8*)(&As[cur][0] + r * 32 + ((fc ^ (r & 3)) * 8));
    }
#pragma unroll
    for (int nt = 0; nt < 4; ++nt) {
      const int r = wn + nt * 16 + fr;
      bq[nt] = *(const bf16x8*)(&Bs[cur][0] + r * 32 + ((fc ^ (r & 3)) * 8));
    }
    __builtin_amdgcn_s_setprio(1);
#pragma unroll
    for (int mt = 0; mt < 4; ++mt)
#pragma unroll
      for (int nt = 0; nt < 4; ++nt)
        acc[mt][nt] = __builtin_amdgcn_mfma_f32_16x16x32_bf16(
            af[mt], bq[nt], acc[mt][nt], 0, 0, 0);
    __builtin_amdgcn_s_setprio(0);
    asm volatile("" ::: "memory");
    __builtin_amdgcn_s_barrier();
    cur = (cur + 1 >= 3) ? 0 : cur + 1;
  }
#undef STAGEU
  const int fq = lane >> 4;
  const int p = (int)(blockIdx.y >> 3);
#pragma unroll
  for (int mt = 0; mt < 4; ++mt) {
#pragma unroll
    for (int nt = 0; nt < 4; ++nt) {
      const long c = col0 + wn + nt * 16 + fr;
      const long cc = c & 2047;
      const long rb = row0 + wm + mt * 16 + fq * 4;
#pragma unroll
      for (int rg = 0; rg < 4; ++rg) {
        const float av = acc[mt][nt][rg];
        const long idx = (rb + rg) * 2048 + cc;
        if (p == 0) {
          const float wv = w0[cc] + av;
          const float sp = log1pf(expf(-wv));
          whb[idx] = expf(-expf(-sp - 0.5f));
        } else if (p == 1) {
          abuf[idx] = f2b(1.f / (1.f + expf(-(a0[cc] + av))));
        } else if (p == 2) {
          const float s = 1.f / (1.f + expf(-(v0[cc] + av)));
          const float vv = b2f(vraw[idx]);
          vfb[idx] = f2b(vv + (vfirst[idx] - vv) * s);
        } else {
          gbuf[idx] = f2b(av);  // g = sigmoid(xg@g1) @ g2 -- NO outer act
        }
      }
    }
  }
}

// ------------------------------ k_post -------------------------------------
__global__ __launch_bounds__(256)
void k_post(unsigned short* __restrict__ kio, unsigned short* __restrict__ abio,
            unsigned short* __restrict__ aao, const float* __restrict__ kkw,
            const float* __restrict__ kaw) {
  const int m = blockIdx.x, tid = threadIdx.x;
  const size_t base = (size_t)m * 2048 + tid * 8;
  us8 k8 = *(const us8*)(kio + base);
  us8 a8 = *(const us8*)(abio + base);
  float kk8[8], ka8[8];
  *(float4*)&kk8[0] = *(const float4*)(kkw + tid * 8);
  *(float4*)&kk8[4] = *(const float4*)(kkw + tid * 8 + 4);
  *(float4*)&ka8[0] = *(const float4*)(kaw + tid * 8);
  *(float4*)&ka8[4] = *(const float4*)(kaw + tid * 8 + 4);
  float kx[8], kv[8], av[8];
  float ss = 0.f;
#pragma unroll
  for (int i = 0; i < 8; ++i) {
    kv[i] = b2f(k8[i]); av[i] = b2f(a8[i]);
    kx[i] = kv[i] * kk8[i]; ss += kx[i] * kx[i];
  }
  ss = red8(ss);
  const float inv = 1.f / fmaxf(sqrtf(ss), 1e-12f);
  us8 kh8, aa8, bb8;
#pragma unroll
  for (int i = 0; i < 8; ++i) {
    const float kkn = kx[i] * inv;
    kh8[i] = f2b(kv[i] * (1.f + (av[i] - 1.f) * ka8[i]));
    aa8[i] = f2b(-kkn);
    bb8[i] = f2b(kkn * av[i]);
  }
  *(us8*)(kio + base) = kh8;
  *(us8*)(aao + base) = aa8;
  *(us8*)(abio + base) = bb8;
}

// ------------------------------ WKV scan (R11) ------------------------------

DEV float red16(float x) {  // all-lanes sum within each 16-lane row
  union { float f; int i; } a, r;
  a.f = x; r.i = __builtin_amdgcn_update_dpp(0, a.i, 0xB1, 0xf, 0xf, true);
  x += r.f;
  a.f = x; r.i = __builtin_amdgcn_update_dpp(0, a.i, 0x4E, 0xf, 0xf, true);
  x += r.f;
  a.f = x; r.i = __builtin_amdgcn_update_dpp(0, a.i, 0x124, 0xf, 0xf, true);
  x += r.f;
  a.f = x; r.i = __builtin_amdgcn_update_dpp(0, a.i, 0x128, 0xf, 0xf, true);
  x += r.f;
  return x;
}

DEV void cv4(const uint2 q, float* o) {
  union { unsigned u; float f; } t;
  t.u = q.x << 16;          o[0] = t.f;
  t.u = q.x & 0xffff0000u;  o[1] = t.f;
  t.u = q.y << 16;          o[2] = t.f;
  t.u = q.y & 0xffff0000u;  o[3] = t.f;
}

__global__ __launch_bounds__(64)
void k_scan(const unsigned short* __restrict__ rp,
            const unsigned short* __restrict__ kp,
            const unsigned short* __restrict__ vp,
            const float* __restrict__ wp,
            const unsigned short* __restrict__ ap,
            const unsigned short* __restrict__ bp,
            const float* __restrict__ s0, unsigned short* __restrict__ yout,
            float* __restrict__ snew) {
  __shared__ float4 slots[8][49];
  __shared__ unsigned short ylds[1024][4];
  const int lane = threadIdx.x;
  const int bh = blockIdx.x & 127;
  const int rq = blockIdx.x >> 7;
  const int b = bh >> 5, h = bh & 31;
  const int kg = lane & 15, rl = lane >> 4;
  const int v = rq * 4 + rl, ks = kg * 4;
  const size_t off_bh = (size_t)b * 1024 * 2048 + (size_t)h * 64;
  const int vfo = 768 + ((rq & 1) * 4 + rl) * 2;

  float S[4];
  *(float4*)&S[0] = *(const float4*)(s0 + (((size_t)bh * 64 + v) * 64 + ks));

  const char* gp = nullptr;
  size_t gstep = 0;
  if (lane < 49) {
    if (lane < 32) {
      const int arr = lane >> 3, sub = lane & 7;
      const unsigned short* base = arr == 0 ? rp : arr == 1 ? kp
                                 : arr == 2 ? ap : bp;
      gp = (const char*)(base + off_bh + sub * 8);
      gstep = 4096;
    } else if (lane < 48) {
      gp = (const char*)(wp + off_bh + (lane - 32) * 4);
      gstep = 8192;
    } else {
      gp = (const char*)(vp + off_bh + (rq & ~1) * 4);
      gstep = 4096;
    }
  }
#pragma unroll
  for (int s = 0; s < 8; ++s) {
    if (lane < 49) gload16(gp, &slots[s][0]);
    gp += gstep;
  }

  uint2 rA, kA, aA, bA, rB, kB, aB, bB;
  float4 wA, wB;
  unsigned short fA, fB;
  asm volatile("s_waitcnt vmcnt(7)" ::: "memory");
  {
    const char* nb = (const char*)&slots[0][0];
    rA = *(const uint2*)(nb + kg * 8);
    kA = *(const uint2*)(nb + 128 + kg * 8);
    aA = *(const uint2*)(nb + 256 + kg * 8);
    bA = *(const uint2*)(nb + 384 + kg * 8);
    wA = *(const float4*)(nb + 512 + kg * 16);
    fA = *(const unsigned short*)(nb + vfo);
  }

#define SSTEP(T, Cr, Ck, Ca, Cb, Cw, Cf, Nr, Nk, Na, Nb, Nw, Nf)             \
  {                                                                          \
    asm volatile("s_waitcnt lgkmcnt(0)" ::: "memory");                       \
    if (lane < 49) gload16(gp, &slots[(T) & 7][0]);                          \
    if ((T) < 1015) gp += gstep;                                             \
    asm volatile("s_waitcnt vmcnt(7)" ::: "memory");                         \
    const char* nb = (const char*)&slots[((T) + 1) & 7][0];                  \
    Nr = *(const uint2*)(nb + kg * 8);                                       \
    Nk = *(const uint2*)(nb + 128 + kg * 8);                                 \
    Na = *(const uint2*)(nb + 256 + kg * 8);                                 \
    Nb = *(const uint2*)(nb + 384 + kg * 8);                                 \
    Nw = *(const float4*)(nb + 512 + kg * 16);                               \
    Nf = *(const unsigned short*)(nb + vfo);                                 \
    float rr[4], kk[4], av[4], bv[4];                                        \
    cv4(Cr, rr); cv4(Ck, kk); cv4(Ca, av); cv4(Cb, bv);                      \
    const float vv = b2f(Cf);                                                \
    float sa = S[0] * av[0] + S[1] * av[1] + S[2] * av[2] + S[3] * av[3];    \
    sa = red16(sa);                                                          \
    float y;                                                                 \
    S[0] = S[0] * Cw.x + sa * bv[0] + vv * kk[0]; y  = S[0] * rr[0];         \
    S[1] = S[1] * Cw.y + sa * bv[1] + vv * kk[1]; y += S[1] * rr[1];         \
    S[2] = S[2] * Cw.z + sa * bv[2] + vv * kk[2]; y += S[2] * rr[2];         \
    S[3] = S[3] * Cw.w + sa * bv[3] + vv * kk[3]; y += S[3] * rr[3];         \
    y = red16(y);                                                            \
    if (kg == 0) ylds[T][rl] = f2b(y);                                       \
  }

  for (int tb = 0; tb < 1024; tb += 2) {
    SSTEP(tb + 0, rA, kA, aA, bA, wA, fA, rB, kB, aB, bB, wB, fB)
    SSTEP(tb + 1, rB, kB, aB, bB, wB, fB, rA, kA, aA, bA, wA, fA)
  }
#undef SSTEP

  *(float4*)(snew + (((size_t)bh * 64 + v) * 64 + ks)) = *(const float4*)&S[0];
  asm volatile("s_waitcnt lgkmcnt(0)" ::: "memory");
#pragma unroll 4
  for (int it = 0; it < 16; ++it) {
    const int t = lane + it * 64;
    const uint2 val = *(const uint2*)&ylds[t][0];
    *(uint2*)(yout + off_bh + (size_t)t * 2048 + rq * 4) = val;
  }
}

// ---------------------- GroupNorm + resid + gate ---------------------------

__global__ __launch_bounds__(256)
void k_gn(const unsigned short* __restrict__ y, const unsigned short* __restrict__ r,
          const unsigned short* __restrict__ kh, const unsigned short* __restrict__ vf,
          const unsigned short* __restrict__ g, const float* __restrict__ rk,
          const float* __restrict__ lw, const float* __restrict__ lb,
          unsigned short* __restrict__ ywg) {
  const int m = blockIdx.x, tid = threadIdx.x;
  const size_t base = (size_t)m * 2048 + tid * 8;
  us8 y8 = *(const us8*)(y + base);
  us8 r8 = *(const us8*)(r + base);
  us8 k8 = *(const us8*)(kh + base);
  us8 v8 = *(const us8*)(vf + base);
  us8 g8 = *(const us8*)(g + base);
  float yv[8];
  float rkv[8];
  *(float4*)&rkv[0] = *(const float4*)(rk + tid * 8);
  *(float4*)&rkv[4] = *(const float4*)(rk + tid * 8 + 4);
  float sy = 0.f, sd = 0.f;
#pragma unroll
  for (int i = 0; i < 8; ++i) {
    yv[i] = b2f(y8[i]);
    sy += yv[i];
    sd += b2f(r8[i]) * b2f(k8[i]) * rkv[i];
  }
  sy = red8(sy);
  sd = red8(sd);
  const float mu = sy * (1.f / 64.f);
  float sq = 0.f;
#pragma unroll
  for (int i = 0; i < 8; ++i) { const float d = yv[i] - mu; sq += d * d; }
  sq = red8(sq);
  const float rstd = rsqrtf(sq * (1.f / 64.f) + 64e-5f);
  us8 o8;
#pragma unroll
  for (int i = 0; i < 8; ++i) {
    const int c = tid * 8 + i;
    const float gn = (yv[i] - mu) * rstd * lw[c] + lb[c];
    o8[i] = f2b((gn + sd * b2f(v8[i])) * b2f(g8[i]));
  }
  *(us8*)(ywg + base) = o8;
}

// ------------------------------ launch -------------------------------------

extern "C" void kernel_launch(void* const* d_in, const int* in_sizes, int n_in,
                              void* d_out, int out_size, void* d_ws,
                              size_t ws_size, hipStream_t stream) {
  (void)in_sizes; (void)n_in; (void)out_size; (void)ws_size;
  const float* x         = (const float*)d_in[0];
  const float* v_first   = (const float*)d_in[1];
  const float* att_shift = (const float*)d_in[2];
  const float* ffn_shift = (const float*)d_in[3];
  const float* wkv0      = (const float*)d_in[4];
  const float* ln1w = (const float*)d_in[5];
  const float* ln1b = (const float*)d_in[6];
  const float* ln2w = (const float*)d_in[7];
  const float* ln2b = (const float*)d_in[8];
  const float* x_r = (const float*)d_in[9];
  const float* x_w = (const float*)d_in[10];
  const float* x_k = (const float*)d_in[11];
  const float* x_v = (const float*)d_in[12];
  const float* x_a = (const float*)d_in[13];
  const float* x_g = (const float*)d_in[14];
  const float* Wr = (const float*)d_in[15];
  const float* Wk = (const float*)d_in[16];
  const float* Wv = (const float*)d_in[17];
  const float* Wo = (const float*)d_in[18];
  const float* w0 = (const float*)d_in[19];
  const float* w1 = (const float*)d_in[20];
  const float* w2 = (const float*)d_in[21];
  const float* v0 = (const float*)d_in[22];
  const float* v1 = (const float*)d_in[23];
  const float* v2 = (const float*)d_in[24];
  const float* a0 = (const float*)d_in[25];
  const float* a1 = (const float*)d_in[26];
  const float* a2 = (const float*)d_in[27];
  const float* g1 = (const float*)d_in[28];
  const float* g2 = (const float*)d_in[29];
  const float* k_k = (const float*)d_in[30];
  const float* k_a = (const float*)d_in[31];
  const float* r_k = (const float*)d_in[32];
  const float* lnxw = (const float*)d_in[33];
  const float* lnxb = (const float*)d_in[34];
  const float* ffn_xk = (const float*)d_in[35];
  const float* Wkf = (const float*)d_in[36];
  const float* Wvf = (const float*)d_in[37];

  char* ws = (char*)d_ws;
  constexpr size_t OFF_TWR   = 0;
  constexpr size_t OFF_TWK   = 8388608;
  constexpr size_t OFF_TWV   = 16777216;
  constexpr size_t OFF_TWO   = 25165824;
  constexpr size_t OFF_TWCAT = 34734080;
  constexpr size_t OFF_HACT  = 37879808;
  constexpr size_t OFF_GBUF  = 40239104;
  constexpr size_t OFF_WH    = 57016320;
  constexpr size_t OFF_R     = 90570752;
  constexpr size_t OFF_KH    = 107347968;
  constexpr size_t OFF_VF    = 124125184;
  constexpr size_t OFF_AA    = 140902400;
  constexpr size_t OFF_BB    = 157679616;
  constexpr size_t OFF_TWUP  = 174456832;  // [8192][288] bf16, 4.7MB

  unsigned short* tWr = (unsigned short*)(ws + OFF_TWR);
  unsigned short* tWk = (unsigned short*)(ws + OFF_TWK);
  unsigned short* tWv = (unsigned short*)(ws + OFF_TWV);
  unsigned short* tWo = (unsigned short*)(ws + OFF_TWO);
  unsigned short* tWcat = (unsigned short*)(ws + OFF_TWCAT);
  unsigned short* Hact  = (unsigned short*)(ws + OFF_HACT);
  unsigned short* gbuf  = (unsigned short*)(ws + OFF_GBUF);
  unsigned short* tWvfh = (unsigned short*)(ws + OFF_GBUF);
  unsigned short* act2  = (unsigned short*)(ws + OFF_WH);
  float*          whb   = (float*)(ws + OFF_WH);
  unsigned short* ywg   = (unsigned short*)(ws + OFF_WH);
  unsigned short* kf    = (unsigned short*)(ws + OFF_WH);
  unsigned short* bxr   = (unsigned short*)(ws + OFF_AA);
  unsigned short* bxk   = (unsigned short*)(ws + OFF_BB);
  unsigned short* bxv   = (unsigned short*)(ws + OFF_VF);
  unsigned short* rbuf  = (unsigned short*)(ws + OFF_R);
  unsigned short* khb   = (unsigned short*)(ws + OFF_KH);
  unsigned short* vfb   = (unsigned short*)(ws + OFF_VF);
  unsigned short* aab   = (unsigned short*)(ws + OFF_AA);
  unsigned short* bbb   = (unsigned short*)(ws + OFF_BB);
  unsigned short* vraw  = (unsigned short*)(ws + OFF_AA);
  unsigned short* abuf  = (unsigned short*)(ws + OFF_BB);
  float*          x1    = (float*)(ws + OFF_R);
  unsigned short* xkf   = (unsigned short*)(ws + OFF_VF);
  unsigned short* tWkf  = (unsigned short*)(ws + OFF_AA);
  unsigned short* tWup  = (unsigned short*)(ws + OFF_TWUP);
  float* out = (float*)d_out;
  float* snew = out + 8388608;

  const dim3 tb(32, 8);
  // ---- weight prep ----
  k_transpose<<<dim3(64, 64), tb, 0, stream>>>(Wr, tWr, 2048, 2048);
  k_transpose<<<dim3(64, 64), tb, 0, stream>>>(Wk, tWk, 2048, 2048);
  k_transpose<<<dim3(64, 64), tb, 0, stream>>>(Wv, tWv, 2048, 2048);
  k_transpose<<<dim3(64, 64), tb, 0, stream>>>(Wo, tWo, 2048, 2048);
  k_wcat<<<6144, 256, 0, stream>>>(w1, a1, v1, g1, x_w, x_a, x_v, x_g, tWcat);
  k_wup<<<9216, 256, 0, stream>>>(w2, a2, v2, g2, tWup);

  // ---- TimeMix front ----
  k_ln1_mix<<<4096, 256, 0, stream>>>(x, att_shift, ln1w, ln1b, x_r, x_k, x_v,
                                      act2, bxr, bxk, bxv);
  gemm2<EP_B16><<<dim3(32, 8), 512, 0, stream>>>(
      bxr, 2048, tWr, 2048, 2048, 2048, nullptr, rbuf, nullptr);
  gemm2<EP_B16><<<dim3(32, 8), 512, 0, stream>>>(
      bxk, 2048, tWk, 2048, 2048, 2048, nullptr, khb, nullptr);
  gemm2<EP_B16><<<dim3(32, 8), 512, 0, stream>>>(
      bxv, 2048, tWv, 2048, 2048, 2048, nullptr, vraw, nullptr);
  gemm_bt<EP_HACT><<<dim3(32, 3), 256, 0, stream>>>(
      act2, 4096, tWcat, 4096, 288, 4096, 288, nullptr, Hact, nullptr, nullptr, nullptr);
  gemm_up4<<<dim3(32, 32), 512, 0, stream>>>(
      Hact, tWup, whb, abuf, vfb, gbuf, w0, a0, v0, vraw, v_first);
  k_post<<<4096, 256, 0, stream>>>(khb, abuf, aab, k_k, k_a);

  // ---- WKV scan ----
  k_scan<<<2048, 64, 0, stream>>>(rbuf, khb, vfb, whb, aab, bbb, wkv0,
                                  (unsigned short*)out, snew);
  k_gn<<<4096, 256, 0, stream>>>((const unsigned short*)out, rbuf, khb, vfb,
                                 gbuf, r_k, lnxw, lnxb, ywg);

  // ---- Wo projection (+x) -> x1 ----
  gemm2<EP_ADDF><<<dim3(32, 8), 512, 0, stream>>>(
      ywg, 2048, tWo, 2048, 2048, 2048, x1, nullptr, x);

  // ---- ChannelMix (two DFF halves) ----
  k_ln2_mix<<<4096, 256, 0, stream>>>(x1, ffn_shift, ln2w, ln2b, ffn_xk, xkf);
  k_transpose<<<dim3(256, 64), tb, 0, stream>>>(Wkf, tWkf, 2048, 8192);
  gemm2<EP_RELU2><<<dim3(32, 16), 512, 0, stream>>>(
      xkf, 2048, tWkf, 2048, 2048, 4096, nullptr, kf, nullptr);
  k_transpose<<<dim3(64, 128), tb, 0, stream>>>(Wvf, tWvfh, 4096, 2048);
  gemm2<EP_ADDF><<<dim3(32, 8), 512, 0, stream>>>(
      kf, 4096, tWvfh, 4096, 4096, 2048, out, nullptr, x1);
  gemm2<EP_RELU2><<<dim3(32, 16), 512, 0, stream>>>(
      xkf, 2048, tWkf + (size_t)4096 * 2048, 2048, 2048, 4096, nullptr, kf, nullptr);
  k_transpose<<<dim3(64, 128), tb, 0, stream>>>(Wvf + (size_t)4096 * 2048, tWvfh,
                                                4096, 2048);
  gemm2<EP_ADDF><<<dim3(32, 8), 512, 0, stream>>>(
      kf, 4096, tWvfh, 4096, 4096, 2048, out, nullptr, out);
}

// Round 13
// 1286.406 us; speedup vs baseline: 1.0102x; 1.0102x over previous
//
#include <hip/hip_runtime.h>
#include <cstdint>

// ---------------------------------------------------------------------------
// RWKV7 block (B=4,T=1024,C=2048,H=32,N=64,DFF=8192) for MI355X gfx950.
// R13: big GEMMs -> gemm3: 128x128 tile, 256 thr (4 waves 2x2), double-buffer
//      LDS (32KB), counted vmcnt(4), both-sides XOR swizzle, setprio.
//      (m92/m103 tile table: 128^2 > 128x256 at the 2-barrier structure.)
//      Scan = R11 optimum. Triple-buffer (R12, neutral) reverted.
// ---------------------------------------------------------------------------

typedef __attribute__((ext_vector_type(4))) float f32x4;
typedef __attribute__((ext_vector_type(8))) __bf16 bf16x8;
typedef __attribute__((ext_vector_type(8))) unsigned short us8;

#define DEV __device__ __forceinline__

DEV unsigned short f2b(float f) {
  union { float f; unsigned u; } v; v.f = f;
  unsigned r = v.u + 0x7fffu + ((v.u >> 16) & 1u);
  return (unsigned short)(r >> 16);
}
DEV float b2f(unsigned short u) {
  union { unsigned u; float f; } v; v.u = (unsigned)u << 16;
  return v.f;
}

DEV void gload16(const void* g, void* l) {
  void* gg = const_cast<void*>(g);
  __builtin_amdgcn_global_load_lds(
      (__attribute__((address_space(1))) unsigned int*)gg,
      (__attribute__((address_space(3))) unsigned int*)l, 16, 0, 0);
}

DEV float red8(float v) {  // sum over aligned 8-lane group
  v += __shfl_xor(v, 1);
  v += __shfl_xor(v, 2);
  v += __shfl_xor(v, 4);
  return v;
}

// ------------------------------ weight prep --------------------------------

__global__ void k_transpose(const float* __restrict__ src,
                            unsigned short* __restrict__ dst, int R, int Cc) {
  __shared__ float tile[32][33];
  const int c0 = blockIdx.x * 32, r0 = blockIdx.y * 32;
  const int tx = threadIdx.x, ty = threadIdx.y;  // block (32,8)
  for (int i = ty; i < 32; i += 8)
    tile[i][tx] = src[(size_t)(r0 + i) * Cc + c0 + tx];
  __syncthreads();
  for (int i = ty; i < 32; i += 8)
    dst[(size_t)(c0 + i) * R + r0 + tx] = f2b(tile[tx][i]);
}

// Wcat^T [384][4096]
__global__ void k_wcat(const float* __restrict__ w1, const float* __restrict__ a1,
                       const float* __restrict__ v1, const float* __restrict__ g1,
                       const float* __restrict__ xw, const float* __restrict__ xa,
                       const float* __restrict__ xv, const float* __restrict__ xg,
                       unsigned short* __restrict__ dst) {
  const int i = blockIdx.x * 256 + threadIdx.x;
  if (i >= 384 * 4096) return;
  const int j = i >> 12, c = i & 4095;
  float val = 0.f;
  if (j < 288) {
    const float* W; const float* mix; int jj, D;
    if (j < 64)       { W = w1; mix = xw; jj = j;       D = 64;  }
    else if (j < 128) { W = a1; mix = xa; jj = j - 64;  D = 64;  }
    else if (j < 160) { W = v1; mix = xv; jj = j - 128; D = 32;  }
    else              { W = g1; mix = xg; jj = j - 160; D = 128; }
    const int cc = c & 2047;
    val = W[(size_t)cc * D + jj];
    if (c >= 2048) val *= mix[cc];
  }
  dst[i] = f2b(val);
}

// Wup^T [8192][288] block-diagonal
__global__ void k_wup(const float* __restrict__ w2, const float* __restrict__ a2,
                      const float* __restrict__ v2, const float* __restrict__ g2,
                      unsigned short* __restrict__ dst) {
  const int i = blockIdx.x * 256 + threadIdx.x;
  if (i >= 8192 * 288) return;
  const int n = i / 288, k = i - n * 288;
  const int p = n >> 11, j = n & 2047;
  float val = 0.f;
  if (p == 0)      { if (k < 64)              val = w2[(size_t)k * 2048 + j]; }
  else if (p == 1) { if (k >= 64 && k < 128)  val = a2[(size_t)(k - 64) * 2048 + j]; }
  else if (p == 2) { if (k >= 128 && k < 160) val = v2[(size_t)(k - 128) * 2048 + j]; }
  else             { if (k >= 160)            val = g2[(size_t)(k - 160) * 2048 + j]; }
  dst[i] = f2b(val);
}

// ------------------------------ LN + mix -----------------------------------

DEV void breduce2(float& a, float& b, float* rbuf) {
#pragma unroll
  for (int m = 1; m < 64; m <<= 1) { a += __shfl_xor(a, m); b += __shfl_xor(b, m); }
  const int wid = threadIdx.x >> 6, lane = threadIdx.x & 63;
  if (lane == 0) { rbuf[wid] = a; rbuf[4 + wid] = b; }
  __syncthreads();
  a = rbuf[0] + rbuf[1] + rbuf[2] + rbuf[3];
  b = rbuf[4] + rbuf[5] + rbuf[6] + rbuf[7];
  __syncthreads();
}

__global__ __launch_bounds__(256)
void k_ln1_mix(const float* __restrict__ x, const float* __restrict__ shift,
               const float* __restrict__ lw, const float* __restrict__ lb,
               const float* __restrict__ mr, const float* __restrict__ mk,
               const float* __restrict__ mv,
               unsigned short* __restrict__ A2, unsigned short* __restrict__ xrb,
               unsigned short* __restrict__ xkb, unsigned short* __restrict__ xvb) {
  __shared__ float rbuf[8];
  const int m = blockIdx.x, tid = threadIdx.x;
  const int b = m >> 10, t = m & 1023;
  const float* xt = x + (size_t)m * 2048 + tid * 8;
  const float* xp = (t > 0) ? (x + (size_t)(m - 1) * 2048 + tid * 8)
                            : (shift + (size_t)b * 2048 + tid * 8);
  float vt[8], vp[8];
  *(float4*)&vt[0] = *(const float4*)(xt);
  *(float4*)&vt[4] = *(const float4*)(xt + 4);
  *(float4*)&vp[0] = *(const float4*)(xp);
  *(float4*)&vp[4] = *(const float4*)(xp + 4);
  float st = 0.f, sp = 0.f;
#pragma unroll
  for (int i = 0; i < 8; ++i) { st += vt[i]; sp += vp[i]; }
  breduce2(st, sp, rbuf);
  const float mt_ = st * (1.f / 2048.f), mp_ = sp * (1.f / 2048.f);
  float qt = 0.f, qp = 0.f;
#pragma unroll
  for (int i = 0; i < 8; ++i) {
    float d0 = vt[i] - mt_; qt += d0 * d0;
    float d1 = vp[i] - mp_; qp += d1 * d1;
  }
  breduce2(qt, qp, rbuf);
  const float rt = rsqrtf(qt * (1.f / 2048.f) + 1e-5f);
  const float rp = rsqrtf(qp * (1.f / 2048.f) + 1e-5f);
  const bool lnp = (t > 0);
#pragma unroll
  for (int i = 0; i < 8; ++i) {
    const int c = tid * 8 + i;
    const float wv = lw[c], bv = lb[c];
    const float xn = (vt[i] - mt_) * rt * wv + bv;
    const float pn = lnp ? ((vp[i] - mp_) * rp * wv + bv) : vp[i];
    const float xx = pn - xn;
    A2[(size_t)m * 4096 + c] = f2b(xn);
    A2[(size_t)m * 4096 + 2048 + c] = f2b(xx);
    xrb[(size_t)m * 2048 + c] = f2b(xn + xx * mr[c]);
    xkb[(size_t)m * 2048 + c] = f2b(xn + xx * mk[c]);
    xvb[(size_t)m * 2048 + c] = f2b(xn + xx * mv[c]);
  }
}

__global__ __launch_bounds__(256)
void k_ln2_mix(const float* __restrict__ x1, const float* __restrict__ shift,
               const float* __restrict__ lw, const float* __restrict__ lb,
               const float* __restrict__ mk, unsigned short* __restrict__ xkf) {
  __shared__ float rbuf[8];
  const int m = blockIdx.x, tid = threadIdx.x;
  const int b = m >> 10, t = m & 1023;
  const float* xt = x1 + (size_t)m * 2048 + tid * 8;
  const float* xp = (t > 0) ? (x1 + (size_t)(m - 1) * 2048 + tid * 8)
                            : (shift + (size_t)b * 2048 + tid * 8);
  float vt[8], vp[8];
  *(float4*)&vt[0] = *(const float4*)(xt);
  *(float4*)&vt[4] = *(const float4*)(xt + 4);
  *(float4*)&vp[0] = *(const float4*)(xp);
  *(float4*)&vp[4] = *(const float4*)(xp + 4);
  float st = 0.f, sp = 0.f;
#pragma unroll
  for (int i = 0; i < 8; ++i) { st += vt[i]; sp += vp[i]; }
  breduce2(st, sp, rbuf);
  const float mt_ = st * (1.f / 2048.f), mp_ = sp * (1.f / 2048.f);
  float qt = 0.f, qp = 0.f;
#pragma unroll
  for (int i = 0; i < 8; ++i) {
    float d0 = vt[i] - mt_; qt += d0 * d0;
    float d1 = vp[i] - mp_; qp += d1 * d1;
  }
  breduce2(qt, qp, rbuf);
  const float rt = rsqrtf(qt * (1.f / 2048.f) + 1e-5f);
  const float rp = rsqrtf(qp * (1.f / 2048.f) + 1e-5f);
  const bool lnp = (t > 0);
#pragma unroll
  for (int i = 0; i < 8; ++i) {
    const int c = tid * 8 + i;
    const float wv = lw[c], bv = lb[c];
    const float xn = (vt[i] - mt_) * rt * wv + bv;
    const float pn = lnp ? ((vp[i] - mp_) * rp * wv + bv) : vp[i];
    xkf[(size_t)m * 2048 + c] = f2b(xn + (pn - xn) * mk[c]);
  }
}

// ------------------------------ epilogues ----------------------------------

constexpr int EP_F32 = 0, EP_B16 = 1, EP_RELU2 = 5, EP_ADDF = 6, EP_HACT = 7;

template <int EP>
DEV void ep_store(float acc, long row, long c, long ldc, float* Co,
                  unsigned short* Cob, const float* bias, const float* e0f,
                  const unsigned short* e0b) {
  const long idx = row * ldc + c;
  (void)bias; (void)e0b;
  if constexpr (EP == EP_F32) {
    Co[idx] = acc;
  } else if constexpr (EP == EP_B16) {
    Cob[idx] = f2b(acc);
  } else if constexpr (EP == EP_RELU2) {
    const float r = fmaxf(acc, 0.f);
    Cob[idx] = f2b(r * r);
  } else if constexpr (EP == EP_ADDF) {
    Co[idx] = acc + e0f[idx];
  } else if constexpr (EP == EP_HACT) {
    float vv = acc;
    if (c < 64) vv = tanhf(vv);                      // w path
    else if (c >= 160) vv = 1.f / (1.f + expf(-vv)); // g path
    Cob[idx] = f2b(vv);
  }
}

// ---------------- GEMM v1 (128x128 m97-style, odd shapes) ------------------

template <int EP>
__global__ __launch_bounds__(256)
void gemm_bt(const unsigned short* __restrict__ A, long lda,
             const unsigned short* __restrict__ Bt, long ldb, long N, long K,
             long ldc, float* __restrict__ Co, unsigned short* __restrict__ Cob,
             const float* __restrict__ bias, const float* __restrict__ e0f,
             const unsigned short* __restrict__ e0b) {
  __shared__ unsigned short As[4096];  // [128][32]
  __shared__ unsigned short Bs[4096];  // [128][32]
  const int tid = threadIdx.x;
  const int wid = tid >> 6, lane = tid & 63;
  const long row0 = (long)blockIdx.x * 128, col0 = (long)blockIdx.y * 128;
  const int wm = (wid >> 1) * 64, wn = (wid & 1) * 64;
  f32x4 acc[4][4] = {};
  const int sr = tid >> 2, sk = (tid & 3) * 8;
  const unsigned short* gA = A + (row0 + sr) * lda + sk;
  const unsigned short* gB = Bt + (col0 + sr) * ldb + sk;
  unsigned short* lA = As + wid * 512;
  unsigned short* lB = Bs + wid * 512;
  const int fr = lane & 15, fk = (lane >> 4) * 8;

  for (long kb = 0; kb < K; kb += 32) {
    gload16(gA + kb, lA);
    gload16(gA + kb + 64 * lda, lA + 2048);
    gload16(gB + kb, lB);
    gload16(gB + kb + 64 * ldb, lB + 2048);
    __syncthreads();
    bf16x8 af[4], bq[4];
#pragma unroll
    for (int mt = 0; mt < 4; ++mt)
      af[mt] = *(const bf16x8*)(As + (wm + mt * 16 + fr) * 32 + fk);
#pragma unroll
    for (int nt = 0; nt < 4; ++nt)
      bq[nt] = *(const bf16x8*)(Bs + (wn + nt * 16 + fr) * 32 + fk);
#pragma unroll
    for (int mt = 0; mt < 4; ++mt)
#pragma unroll
      for (int nt = 0; nt < 4; ++nt)
        acc[mt][nt] = __builtin_amdgcn_mfma_f32_16x16x32_bf16(
            af[mt], bq[nt], acc[mt][nt], 0, 0, 0);
    __syncthreads();
  }
  const int fq = lane >> 4;
#pragma unroll
  for (int mt = 0; mt < 4; ++mt) {
#pragma unroll
    for (int nt = 0; nt < 4; ++nt) {
      const long c = col0 + wn + nt * 16 + fr;
      if (c < N) {
        const long rb = row0 + wm + mt * 16 + fq * 4;
#pragma unroll
        for (int rg = 0; rg < 4; ++rg)
          ep_store<EP>(acc[mt][nt][rg], rb + rg, c, ldc, Co, Cob, bias, e0f, e0b);
      }
    }
  }
}

// ---------------- GEMM v3 (128x128, counted vmcnt, swizzled dbuf) ----------
// 256 thr = 4 waves (2x2); dbuf LDS 32KB (A,B each [128][32] bf16, 4-slot
// rows XOR-swizzled slot^=(row&3) on BOTH staged source and ds_read).
// Counted vmcnt(4): next tile's 4 gloads stay in flight across barriers.

template <int EP>
__global__ __launch_bounds__(256)
void gemm3(const unsigned short* __restrict__ A, long lda,
           const unsigned short* __restrict__ Bt, long ldb, long K, long ldc,
           float* __restrict__ Co, unsigned short* __restrict__ Cob,
           const float* __restrict__ e0f) {
  __shared__ unsigned short As[2][4096];
  __shared__ unsigned short Bs[2][4096];
  const int tid = threadIdx.x;
  const int wid = tid >> 6, lane = tid & 63;
  const long row0 = (long)blockIdx.x * 128, col0 = (long)blockIdx.y * 128;
  const int wm = (wid >> 1) * 64, wn = (wid & 1) * 64;
  f32x4 acc[4][4] = {};
  const int srow = tid >> 2;                      // 0..63
  const int scol = 8 * ((tid & 3) ^ (srow & 3));  // pre-swizzled 16B slot
  const unsigned short* gA = A + (row0 + srow) * lda + scol;
  const unsigned short* gB = Bt + (col0 + srow) * ldb + scol;
  const int fr = lane & 15, fc = lane >> 4;

#define STAGE3(buf, kb)                                         \
  {                                                             \
    gload16(gA + (kb), &As[buf][0] + wid * 512);                \
    gload16(gA + (kb) + 64 * lda, &As[buf][2048] + wid * 512);  \
    gload16(gB + (kb), &Bs[buf][0] + wid * 512);                \
    gload16(gB + (kb) + 64 * ldb, &Bs[buf][2048] + wid * 512);  \
  }

  STAGE3(0, 0)
  const int NT = (int)(K >> 5);
  int cur = 0;
  for (int kt = 0; kt < NT; ++kt) {
    if (kt + 1 < NT) {
      STAGE3(cur ^ 1, (long)(kt + 1) * 32)
      asm volatile("s_waitcnt vmcnt(4)" ::: "memory");
    } else {
      asm volatile("s_waitcnt vmcnt(0)" ::: "memory");
    }
    __builtin_amdgcn_s_barrier();
    asm volatile("" ::: "memory");
    bf16x8 af[4], bq[4];
#pragma unroll
    for (int mt = 0; mt < 4; ++mt) {
      const int r = wm + mt * 16 + fr;
      af[mt] = *(const bf16x8*)(&As[cur][0] + r * 32 + ((fc ^ (r & 3)) * 8));
    }
#pragma unroll
    for (int nt = 0; nt < 4; ++nt) {
      const int r = wn + nt * 16 + fr;
      bq[nt] = *(const bf16x8*)(&Bs[cur][0] + r * 32 + ((fc ^ (r & 3)) * 8));
    }
    __builtin_amdgcn_s_setprio(1);
#pragma unroll
    for (int mt = 0; mt < 4; ++mt)
#pragma unroll
      for (int nt = 0; nt < 4; ++nt)
        acc[mt][nt] = __builtin_amdgcn_mfma_f32_16x16x32_bf16(
            af[mt], bq[nt], acc[mt][nt], 0, 0, 0);
    __builtin_amdgcn_s_setprio(0);
    asm volatile("" ::: "memory");
    __builtin_amdgcn_s_barrier();
    cur ^= 1;
  }
#undef STAGE3
  const int fq = lane >> 4;
#pragma unroll
  for (int mt = 0; mt < 4; ++mt) {
#pragma unroll
    for (int nt = 0; nt < 4; ++nt) {
      const long c = col0 + wn + nt * 16 + fr;
      const long rb = row0 + wm + mt * 16 + fq * 4;
#pragma unroll
      for (int rg = 0; rg < 4; ++rg)
        ep_store<EP>(acc[mt][nt][rg], rb + rg, c, ldc, Co, Cob, nullptr, e0f,
                     nullptr);
    }
  }
}

// ---------------- gemm_up128: Hact[4096][288] @ Wup^T[8192][288] -----------
// gemm3 body; path p = blockIdx.y>>4 block-uniform (BN=128 divides 2048).

__global__ __launch_bounds__(256)
void gemm_up128(const unsigned short* __restrict__ A,
                const unsigned short* __restrict__ Bt,
                float* __restrict__ whb, unsigned short* __restrict__ abuf,
                unsigned short* __restrict__ vfb, unsigned short* __restrict__ gbuf,
                const float* __restrict__ w0, const float* __restrict__ a0,
                const float* __restrict__ v0,
                const unsigned short* __restrict__ vraw,
                const float* __restrict__ vfirst) {
  __shared__ unsigned short As[2][4096];
  __shared__ unsigned short Bs[2][4096];
  const int tid = threadIdx.x;
  const int wid = tid >> 6, lane = tid & 63;
  const long row0 = (long)blockIdx.x * 128, col0 = (long)blockIdx.y * 128;
  const int wm = (wid >> 1) * 64, wn = (wid & 1) * 64;
  f32x4 acc[4][4] = {};
  const int srow = tid >> 2;
  const int scol = 8 * ((tid & 3) ^ (srow & 3));
  const unsigned short* gA = A + (row0 + srow) * 288 + scol;
  const unsigned short* gB = Bt + (col0 + srow) * 288 + scol;
  const int fr = lane & 15, fc = lane >> 4;

#define STAGEU(buf, kb)                                         \
  {                                                             \
    gload16(gA + (kb), &As[buf][0] + wid * 512);                \
    gload16(gA + (kb) + 64 * 288, &As[buf][2048] + wid * 512);  \
    gload16(gB + (kb), &Bs[buf][0] + wid * 512);                \
    gload16(gB + (kb) + 64 * 288, &Bs[buf][2048] + wid * 512);  \
  }

  STAGEU(0, 0)
  int cur = 0;
  for (int kt = 0; kt < 9; ++kt) {
    if (kt + 1 < 9) {
      STAGEU(cur ^ 1, (long)(kt + 1) * 32)
      asm volatile("s_waitcnt vmcnt(4)" ::: "memory");
    } else {
      asm volatile("s_waitcnt vmcnt(0)" ::: "memory");
    }
    __builtin_amdgcn_s_barrier();
    asm volatile("" ::: "memory");
    bf16x8 af[4], bq[4];
#pragma unroll
    for (int mt = 0; mt < 4; ++mt) {
      const int r = wm + mt * 16 + fr;
      af[mt] = *(const bf16x8*)(&As[cur][0] + r * 32 + ((fc ^ (r & 3)) * 8));
    }
#pragma unroll
    for (int nt = 0; nt < 4; ++nt) {
      const int r = wn + nt * 16 + fr;
      bq[nt] = *(const bf16x8*)(&Bs[cur][0] + r * 32 + ((fc ^ (r & 3)) * 8));
    }
    __builtin_amdgcn_s_setprio(1);
#pragma unroll
    for (int mt = 0; mt < 4; ++mt)
#pragma unroll
      for (int nt = 0; nt < 4; ++nt)
        acc[mt][nt] = __builtin_amdgcn_mfma_f32_16x16x32_bf16(
            af[mt], bq[nt], acc[mt][nt], 0, 0, 0);
    __builtin_amdgcn_s_setprio(0);
    asm volatile("" ::: "memory");
    __builtin_amdgcn_s_barrier();
    cur ^= 1;
  }
#undef STAGEU
  const int fq = lane >> 4;
  const int p = (int)(blockIdx.y >> 4);
#pragma unroll
  for (int mt = 0; mt < 4; ++mt) {
#pragma unroll
    for (int nt = 0; nt < 4; ++nt) {
      const long c = col0 + wn + nt * 16 + fr;
      const long cc = c & 2047;
      const long rb = row0 + wm + mt * 16 + fq * 4;
#pragma unroll
      for (int rg = 0; rg < 4; ++rg) {
        const float av = acc[mt][nt][rg];
        const long idx = (rb + rg) * 2048 + cc;
        if (p == 0) {
          const float wv = w0[cc] + av;
          const float sp = log1pf(expf(-wv));
          whb[idx] = expf(-expf(-sp - 0.5f));
        } else if (p == 1) {
          abuf[idx] = f2b(1.f / (1.f + expf(-(a0[cc] + av))));
        } else if (p == 2) {
          const float s = 1.f / (1.f + expf(-(v0[cc] + av)));
          const float vv = b2f(vraw[idx]);
          vfb[idx] = f2b(vv + (vfirst[idx] - vv) * s);
        } else {
          gbuf[idx] = f2b(av);  // g = sigmoid(xg@g1) @ g2 -- NO outer act
        }
      }
    }
  }
}

// ------------------------------ k_post -------------------------------------
__global__ __launch_bounds__(256)
void k_post(unsigned short* __restrict__ kio, unsigned short* __restrict__ abio,
            unsigned short* __restrict__ aao, const float* __restrict__ kkw,
            const float* __restrict__ kaw) {
  const int m = blockIdx.x, tid = threadIdx.x;
  const size_t base = (size_t)m * 2048 + tid * 8;
  us8 k8 = *(const us8*)(kio + base);
  us8 a8 = *(const us8*)(abio + base);
  float kk8[8], ka8[8];
  *(float4*)&kk8[0] = *(const float4*)(kkw + tid * 8);
  *(float4*)&kk8[4] = *(const float4*)(kkw + tid * 8 + 4);
  *(float4*)&ka8[0] = *(const float4*)(kaw + tid * 8);
  *(float4*)&ka8[4] = *(const float4*)(kaw + tid * 8 + 4);
  float kx[8], kv[8], av[8];
  float ss = 0.f;
#pragma unroll
  for (int i = 0; i < 8; ++i) {
    kv[i] = b2f(k8[i]); av[i] = b2f(a8[i]);
    kx[i] = kv[i] * kk8[i]; ss += kx[i] * kx[i];
  }
  ss = red8(ss);
  const float inv = 1.f / fmaxf(sqrtf(ss), 1e-12f);
  us8 kh8, aa8, bb8;
#pragma unroll
  for (int i = 0; i < 8; ++i) {
    const float kkn = kx[i] * inv;
    kh8[i] = f2b(kv[i] * (1.f + (av[i] - 1.f) * ka8[i]));
    aa8[i] = f2b(-kkn);
    bb8[i] = f2b(kkn * av[i]);
  }
  *(us8*)(kio + base) = kh8;
  *(us8*)(aao + base) = aa8;
  *(us8*)(abio + base) = bb8;
}

// ------------------------------ WKV scan (R11) ------------------------------

DEV float red16(float x) {  // all-lanes sum within each 16-lane row
  union { float f; int i; } a, r;
  a.f = x; r.i = __builtin_amdgcn_update_dpp(0, a.i, 0xB1, 0xf, 0xf, true);
  x += r.f;
  a.f = x; r.i = __builtin_amdgcn_update_dpp(0, a.i, 0x4E, 0xf, 0xf, true);
  x += r.f;
  a.f = x; r.i = __builtin_amdgcn_update_dpp(0, a.i, 0x124, 0xf, 0xf, true);
  x += r.f;
  a.f = x; r.i = __builtin_amdgcn_update_dpp(0, a.i, 0x128, 0xf, 0xf, true);
  x += r.f;
  return x;
}

DEV void cv4(const uint2 q, float* o) {
  union { unsigned u; float f; } t;
  t.u = q.x << 16;          o[0] = t.f;
  t.u = q.x & 0xffff0000u;  o[1] = t.f;
  t.u = q.y << 16;          o[2] = t.f;
  t.u = q.y & 0xffff0000u;  o[3] = t.f;
}

__global__ __launch_bounds__(64)
void k_scan(const unsigned short* __restrict__ rp,
            const unsigned short* __restrict__ kp,
            const unsigned short* __restrict__ vp,
            const float* __restrict__ wp,
            const unsigned short* __restrict__ ap,
            const unsigned short* __restrict__ bp,
            const float* __restrict__ s0, unsigned short* __restrict__ yout,
            float* __restrict__ snew) {
  __shared__ float4 slots[8][49];
  __shared__ unsigned short ylds[1024][4];
  const int lane = threadIdx.x;
  const int bh = blockIdx.x & 127;
  const int rq = blockIdx.x >> 7;
  const int b = bh >> 5, h = bh & 31;
  const int kg = lane & 15, rl = lane >> 4;
  const int v = rq * 4 + rl, ks = kg * 4;
  const size_t off_bh = (size_t)b * 1024 * 2048 + (size_t)h * 64;
  const int vfo = 768 + ((rq & 1) * 4 + rl) * 2;

  float S[4];
  *(float4*)&S[0] = *(const float4*)(s0 + (((size_t)bh * 64 + v) * 64 + ks));

  const char* gp = nullptr;
  size_t gstep = 0;
  if (lane < 49) {
    if (lane < 32) {
      const int arr = lane >> 3, sub = lane & 7;
      const unsigned short* base = arr == 0 ? rp : arr == 1 ? kp
                                 : arr == 2 ? ap : bp;
      gp = (const char*)(base + off_bh + sub * 8);
      gstep = 4096;
    } else if (lane < 48) {
      gp = (const char*)(wp + off_bh + (lane - 32) * 4);
      gstep = 8192;
    } else {
      gp = (const char*)(vp + off_bh + (rq & ~1) * 4);
      gstep = 4096;
    }
  }
#pragma unroll
  for (int s = 0; s < 8; ++s) {
    if (lane < 49) gload16(gp, &slots[s][0]);
    gp += gstep;
  }

  uint2 rA, kA, aA, bA, rB, kB, aB, bB;
  float4 wA, wB;
  unsigned short fA, fB;
  asm volatile("s_waitcnt vmcnt(7)" ::: "memory");
  {
    const char* nb = (const char*)&slots[0][0];
    rA = *(const uint2*)(nb + kg * 8);
    kA = *(const uint2*)(nb + 128 + kg * 8);
    aA = *(const uint2*)(nb + 256 + kg * 8);
    bA = *(const uint2*)(nb + 384 + kg * 8);
    wA = *(const float4*)(nb + 512 + kg * 16);
    fA = *(const unsigned short*)(nb + vfo);
  }

#define SSTEP(T, Cr, Ck, Ca, Cb, Cw, Cf, Nr, Nk, Na, Nb, Nw, Nf)             \
  {                                                                          \
    asm volatile("s_waitcnt lgkmcnt(0)" ::: "memory");                       \
    if (lane < 49) gload16(gp, &slots[(T) & 7][0]);                          \
    if ((T) < 1015) gp += gstep;                                             \
    asm volatile("s_waitcnt vmcnt(7)" ::: "memory");                         \
    const char* nb = (const char*)&slots[((T) + 1) & 7][0];                  \
    Nr = *(const uint2*)(nb + kg * 8);                                       \
    Nk = *(const uint2*)(nb + 128 + kg * 8);                                 \
    Na = *(const uint2*)(nb + 256 + kg * 8);                                 \
    Nb = *(const uint2*)(nb + 384 + kg * 8);                                 \
    Nw = *(const float4*)(nb + 512 + kg * 16);                               \
    Nf = *(const unsigned short*)(nb + vfo);                                 \
    float rr[4], kk[4], av[4], bv[4];                                        \
    cv4(Cr, rr); cv4(Ck, kk); cv4(Ca, av); cv4(Cb, bv);                      \
    const float vv = b2f(Cf);                                                \
    float sa = S[0] * av[0] + S[1] * av[1] + S[2] * av[2] + S[3] * av[3];    \
    sa = red16(sa);                                                          \
    float y;                                                                 \
    S[0] = S[0] * Cw.x + sa * bv[0] + vv * kk[0]; y  = S[0] * rr[0];         \
    S[1] = S[1] * Cw.y + sa * bv[1] + vv * kk[1]; y += S[1] * rr[1];         \
    S[2] = S[2] * Cw.z + sa * bv[2] + vv * kk[2]; y += S[2] * rr[2];         \
    S[3] = S[3] * Cw.w + sa * bv[3] + vv * kk[3]; y += S[3] * rr[3];         \
    y = red16(y);                                                            \
    if (kg == 0) ylds[T][rl] = f2b(y);                                       \
  }

  for (int tb = 0; tb < 1024; tb += 2) {
    SSTEP(tb + 0, rA, kA, aA, bA, wA, fA, rB, kB, aB, bB, wB, fB)
    SSTEP(tb + 1, rB, kB, aB, bB, wB, fB, rA, kA, aA, bA, wA, fA)
  }
#undef SSTEP

  *(float4*)(snew + (((size_t)bh * 64 + v) * 64 + ks)) = *(const float4*)&S[0];
  asm volatile("s_waitcnt lgkmcnt(0)" ::: "memory");
#pragma unroll 4
  for (int it = 0; it < 16; ++it) {
    const int t = lane + it * 64;
    const uint2 val = *(const uint2*)&ylds[t][0];
    *(uint2*)(yout + off_bh + (size_t)t * 2048 + rq * 4) = val;
  }
}

// ---------------------- GroupNorm + resid + gate ---------------------------

__global__ __launch_bounds__(256)
void k_gn(const unsigned short* __restrict__ y, const unsigned short* __restrict__ r,
          const unsigned short* __restrict__ kh, const unsigned short* __restrict__ vf,
          const unsigned short* __restrict__ g, const float* __restrict__ rk,
          const float* __restrict__ lw, const float* __restrict__ lb,
          unsigned short* __restrict__ ywg) {
  const int m = blockIdx.x, tid = threadIdx.x;
  const size_t base = (size_t)m * 2048 + tid * 8;
  us8 y8 = *(const us8*)(y + base);
  us8 r8 = *(const us8*)(r + base);
  us8 k8 = *(const us8*)(kh + base);
  us8 v8 = *(const us8*)(vf + base);
  us8 g8 = *(const us8*)(g + base);
  float yv[8];
  float rkv[8];
  *(float4*)&rkv[0] = *(const float4*)(rk + tid * 8);
  *(float4*)&rkv[4] = *(const float4*)(rk + tid * 8 + 4);
  float sy = 0.f, sd = 0.f;
#pragma unroll
  for (int i = 0; i < 8; ++i) {
    yv[i] = b2f(y8[i]);
    sy += yv[i];
    sd += b2f(r8[i]) * b2f(k8[i]) * rkv[i];
  }
  sy = red8(sy);
  sd = red8(sd);
  const float mu = sy * (1.f / 64.f);
  float sq = 0.f;
#pragma unroll
  for (int i = 0; i < 8; ++i) { const float d = yv[i] - mu; sq += d * d; }
  sq = red8(sq);
  const float rstd = rsqrtf(sq * (1.f / 64.f) + 64e-5f);
  us8 o8;
#pragma unroll
  for (int i = 0; i < 8; ++i) {
    const int c = tid * 8 + i;
    const float gn = (yv[i] - mu) * rstd * lw[c] + lb[c];
    o8[i] = f2b((gn + sd * b2f(v8[i])) * b2f(g8[i]));
  }
  *(us8*)(ywg + base) = o8;
}

// ------------------------------ launch -------------------------------------

extern "C" void kernel_launch(void* const* d_in, const int* in_sizes, int n_in,
                              void* d_out, int out_size, void* d_ws,
                              size_t ws_size, hipStream_t stream) {
  (void)in_sizes; (void)n_in; (void)out_size; (void)ws_size;
  const float* x         = (const float*)d_in[0];
  const float* v_first   = (const float*)d_in[1];
  const float* att_shift = (const float*)d_in[2];
  const float* ffn_shift = (const float*)d_in[3];
  const float* wkv0      = (const float*)d_in[4];
  const float* ln1w = (const float*)d_in[5];
  const float* ln1b = (const float*)d_in[6];
  const float* ln2w = (const float*)d_in[7];
  const float* ln2b = (const float*)d_in[8];
  const float* x_r = (const float*)d_in[9];
  const float* x_w = (const float*)d_in[10];
  const float* x_k = (const float*)d_in[11];
  const float* x_v = (const float*)d_in[12];
  const float* x_a = (const float*)d_in[13];
  const float* x_g = (const float*)d_in[14];
  const float* Wr = (const float*)d_in[15];
  const float* Wk = (const float*)d_in[16];
  const float* Wv = (const float*)d_in[17];
  const float* Wo = (const float*)d_in[18];
  const float* w0 = (const float*)d_in[19];
  const float* w1 = (const float*)d_in[20];
  const float* w2 = (const float*)d_in[21];
  const float* v0 = (const float*)d_in[22];
  const float* v1 = (const float*)d_in[23];
  const float* v2 = (const float*)d_in[24];
  const float* a0 = (const float*)d_in[25];
  const float* a1 = (const float*)d_in[26];
  const float* a2 = (const float*)d_in[27];
  const float* g1 = (const float*)d_in[28];
  const float* g2 = (const float*)d_in[29];
  const float* k_k = (const float*)d_in[30];
  const float* k_a = (const float*)d_in[31];
  const float* r_k = (const float*)d_in[32];
  const float* lnxw = (const float*)d_in[33];
  const float* lnxb = (const float*)d_in[34];
  const float* ffn_xk = (const float*)d_in[35];
  const float* Wkf = (const float*)d_in[36];
  const float* Wvf = (const float*)d_in[37];

  char* ws = (char*)d_ws;
  constexpr size_t OFF_TWR   = 0;
  constexpr size_t OFF_TWK   = 8388608;
  constexpr size_t OFF_TWV   = 16777216;
  constexpr size_t OFF_TWO   = 25165824;
  constexpr size_t OFF_TWCAT = 34734080;
  constexpr size_t OFF_HACT  = 37879808;
  constexpr size_t OFF_GBUF  = 40239104;
  constexpr size_t OFF_WH    = 57016320;
  constexpr size_t OFF_R     = 90570752;
  constexpr size_t OFF_KH    = 107347968;
  constexpr size_t OFF_VF    = 124125184;
  constexpr size_t OFF_AA    = 140902400;
  constexpr size_t OFF_BB    = 157679616;
  constexpr size_t OFF_TWUP  = 174456832;  // [8192][288] bf16, 4.7MB

  unsigned short* tWr = (unsigned short*)(ws + OFF_TWR);
  unsigned short* tWk = (unsigned short*)(ws + OFF_TWK);
  unsigned short* tWv = (unsigned short*)(ws + OFF_TWV);
  unsigned short* tWo = (unsigned short*)(ws + OFF_TWO);
  unsigned short* tWcat = (unsigned short*)(ws + OFF_TWCAT);
  unsigned short* Hact  = (unsigned short*)(ws + OFF_HACT);
  unsigned short* gbuf  = (unsigned short*)(ws + OFF_GBUF);
  unsigned short* tWvfh = (unsigned short*)(ws + OFF_GBUF);
  unsigned short* act2  = (unsigned short*)(ws + OFF_WH);
  float*          whb   = (float*)(ws + OFF_WH);
  unsigned short* ywg   = (unsigned short*)(ws + OFF_WH);
  unsigned short* kf    = (unsigned short*)(ws + OFF_WH);
  unsigned short* bxr   = (unsigned short*)(ws + OFF_AA);
  unsigned short* bxk   = (unsigned short*)(ws + OFF_BB);
  unsigned short* bxv   = (unsigned short*)(ws + OFF_VF);
  unsigned short* rbuf  = (unsigned short*)(ws + OFF_R);
  unsigned short* khb   = (unsigned short*)(ws + OFF_KH);
  unsigned short* vfb   = (unsigned short*)(ws + OFF_VF);
  unsigned short* aab   = (unsigned short*)(ws + OFF_AA);
  unsigned short* bbb   = (unsigned short*)(ws + OFF_BB);
  unsigned short* vraw  = (unsigned short*)(ws + OFF_AA);
  unsigned short* abuf  = (unsigned short*)(ws + OFF_BB);
  float*          x1    = (float*)(ws + OFF_R);
  unsigned short* xkf   = (unsigned short*)(ws + OFF_VF);
  unsigned short* tWkf  = (unsigned short*)(ws + OFF_AA);
  unsigned short* tWup  = (unsigned short*)(ws + OFF_TWUP);
  float* out = (float*)d_out;
  float* snew = out + 8388608;

  const dim3 tb(32, 8);
  // ---- weight prep ----
  k_transpose<<<dim3(64, 64), tb, 0, stream>>>(Wr, tWr, 2048, 2048);
  k_transpose<<<dim3(64, 64), tb, 0, stream>>>(Wk, tWk, 2048, 2048);
  k_transpose<<<dim3(64, 64), tb, 0, stream>>>(Wv, tWv, 2048, 2048);
  k_transpose<<<dim3(64, 64), tb, 0, stream>>>(Wo, tWo, 2048, 2048);
  k_wcat<<<6144, 256, 0, stream>>>(w1, a1, v1, g1, x_w, x_a, x_v, x_g, tWcat);
  k_wup<<<9216, 256, 0, stream>>>(w2, a2, v2, g2, tWup);

  // ---- TimeMix front ----
  k_ln1_mix<<<4096, 256, 0, stream>>>(x, att_shift, ln1w, ln1b, x_r, x_k, x_v,
                                      act2, bxr, bxk, bxv);
  gemm3<EP_B16><<<dim3(32, 16), 256, 0, stream>>>(
      bxr, 2048, tWr, 2048, 2048, 2048, nullptr, rbuf, nullptr);
  gemm3<EP_B16><<<dim3(32, 16), 256, 0, stream>>>(
      bxk, 2048, tWk, 2048, 2048, 2048, nullptr, khb, nullptr);
  gemm3<EP_B16><<<dim3(32, 16), 256, 0, stream>>>(
      bxv, 2048, tWv, 2048, 2048, 2048, nullptr, vraw, nullptr);
  gemm_bt<EP_HACT><<<dim3(32, 3), 256, 0, stream>>>(
      act2, 4096, tWcat, 4096, 288, 4096, 288, nullptr, Hact, nullptr, nullptr, nullptr);
  gemm_up128<<<dim3(32, 64), 256, 0, stream>>>(
      Hact, tWup, whb, abuf, vfb, gbuf, w0, a0, v0, vraw, v_first);
  k_post<<<4096, 256, 0, stream>>>(khb, abuf, aab, k_k, k_a);

  // ---- WKV scan ----
  k_scan<<<2048, 64, 0, stream>>>(rbuf, khb, vfb, whb, aab, bbb, wkv0,
                                  (unsigned short*)out, snew);
  k_gn<<<4096, 256, 0, stream>>>((const unsigned short*)out, rbuf, khb, vfb,
                                 gbuf, r_k, lnxw, lnxb, ywg);

  // ---- Wo projection (+x) -> x1 ----
  gemm3<EP_ADDF><<<dim3(32, 16), 256, 0, stream>>>(
      ywg, 2048, tWo, 2048, 2048, 2048, x1, nullptr, x);

  // ---- ChannelMix (two DFF halves) ----
  k_ln2_mix<<<4096, 256, 0, stream>>>(x1, ffn_shift, ln2w, ln2b, ffn_xk, xkf);
  k_transpose<<<dim3(256, 64), tb, 0, stream>>>(Wkf, tWkf, 2048, 8192);
  gemm3<EP_RELU2><<<dim3(32, 32), 256, 0, stream>>>(
      xkf, 2048, tWkf, 2048, 2048, 4096, nullptr, kf, nullptr);
  k_transpose<<<dim3(64, 128), tb, 0, stream>>>(Wvf, tWvfh, 4096, 2048);
  gemm3<EP_ADDF><<<dim3(32, 16), 256, 0, stream>>>(
      kf, 4096, tWvfh, 4096, 4096, 2048, out, nullptr, x1);
  gemm3<EP_RELU2><<<dim3(32, 32), 256, 0, stream>>>(
      xkf, 2048, tWkf + (size_t)4096 * 2048, 2048, 2048, 4096, nullptr, kf, nullptr);
  k_transpose<<<dim3(64, 128), tb, 0, stream>>>(Wvf + (size_t)4096 * 2048, tWvfh,
                                                4096, 2048);
  gemm3<EP_ADDF><<<dim3(32, 16), 256, 0, stream>>>(
      kf, 4096, tWvfh, 4096, 4096, 2048, out, nullptr, out);
}

// Round 14
// 1276.499 us; speedup vs baseline: 1.0180x; 1.0078x over previous
//
#include <hip/hip_runtime.h>
#include <cstdint>

// ---------------------------------------------------------------------------
// RWKV7 block (B=4,T=1024,C=2048,H=32,N=64,DFF=8192) for MI355X gfx950.
// R14: 8-phase 256x256 GEMM (gemm8p, T3+T4 counted-vmcnt schedule, st-swizzle)
//      for the two FFN-up GEMMs (grid 256 = 1 block/CU). Rest = R13.
// ---------------------------------------------------------------------------

typedef __attribute__((ext_vector_type(4))) float f32x4;
typedef __attribute__((ext_vector_type(8))) __bf16 bf16x8;
typedef __attribute__((ext_vector_type(8))) unsigned short us8;

#define DEV __device__ __forceinline__

DEV unsigned short f2b(float f) {
  union { float f; unsigned u; } v; v.f = f;
  unsigned r = v.u + 0x7fffu + ((v.u >> 16) & 1u);
  return (unsigned short)(r >> 16);
}
DEV float b2f(unsigned short u) {
  union { unsigned u; float f; } v; v.u = (unsigned)u << 16;
  return v.f;
}

DEV void gload16(const void* g, void* l) {
  void* gg = const_cast<void*>(g);
  __builtin_amdgcn_global_load_lds(
      (__attribute__((address_space(1))) unsigned int*)gg,
      (__attribute__((address_space(3))) unsigned int*)l, 16, 0, 0);
}

DEV float red8(float v) {  // sum over aligned 8-lane group
  v += __shfl_xor(v, 1);
  v += __shfl_xor(v, 2);
  v += __shfl_xor(v, 4);
  return v;
}

// ------------------------------ weight prep --------------------------------

__global__ void k_transpose(const float* __restrict__ src,
                            unsigned short* __restrict__ dst, int R, int Cc) {
  __shared__ float tile[32][33];
  const int c0 = blockIdx.x * 32, r0 = blockIdx.y * 32;
  const int tx = threadIdx.x, ty = threadIdx.y;  // block (32,8)
  for (int i = ty; i < 32; i += 8)
    tile[i][tx] = src[(size_t)(r0 + i) * Cc + c0 + tx];
  __syncthreads();
  for (int i = ty; i < 32; i += 8)
    dst[(size_t)(c0 + i) * R + r0 + tx] = f2b(tile[tx][i]);
}

// Wcat^T [384][4096]
__global__ void k_wcat(const float* __restrict__ w1, const float* __restrict__ a1,
                       const float* __restrict__ v1, const float* __restrict__ g1,
                       const float* __restrict__ xw, const float* __restrict__ xa,
                       const float* __restrict__ xv, const float* __restrict__ xg,
                       unsigned short* __restrict__ dst) {
  const int i = blockIdx.x * 256 + threadIdx.x;
  if (i >= 384 * 4096) return;
  const int j = i >> 12, c = i & 4095;
  float val = 0.f;
  if (j < 288) {
    const float* W; const float* mix; int jj, D;
    if (j < 64)       { W = w1; mix = xw; jj = j;       D = 64;  }
    else if (j < 128) { W = a1; mix = xa; jj = j - 64;  D = 64;  }
    else if (j < 160) { W = v1; mix = xv; jj = j - 128; D = 32;  }
    else              { W = g1; mix = xg; jj = j - 160; D = 128; }
    const int cc = c & 2047;
    val = W[(size_t)cc * D + jj];
    if (c >= 2048) val *= mix[cc];
  }
  dst[i] = f2b(val);
}

// Wup^T [8192][288] block-diagonal
__global__ void k_wup(const float* __restrict__ w2, const float* __restrict__ a2,
                      const float* __restrict__ v2, const float* __restrict__ g2,
                      unsigned short* __restrict__ dst) {
  const int i = blockIdx.x * 256 + threadIdx.x;
  if (i >= 8192 * 288) return;
  const int n = i / 288, k = i - n * 288;
  const int p = n >> 11, j = n & 2047;
  float val = 0.f;
  if (p == 0)      { if (k < 64)              val = w2[(size_t)k * 2048 + j]; }
  else if (p == 1) { if (k >= 64 && k < 128)  val = a2[(size_t)(k - 64) * 2048 + j]; }
  else if (p == 2) { if (k >= 128 && k < 160) val = v2[(size_t)(k - 128) * 2048 + j]; }
  else             { if (k >= 160)            val = g2[(size_t)(k - 160) * 2048 + j]; }
  dst[i] = f2b(val);
}

// ------------------------------ LN + mix -----------------------------------

DEV void breduce2(float& a, float& b, float* rbuf) {
#pragma unroll
  for (int m = 1; m < 64; m <<= 1) { a += __shfl_xor(a, m); b += __shfl_xor(b, m); }
  const int wid = threadIdx.x >> 6, lane = threadIdx.x & 63;
  if (lane == 0) { rbuf[wid] = a; rbuf[4 + wid] = b; }
  __syncthreads();
  a = rbuf[0] + rbuf[1] + rbuf[2] + rbuf[3];
  b = rbuf[4] + rbuf[5] + rbuf[6] + rbuf[7];
  __syncthreads();
}

__global__ __launch_bounds__(256)
void k_ln1_mix(const float* __restrict__ x, const float* __restrict__ shift,
               const float* __restrict__ lw, const float* __restrict__ lb,
               const float* __restrict__ mr, const float* __restrict__ mk,
               const float* __restrict__ mv,
               unsigned short* __restrict__ A2, unsigned short* __restrict__ xrb,
               unsigned short* __restrict__ xkb, unsigned short* __restrict__ xvb) {
  __shared__ float rbuf[8];
  const int m = blockIdx.x, tid = threadIdx.x;
  const int b = m >> 10, t = m & 1023;
  const float* xt = x + (size_t)m * 2048 + tid * 8;
  const float* xp = (t > 0) ? (x + (size_t)(m - 1) * 2048 + tid * 8)
                            : (shift + (size_t)b * 2048 + tid * 8);
  float vt[8], vp[8];
  *(float4*)&vt[0] = *(const float4*)(xt);
  *(float4*)&vt[4] = *(const float4*)(xt + 4);
  *(float4*)&vp[0] = *(const float4*)(xp);
  *(float4*)&vp[4] = *(const float4*)(xp + 4);
  float st = 0.f, sp = 0.f;
#pragma unroll
  for (int i = 0; i < 8; ++i) { st += vt[i]; sp += vp[i]; }
  breduce2(st, sp, rbuf);
  const float mt_ = st * (1.f / 2048.f), mp_ = sp * (1.f / 2048.f);
  float qt = 0.f, qp = 0.f;
#pragma unroll
  for (int i = 0; i < 8; ++i) {
    float d0 = vt[i] - mt_; qt += d0 * d0;
    float d1 = vp[i] - mp_; qp += d1 * d1;
  }
  breduce2(qt, qp, rbuf);
  const float rt = rsqrtf(qt * (1.f / 2048.f) + 1e-5f);
  const float rp = rsqrtf(qp * (1.f / 2048.f) + 1e-5f);
  const bool lnp = (t > 0);
#pragma unroll
  for (int i = 0; i < 8; ++i) {
    const int c = tid * 8 + i;
    const float wv = lw[c], bv = lb[c];
    const float xn = (vt[i] - mt_) * rt * wv + bv;
    const float pn = lnp ? ((vp[i] - mp_) * rp * wv + bv) : vp[i];
    const float xx = pn - xn;
    A2[(size_t)m * 4096 + c] = f2b(xn);
    A2[(size_t)m * 4096 + 2048 + c] = f2b(xx);
    xrb[(size_t)m * 2048 + c] = f2b(xn + xx * mr[c]);
    xkb[(size_t)m * 2048 + c] = f2b(xn + xx * mk[c]);
    xvb[(size_t)m * 2048 + c] = f2b(xn + xx * mv[c]);
  }
}

__global__ __launch_bounds__(256)
void k_ln2_mix(const float* __restrict__ x1, const float* __restrict__ shift,
               const float* __restrict__ lw, const float* __restrict__ lb,
               const float* __restrict__ mk, unsigned short* __restrict__ xkf) {
  __shared__ float rbuf[8];
  const int m = blockIdx.x, tid = threadIdx.x;
  const int b = m >> 10, t = m & 1023;
  const float* xt = x1 + (size_t)m * 2048 + tid * 8;
  const float* xp = (t > 0) ? (x1 + (size_t)(m - 1) * 2048 + tid * 8)
                            : (shift + (size_t)b * 2048 + tid * 8);
  float vt[8], vp[8];
  *(float4*)&vt[0] = *(const float4*)(xt);
  *(float4*)&vt[4] = *(const float4*)(xt + 4);
  *(float4*)&vp[0] = *(const float4*)(xp);
  *(float4*)&vp[4] = *(const float4*)(xp + 4);
  float st = 0.f, sp = 0.f;
#pragma unroll
  for (int i = 0; i < 8; ++i) { st += vt[i]; sp += vp[i]; }
  breduce2(st, sp, rbuf);
  const float mt_ = st * (1.f / 2048.f), mp_ = sp * (1.f / 2048.f);
  float qt = 0.f, qp = 0.f;
#pragma unroll
  for (int i = 0; i < 8; ++i) {
    float d0 = vt[i] - mt_; qt += d0 * d0;
    float d1 = vp[i] - mp_; qp += d1 * d1;
  }
  breduce2(qt, qp, rbuf);
  const float rt = rsqrtf(qt * (1.f / 2048.f) + 1e-5f);
  const float rp = rsqrtf(qp * (1.f / 2048.f) + 1e-5f);
  const bool lnp = (t > 0);
#pragma unroll
  for (int i = 0; i < 8; ++i) {
    const int c = tid * 8 + i;
    const float wv = lw[c], bv = lb[c];
    const float xn = (vt[i] - mt_) * rt * wv + bv;
    const float pn = lnp ? ((vp[i] - mp_) * rp * wv + bv) : vp[i];
    xkf[(size_t)m * 2048 + c] = f2b(xn + (pn - xn) * mk[c]);
  }
}

// ------------------------------ epilogues ----------------------------------

constexpr int EP_F32 = 0, EP_B16 = 1, EP_RELU2 = 5, EP_ADDF = 6, EP_HACT = 7;

template <int EP>
DEV void ep_store(float acc, long row, long c, long ldc, float* Co,
                  unsigned short* Cob, const float* bias, const float* e0f,
                  const unsigned short* e0b) {
  const long idx = row * ldc + c;
  (void)bias; (void)e0b;
  if constexpr (EP == EP_F32) {
    Co[idx] = acc;
  } else if constexpr (EP == EP_B16) {
    Cob[idx] = f2b(acc);
  } else if constexpr (EP == EP_RELU2) {
    const float r = fmaxf(acc, 0.f);
    Cob[idx] = f2b(r * r);
  } else if constexpr (EP == EP_ADDF) {
    Co[idx] = acc + e0f[idx];
  } else if constexpr (EP == EP_HACT) {
    float vv = acc;
    if (c < 64) vv = tanhf(vv);                      // w path
    else if (c >= 160) vv = 1.f / (1.f + expf(-vv)); // g path
    Cob[idx] = f2b(vv);
  }
}

// ---------------- GEMM v1 (128x128 m97-style, odd shapes) ------------------

template <int EP>
__global__ __launch_bounds__(256)
void gemm_bt(const unsigned short* __restrict__ A, long lda,
             const unsigned short* __restrict__ Bt, long ldb, long N, long K,
             long ldc, float* __restrict__ Co, unsigned short* __restrict__ Cob,
             const float* __restrict__ bias, const float* __restrict__ e0f,
             const unsigned short* __restrict__ e0b) {
  __shared__ unsigned short As[4096];
  __shared__ unsigned short Bs[4096];
  const int tid = threadIdx.x;
  const int wid = tid >> 6, lane = tid & 63;
  const long row0 = (long)blockIdx.x * 128, col0 = (long)blockIdx.y * 128;
  const int wm = (wid >> 1) * 64, wn = (wid & 1) * 64;
  f32x4 acc[4][4] = {};
  const int sr = tid >> 2, sk = (tid & 3) * 8;
  const unsigned short* gA = A + (row0 + sr) * lda + sk;
  const unsigned short* gB = Bt + (col0 + sr) * ldb + sk;
  unsigned short* lA = As + wid * 512;
  unsigned short* lB = Bs + wid * 512;
  const int fr = lane & 15, fk = (lane >> 4) * 8;

  for (long kb = 0; kb < K; kb += 32) {
    gload16(gA + kb, lA);
    gload16(gA + kb + 64 * lda, lA + 2048);
    gload16(gB + kb, lB);
    gload16(gB + kb + 64 * ldb, lB + 2048);
    __syncthreads();
    bf16x8 af[4], bq[4];
#pragma unroll
    for (int mt = 0; mt < 4; ++mt)
      af[mt] = *(const bf16x8*)(As + (wm + mt * 16 + fr) * 32 + fk);
#pragma unroll
    for (int nt = 0; nt < 4; ++nt)
      bq[nt] = *(const bf16x8*)(Bs + (wn + nt * 16 + fr) * 32 + fk);
#pragma unroll
    for (int mt = 0; mt < 4; ++mt)
#pragma unroll
      for (int nt = 0; nt < 4; ++nt)
        acc[mt][nt] = __builtin_amdgcn_mfma_f32_16x16x32_bf16(
            af[mt], bq[nt], acc[mt][nt], 0, 0, 0);
    __syncthreads();
  }
  const int fq = lane >> 4;
#pragma unroll
  for (int mt = 0; mt < 4; ++mt) {
#pragma unroll
    for (int nt = 0; nt < 4; ++nt) {
      const long c = col0 + wn + nt * 16 + fr;
      if (c < N) {
        const long rb = row0 + wm + mt * 16 + fq * 4;
#pragma unroll
        for (int rg = 0; rg < 4; ++rg)
          ep_store<EP>(acc[mt][nt][rg], rb + rg, c, ldc, Co, Cob, bias, e0f, e0b);
      }
    }
  }
}

// ---------------- GEMM v3 (128x128, counted vmcnt, swizzled dbuf) ----------

template <int EP>
__global__ __launch_bounds__(256)
void gemm3(const unsigned short* __restrict__ A, long lda,
           const unsigned short* __restrict__ Bt, long ldb, long K, long ldc,
           float* __restrict__ Co, unsigned short* __restrict__ Cob,
           const float* __restrict__ e0f) {
  __shared__ unsigned short As[2][4096];
  __shared__ unsigned short Bs[2][4096];
  const int tid = threadIdx.x;
  const int wid = tid >> 6, lane = tid & 63;
  const long row0 = (long)blockIdx.x * 128, col0 = (long)blockIdx.y * 128;
  const int wm = (wid >> 1) * 64, wn = (wid & 1) * 64;
  f32x4 acc[4][4] = {};
  const int srow = tid >> 2;
  const int scol = 8 * ((tid & 3) ^ (srow & 3));
  const unsigned short* gA = A + (row0 + srow) * lda + scol;
  const unsigned short* gB = Bt + (col0 + srow) * ldb + scol;
  const int fr = lane & 15, fc = lane >> 4;

#define STAGE3(buf, kb)                                         \
  {                                                             \
    gload16(gA + (kb), &As[buf][0] + wid * 512);                \
    gload16(gA + (kb) + 64 * lda, &As[buf][2048] + wid * 512);  \
    gload16(gB + (kb), &Bs[buf][0] + wid * 512);                \
    gload16(gB + (kb) + 64 * ldb, &Bs[buf][2048] + wid * 512);  \
  }

  STAGE3(0, 0)
  const int NT = (int)(K >> 5);
  int cur = 0;
  for (int kt = 0; kt < NT; ++kt) {
    if (kt + 1 < NT) {
      STAGE3(cur ^ 1, (long)(kt + 1) * 32)
      asm volatile("s_waitcnt vmcnt(4)" ::: "memory");
    } else {
      asm volatile("s_waitcnt vmcnt(0)" ::: "memory");
    }
    __builtin_amdgcn_s_barrier();
    asm volatile("" ::: "memory");
    bf16x8 af[4], bq[4];
#pragma unroll
    for (int mt = 0; mt < 4; ++mt) {
      const int r = wm + mt * 16 + fr;
      af[mt] = *(const bf16x8*)(&As[cur][0] + r * 32 + ((fc ^ (r & 3)) * 8));
    }
#pragma unroll
    for (int nt = 0; nt < 4; ++nt) {
      const int r = wn + nt * 16 + fr;
      bq[nt] = *(const bf16x8*)(&Bs[cur][0] + r * 32 + ((fc ^ (r & 3)) * 8));
    }
    __builtin_amdgcn_s_setprio(1);
#pragma unroll
    for (int mt = 0; mt < 4; ++mt)
#pragma unroll
      for (int nt = 0; nt < 4; ++nt)
        acc[mt][nt] = __builtin_amdgcn_mfma_f32_16x16x32_bf16(
            af[mt], bq[nt], acc[mt][nt], 0, 0, 0);
    __builtin_amdgcn_s_setprio(0);
    asm volatile("" ::: "memory");
    __builtin_amdgcn_s_barrier();
    cur ^= 1;
  }
#undef STAGE3
  const int fq = lane >> 4;
#pragma unroll
  for (int mt = 0; mt < 4; ++mt) {
#pragma unroll
    for (int nt = 0; nt < 4; ++nt) {
      const long c = col0 + wn + nt * 16 + fr;
      const long rb = row0 + wm + mt * 16 + fq * 4;
#pragma unroll
      for (int rg = 0; rg < 4; ++rg)
        ep_store<EP>(acc[mt][nt][rg], rb + rg, c, ldc, Co, Cob, nullptr, e0f,
                     nullptr);
    }
  }
}

// ---------------- GEMM 8-phase 256x256 (T3+T4, st-swizzle) -----------------
// BM=BN=256, BK=64; 512 thr = 8 waves. LDS 128KB: 2 bufs x {A0,A1,B0,B1}
// halves of [128 rows][64 k] bf16 (16KB each). Per K-tile: 4 phases; phase p
// computes quadrant (mh=p>>1, nh=p&1): every wave does 4m x 2n x 2ks = 16
// MFMA. Stage order (next tile): p0->A0, p1->B0, p2->A1, p3->B1 (2 gload16
// per thread per phase). Wait ledger: vmcnt(2)@p0, vmcnt(4)@p3 confirm each
// half >=1 barrier before first read. Swizzle (both sides, rule 21):
// element col ^= ((row>>2)&1)<<4 within each [128][64] half.

template <int EP>
__global__ __launch_bounds__(512)
void gemm8p(const unsigned short* __restrict__ A, long lda,
            const unsigned short* __restrict__ Bt, long ldb, long K, long ldc,
            float* __restrict__ Co, unsigned short* __restrict__ Cob,
            const float* __restrict__ e0f) {
  __shared__ unsigned short lds[65536];  // 128KB
  const int tid = threadIdx.x;
  const int wid = tid >> 6, lane = tid & 63;
  const long row0 = (long)blockIdx.x * 256, col0 = (long)blockIdx.y * 256;
  const int wrow = (wid >> 2) * 64;  // within 128-row A half
  const int wcol = (wid & 3) * 32;   // within 128-col B half
  const int fr = lane & 15, fc = lane >> 4;
  f32x4 acc[2][4][2][2] = {};  // [mh][mt][nh][nt]

  // staging source (inverse-swizzled)
  const int sr0 = tid >> 3;                       // 0..63
  int sce = (tid & 7) * 8;
  sce ^= ((sr0 >> 2) & 1) << 4;                   // swizzled element col
  const unsigned short* gA = A + (row0 + sr0) * lda + sce;
  const unsigned short* gB = Bt + (col0 + sr0) * ldb + sce;

  // halves: 0=A0,1=A1,2=B0,3=B1 at lds + buf*32768 + half*8192
#define STG8(half, src, ld, kb, buf)                                     \
  {                                                                      \
    const unsigned short* s_ = (src) + (kb);                             \
    unsigned short* d_ = lds + (buf) * 32768 + (half) * 8192 + tid * 8;  \
    gload16(s_, d_);                                                     \
    gload16(s_ + 64 * (ld), d_ + 4096);                                  \
  }

  // prologue: tile 0 into buf 0
  STG8(0, gA, lda, 0, 0)
  STG8(2, gB, ldb, 0, 0)
  STG8(1, gA + 128 * lda, lda, 0, 0)
  STG8(3, gB + 128 * ldb, ldb, 0, 0)
  asm volatile("s_waitcnt vmcnt(0)" ::: "memory");
  __builtin_amdgcn_s_barrier();

  const int NT = (int)(K >> 6);
  int cur = 0;

#define PHASE8(P, KT)                                                         \
  {                                                                           \
    constexpr int mh = (P) >> 1, nh = (P) & 1;                                \
    const int bb = cur * 32768;                                               \
    bf16x8 af[4][2], bq[2][2];                                                \
    _Pragma("unroll") for (int mt = 0; mt < 4; ++mt)                          \
      _Pragma("unroll") for (int ks = 0; ks < 2; ++ks) {                      \
        const int r = wrow + mt * 16 + fr;                                    \
        const int e = (ks * 32 + fc * 8) ^ (((r >> 2) & 1) << 4);             \
        af[mt][ks] = *(const bf16x8*)(lds + bb + mh * 8192 + r * 64 + e);     \
      }                                                                       \
    _Pragma("unroll") for (int nt = 0; nt < 2; ++nt)                          \
      _Pragma("unroll") for (int ks = 0; ks < 2; ++ks) {                      \
        const int r = wcol + nt * 16 + fr;                                    \
        const int e = (ks * 32 + fc * 8) ^ (((r >> 2) & 1) << 4);             \
        bq[nt][ks] =                                                          \
            *(const bf16x8*)(lds + bb + 16384 + nh * 8192 + r * 64 + e);      \
      }                                                                       \
    if ((KT) + 1 < NT) {                                                      \
      const long kb_ = (long)((KT) + 1) * 64;                                 \
      if constexpr ((P) == 0) STG8(0, gA, lda, kb_, cur ^ 1)                  \
      else if constexpr ((P) == 1) STG8(2, gB, ldb, kb_, cur ^ 1)             \
      else if constexpr ((P) == 2) STG8(1, gA + 128 * lda, lda, kb_, cur ^ 1) \
      else STG8(3, gB + 128 * ldb, ldb, kb_, cur ^ 1)                         \
    }                                                                         \
    if constexpr ((P) == 0) asm volatile("s_waitcnt vmcnt(2)" ::: "memory");  \
    if constexpr ((P) == 3) asm volatile("s_waitcnt vmcnt(4)" ::: "memory");  \
    __builtin_amdgcn_s_barrier();                                             \
    asm volatile("s_waitcnt lgkmcnt(0)" ::: "memory");                        \
    __builtin_amdgcn_s_setprio(1);                                            \
    _Pragma("unroll") for (int mt = 0; mt < 4; ++mt)                          \
      _Pragma("unroll") for (int nt = 0; nt < 2; ++nt)                        \
        _Pragma("unroll") for (int ks = 0; ks < 2; ++ks)                      \
          acc[mh][mt][nh][nt] = __builtin_amdgcn_mfma_f32_16x16x32_bf16(      \
              af[mt][ks], bq[nt][ks], acc[mh][mt][nh][nt], 0, 0, 0);          \
    __builtin_amdgcn_s_setprio(0);                                            \
    asm volatile("" ::: "memory");                                            \
    __builtin_amdgcn_s_barrier();                                             \
  }

  for (int kt = 0; kt < NT; ++kt) {
    PHASE8(0, kt)
    PHASE8(1, kt)
    PHASE8(2, kt)
    PHASE8(3, kt)
    cur ^= 1;
  }
#undef PHASE8
#undef STG8

  const int fq = lane >> 4;
#pragma unroll
  for (int mh = 0; mh < 2; ++mh)
#pragma unroll
    for (int mt = 0; mt < 4; ++mt)
#pragma unroll
      for (int nh = 0; nh < 2; ++nh)
#pragma unroll
        for (int nt = 0; nt < 2; ++nt) {
          const long c = col0 + nh * 128 + wcol + nt * 16 + fr;
          const long rb = row0 + mh * 128 + wrow + mt * 16 + fq * 4;
#pragma unroll
          for (int rg = 0; rg < 4; ++rg)
            ep_store<EP>(acc[mh][mt][nh][nt][rg], rb + rg, c, ldc, Co, Cob,
                         nullptr, e0f, nullptr);
        }
}

// ---------------- gemm_up128: Hact[4096][288] @ Wup^T[8192][288] -----------

__global__ __launch_bounds__(256)
void gemm_up128(const unsigned short* __restrict__ A,
                const unsigned short* __restrict__ Bt,
                float* __restrict__ whb, unsigned short* __restrict__ abuf,
                unsigned short* __restrict__ vfb, unsigned short* __restrict__ gbuf,
                const float* __restrict__ w0, const float* __restrict__ a0,
                const float* __restrict__ v0,
                const unsigned short* __restrict__ vraw,
                const float* __restrict__ vfirst) {
  __shared__ unsigned short As[2][4096];
  __shared__ unsigned short Bs[2][4096];
  const int tid = threadIdx.x;
  const int wid = tid >> 6, lane = tid & 63;
  const long row0 = (long)blockIdx.x * 128, col0 = (long)blockIdx.y * 128;
  const int wm = (wid >> 1) * 64, wn = (wid & 1) * 64;
  f32x4 acc[4][4] = {};
  const int srow = tid >> 2;
  const int scol = 8 * ((tid & 3) ^ (srow & 3));
  const unsigned short* gA = A + (row0 + srow) * 288 + scol;
  const unsigned short* gB = Bt + (col0 + srow) * 288 + scol;
  const int fr = lane & 15, fc = lane >> 4;

#define STAGEU(buf, kb)                                         \
  {                                                             \
    gload16(gA + (kb), &As[buf][0] + wid * 512);                \
    gload16(gA + (kb) + 64 * 288, &As[buf][2048] + wid * 512);  \
    gload16(gB + (kb), &Bs[buf][0] + wid * 512);                \
    gload16(gB + (kb) + 64 * 288, &Bs[buf][2048] + wid * 512);  \
  }

  STAGEU(0, 0)
  int cur = 0;
  for (int kt = 0; kt < 9; ++kt) {
    if (kt + 1 < 9) {
      STAGEU(cur ^ 1, (long)(kt + 1) * 32)
      asm volatile("s_waitcnt vmcnt(4)" ::: "memory");
    } else {
      asm volatile("s_waitcnt vmcnt(0)" ::: "memory");
    }
    __builtin_amdgcn_s_barrier();
    asm volatile("" ::: "memory");
    bf16x8 af[4], bq[4];
#pragma unroll
    for (int mt = 0; mt < 4; ++mt) {
      const int r = wm + mt * 16 + fr;
      af[mt] = *(const bf16x8*)(&As[cur][0] + r * 32 + ((fc ^ (r & 3)) * 8));
    }
#pragma unroll
    for (int nt = 0; nt < 4; ++nt) {
      const int r = wn + nt * 16 + fr;
      bq[nt] = *(const bf16x8*)(&Bs[cur][0] + r * 32 + ((fc ^ (r & 3)) * 8));
    }
    __builtin_amdgcn_s_setprio(1);
#pragma unroll
    for (int mt = 0; mt < 4; ++mt)
#pragma unroll
      for (int nt = 0; nt < 4; ++nt)
        acc[mt][nt] = __builtin_amdgcn_mfma_f32_16x16x32_bf16(
            af[mt], bq[nt], acc[mt][nt], 0, 0, 0);
    __builtin_amdgcn_s_setprio(0);
    asm volatile("" ::: "memory");
    __builtin_amdgcn_s_barrier();
    cur ^= 1;
  }
#undef STAGEU
  const int fq = lane >> 4;
  const int p = (int)(blockIdx.y >> 4);
#pragma unroll
  for (int mt = 0; mt < 4; ++mt) {
#pragma unroll
    for (int nt = 0; nt < 4; ++nt) {
      const long c = col0 + wn + nt * 16 + fr;
      const long cc = c & 2047;
      const long rb = row0 + wm + mt * 16 + fq * 4;
#pragma unroll
      for (int rg = 0; rg < 4; ++rg) {
        const float av = acc[mt][nt][rg];
        const long idx = (rb + rg) * 2048 + cc;
        if (p == 0) {
          const float wv = w0[cc] + av;
          const float sp = log1pf(expf(-wv));
          whb[idx] = expf(-expf(-sp - 0.5f));
        } else if (p == 1) {
          abuf[idx] = f2b(1.f / (1.f + expf(-(a0[cc] + av))));
        } else if (p == 2) {
          const float s = 1.f / (1.f + expf(-(v0[cc] + av)));
          const float vv = b2f(vraw[idx]);
          vfb[idx] = f2b(vv + (vfirst[idx] - vv) * s);
        } else {
          gbuf[idx] = f2b(av);  // g = sigmoid(xg@g1) @ g2 -- NO outer act
        }
      }
    }
  }
}

// ------------------------------ k_post -------------------------------------
__global__ __launch_bounds__(256)
void k_post(unsigned short* __restrict__ kio, unsigned short* __restrict__ abio,
            unsigned short* __restrict__ aao, const float* __restrict__ kkw,
            const float* __restrict__ kaw) {
  const int m = blockIdx.x, tid = threadIdx.x;
  const size_t base = (size_t)m * 2048 + tid * 8;
  us8 k8 = *(const us8*)(kio + base);
  us8 a8 = *(const us8*)(abio + base);
  float kk8[8], ka8[8];
  *(float4*)&kk8[0] = *(const float4*)(kkw + tid * 8);
  *(float4*)&kk8[4] = *(const float4*)(kkw + tid * 8 + 4);
  *(float4*)&ka8[0] = *(const float4*)(kaw + tid * 8);
  *(float4*)&ka8[4] = *(const float4*)(kaw + tid * 8 + 4);
  float kx[8], kv[8], av[8];
  float ss = 0.f;
#pragma unroll
  for (int i = 0; i < 8; ++i) {
    kv[i] = b2f(k8[i]); av[i] = b2f(a8[i]);
    kx[i] = kv[i] * kk8[i]; ss += kx[i] * kx[i];
  }
  ss = red8(ss);
  const float inv = 1.f / fmaxf(sqrtf(ss), 1e-12f);
  us8 kh8, aa8, bb8;
#pragma unroll
  for (int i = 0; i < 8; ++i) {
    const float kkn = kx[i] * inv;
    kh8[i] = f2b(kv[i] * (1.f + (av[i] - 1.f) * ka8[i]));
    aa8[i] = f2b(-kkn);
    bb8[i] = f2b(kkn * av[i]);
  }
  *(us8*)(kio + base) = kh8;
  *(us8*)(aao + base) = aa8;
  *(us8*)(abio + base) = bb8;
}

// ------------------------------ WKV scan (R11) ------------------------------

DEV float red16(float x) {  // all-lanes sum within each 16-lane row
  union { float f; int i; } a, r;
  a.f = x; r.i = __builtin_amdgcn_update_dpp(0, a.i, 0xB1, 0xf, 0xf, true);
  x += r.f;
  a.f = x; r.i = __builtin_amdgcn_update_dpp(0, a.i, 0x4E, 0xf, 0xf, true);
  x += r.f;
  a.f = x; r.i = __builtin_amdgcn_update_dpp(0, a.i, 0x124, 0xf, 0xf, true);
  x += r.f;
  a.f = x; r.i = __builtin_amdgcn_update_dpp(0, a.i, 0x128, 0xf, 0xf, true);
  x += r.f;
  return x;
}

DEV void cv4(const uint2 q, float* o) {
  union { unsigned u; float f; } t;
  t.u = q.x << 16;          o[0] = t.f;
  t.u = q.x & 0xffff0000u;  o[1] = t.f;
  t.u = q.y << 16;          o[2] = t.f;
  t.u = q.y & 0xffff0000u;  o[3] = t.f;
}

__global__ __launch_bounds__(64)
void k_scan(const unsigned short* __restrict__ rp,
            const unsigned short* __restrict__ kp,
            const unsigned short* __restrict__ vp,
            const float* __restrict__ wp,
            const unsigned short* __restrict__ ap,
            const unsigned short* __restrict__ bp,
            const float* __restrict__ s0, unsigned short* __restrict__ yout,
            float* __restrict__ snew) {
  __shared__ float4 slots[8][49];
  __shared__ unsigned short ylds[1024][4];
  const int lane = threadIdx.x;
  const int bh = blockIdx.x & 127;
  const int rq = blockIdx.x >> 7;
  const int b = bh >> 5, h = bh & 31;
  const int kg = lane & 15, rl = lane >> 4;
  const int v = rq * 4 + rl, ks = kg * 4;
  const size_t off_bh = (size_t)b * 1024 * 2048 + (size_t)h * 64;
  const int vfo = 768 + ((rq & 1) * 4 + rl) * 2;

  float S[4];
  *(float4*)&S[0] = *(const float4*)(s0 + (((size_t)bh * 64 + v) * 64 + ks));

  const char* gp = nullptr;
  size_t gstep = 0;
  if (lane < 49) {
    if (lane < 32) {
      const int arr = lane >> 3, sub = lane & 7;
      const unsigned short* base = arr == 0 ? rp : arr == 1 ? kp
                                 : arr == 2 ? ap : bp;
      gp = (const char*)(base + off_bh + sub * 8);
      gstep = 4096;
    } else if (lane < 48) {
      gp = (const char*)(wp + off_bh + (lane - 32) * 4);
      gstep = 8192;
    } else {
      gp = (const char*)(vp + off_bh + (rq & ~1) * 4);
      gstep = 4096;
    }
  }
#pragma unroll
  for (int s = 0; s < 8; ++s) {
    if (lane < 49) gload16(gp, &slots[s][0]);
    gp += gstep;
  }

  uint2 rA, kA, aA, bA, rB, kB, aB, bB;
  float4 wA, wB;
  unsigned short fA, fB;
  asm volatile("s_waitcnt vmcnt(7)" ::: "memory");
  {
    const char* nb = (const char*)&slots[0][0];
    rA = *(const uint2*)(nb + kg * 8);
    kA = *(const uint2*)(nb + 128 + kg * 8);
    aA = *(const uint2*)(nb + 256 + kg * 8);
    bA = *(const uint2*)(nb + 384 + kg * 8);
    wA = *(const float4*)(nb + 512 + kg * 16);
    fA = *(const unsigned short*)(nb + vfo);
  }

#define SSTEP(T, Cr, Ck, Ca, Cb, Cw, Cf, Nr, Nk, Na, Nb, Nw, Nf)             \
  {                                                                          \
    asm volatile("s_waitcnt lgkmcnt(0)" ::: "memory");                       \
    if (lane < 49) gload16(gp, &slots[(T) & 7][0]);                          \
    if ((T) < 1015) gp += gstep;                                             \
    asm volatile("s_waitcnt vmcnt(7)" ::: "memory");                         \
    const char* nb = (const char*)&slots[((T) + 1) & 7][0];                  \
    Nr = *(const uint2*)(nb + kg * 8);                                       \
    Nk = *(const uint2*)(nb + 128 + kg * 8);                                 \
    Na = *(const uint2*)(nb + 256 + kg * 8);                                 \
    Nb = *(const uint2*)(nb + 384 + kg * 8);                                 \
    Nw = *(const float4*)(nb + 512 + kg * 16);                               \
    Nf = *(const unsigned short*)(nb + vfo);                                 \
    float rr[4], kk[4], av[4], bv[4];                                        \
    cv4(Cr, rr); cv4(Ck, kk); cv4(Ca, av); cv4(Cb, bv);                      \
    const float vv = b2f(Cf);                                                \
    float sa = S[0] * av[0] + S[1] * av[1] + S[2] * av[2] + S[3] * av[3];    \
    sa = red16(sa);                                                          \
    float y;                                                                 \
    S[0] = S[0] * Cw.x + sa * bv[0] + vv * kk[0]; y  = S[0] * rr[0];         \
    S[1] = S[1] * Cw.y + sa * bv[1] + vv * kk[1]; y += S[1] * rr[1];         \
    S[2] = S[2] * Cw.z + sa * bv[2] + vv * kk[2]; y += S[2] * rr[2];         \
    S[3] = S[3] * Cw.w + sa * bv[3] + vv * kk[3]; y += S[3] * rr[3];         \
    y = red16(y);                                                            \
    if (kg == 0) ylds[T][rl] = f2b(y);                                       \
  }

  for (int tb = 0; tb < 1024; tb += 2) {
    SSTEP(tb + 0, rA, kA, aA, bA, wA, fA, rB, kB, aB, bB, wB, fB)
    SSTEP(tb + 1, rB, kB, aB, bB, wB, fB, rA, kA, aA, bA, wA, fA)
  }
#undef SSTEP

  *(float4*)(snew + (((size_t)bh * 64 + v) * 64 + ks)) = *(const float4*)&S[0];
  asm volatile("s_waitcnt lgkmcnt(0)" ::: "memory");
#pragma unroll 4
  for (int it = 0; it < 16; ++it) {
    const int t = lane + it * 64;
    const uint2 val = *(const uint2*)&ylds[t][0];
    *(uint2*)(yout + off_bh + (size_t)t * 2048 + rq * 4) = val;
  }
}

// ---------------------- GroupNorm + resid + gate ---------------------------

__global__ __launch_bounds__(256)
void k_gn(const unsigned short* __restrict__ y, const unsigned short* __restrict__ r,
          const unsigned short* __restrict__ kh, const unsigned short* __restrict__ vf,
          const unsigned short* __restrict__ g, const float* __restrict__ rk,
          const float* __restrict__ lw, const float* __restrict__ lb,
          unsigned short* __restrict__ ywg) {
  const int m = blockIdx.x, tid = threadIdx.x;
  const size_t base = (size_t)m * 2048 + tid * 8;
  us8 y8 = *(const us8*)(y + base);
  us8 r8 = *(const us8*)(r + base);
  us8 k8 = *(const us8*)(kh + base);
  us8 v8 = *(const us8*)(vf + base);
  us8 g8 = *(const us8*)(g + base);
  float yv[8];
  float rkv[8];
  *(float4*)&rkv[0] = *(const float4*)(rk + tid * 8);
  *(float4*)&rkv[4] = *(const float4*)(rk + tid * 8 + 4);
  float sy = 0.f, sd = 0.f;
#pragma unroll
  for (int i = 0; i < 8; ++i) {
    yv[i] = b2f(y8[i]);
    sy += yv[i];
    sd += b2f(r8[i]) * b2f(k8[i]) * rkv[i];
  }
  sy = red8(sy);
  sd = red8(sd);
  const float mu = sy * (1.f / 64.f);
  float sq = 0.f;
#pragma unroll
  for (int i = 0; i < 8; ++i) { const float d = yv[i] - mu; sq += d * d; }
  sq = red8(sq);
  const float rstd = rsqrtf(sq * (1.f / 64.f) + 64e-5f);
  us8 o8;
#pragma unroll
  for (int i = 0; i < 8; ++i) {
    const int c = tid * 8 + i;
    const float gn = (yv[i] - mu) * rstd * lw[c] + lb[c];
    o8[i] = f2b((gn + sd * b2f(v8[i])) * b2f(g8[i]));
  }
  *(us8*)(ywg + base) = o8;
}

// ------------------------------ launch -------------------------------------

extern "C" void kernel_launch(void* const* d_in, const int* in_sizes, int n_in,
                              void* d_out, int out_size, void* d_ws,
                              size_t ws_size, hipStream_t stream) {
  (void)in_sizes; (void)n_in; (void)out_size; (void)ws_size;
  const float* x         = (const float*)d_in[0];
  const float* v_first   = (const float*)d_in[1];
  const float* att_shift = (const float*)d_in[2];
  const float* ffn_shift = (const float*)d_in[3];
  const float* wkv0      = (const float*)d_in[4];
  const float* ln1w = (const float*)d_in[5];
  const float* ln1b = (const float*)d_in[6];
  const float* ln2w = (const float*)d_in[7];
  const float* ln2b = (const float*)d_in[8];
  const float* x_r = (const float*)d_in[9];
  const float* x_w = (const float*)d_in[10];
  const float* x_k = (const float*)d_in[11];
  const float* x_v = (const float*)d_in[12];
  const float* x_a = (const float*)d_in[13];
  const float* x_g = (const float*)d_in[14];
  const float* Wr = (const float*)d_in[15];
  const float* Wk = (const float*)d_in[16];
  const float* Wv = (const float*)d_in[17];
  const float* Wo = (const float*)d_in[18];
  const float* w0 = (const float*)d_in[19];
  const float* w1 = (const float*)d_in[20];
  const float* w2 = (const float*)d_in[21];
  const float* v0 = (const float*)d_in[22];
  const float* v1 = (const float*)d_in[23];
  const float* v2 = (const float*)d_in[24];
  const float* a0 = (const float*)d_in[25];
  const float* a1 = (const float*)d_in[26];
  const float* a2 = (const float*)d_in[27];
  const float* g1 = (const float*)d_in[28];
  const float* g2 = (const float*)d_in[29];
  const float* k_k = (const float*)d_in[30];
  const float* k_a = (const float*)d_in[31];
  const float* r_k = (const float*)d_in[32];
  const float* lnxw = (const float*)d_in[33];
  const float* lnxb = (const float*)d_in[34];
  const float* ffn_xk = (const float*)d_in[35];
  const float* Wkf = (const float*)d_in[36];
  const float* Wvf = (const float*)d_in[37];

  char* ws = (char*)d_ws;
  constexpr size_t OFF_TWR   = 0;
  constexpr size_t OFF_TWK   = 8388608;
  constexpr size_t OFF_TWV   = 16777216;
  constexpr size_t OFF_TWO   = 25165824;
  constexpr size_t OFF_TWCAT = 34734080;
  constexpr size_t OFF_HACT  = 37879808;
  constexpr size_t OFF_GBUF  = 40239104;
  constexpr size_t OFF_WH    = 57016320;
  constexpr size_t OFF_R     = 90570752;
  constexpr size_t OFF_KH    = 107347968;
  constexpr size_t OFF_VF    = 124125184;
  constexpr size_t OFF_AA    = 140902400;
  constexpr size_t OFF_BB    = 157679616;
  constexpr size_t OFF_TWUP  = 174456832;  // [8192][288] bf16, 4.7MB

  unsigned short* tWr = (unsigned short*)(ws + OFF_TWR);
  unsigned short* tWk = (unsigned short*)(ws + OFF_TWK);
  unsigned short* tWv = (unsigned short*)(ws + OFF_TWV);
  unsigned short* tWo = (unsigned short*)(ws + OFF_TWO);
  unsigned short* tWcat = (unsigned short*)(ws + OFF_TWCAT);
  unsigned short* Hact  = (unsigned short*)(ws + OFF_HACT);
  unsigned short* gbuf  = (unsigned short*)(ws + OFF_GBUF);
  unsigned short* tWvfh = (unsigned short*)(ws + OFF_GBUF);
  unsigned short* act2  = (unsigned short*)(ws + OFF_WH);
  float*          whb   = (float*)(ws + OFF_WH);
  unsigned short* ywg   = (unsigned short*)(ws + OFF_WH);
  unsigned short* kf    = (unsigned short*)(ws + OFF_WH);
  unsigned short* bxr   = (unsigned short*)(ws + OFF_AA);
  unsigned short* bxk   = (unsigned short*)(ws + OFF_BB);
  unsigned short* bxv   = (unsigned short*)(ws + OFF_VF);
  unsigned short* rbuf  = (unsigned short*)(ws + OFF_R);
  unsigned short* khb   = (unsigned short*)(ws + OFF_KH);
  unsigned short* vfb   = (unsigned short*)(ws + OFF_VF);
  unsigned short* aab   = (unsigned short*)(ws + OFF_AA);
  unsigned short* bbb   = (unsigned short*)(ws + OFF_BB);
  unsigned short* vraw  = (unsigned short*)(ws + OFF_AA);
  unsigned short* abuf  = (unsigned short*)(ws + OFF_BB);
  float*          x1    = (float*)(ws + OFF_R);
  unsigned short* xkf   = (unsigned short*)(ws + OFF_VF);
  unsigned short* tWkf  = (unsigned short*)(ws + OFF_AA);
  unsigned short* tWup  = (unsigned short*)(ws + OFF_TWUP);
  float* out = (float*)d_out;
  float* snew = out + 8388608;

  const dim3 tb(32, 8);
  // ---- weight prep ----
  k_transpose<<<dim3(64, 64), tb, 0, stream>>>(Wr, tWr, 2048, 2048);
  k_transpose<<<dim3(64, 64), tb, 0, stream>>>(Wk, tWk, 2048, 2048);
  k_transpose<<<dim3(64, 64), tb, 0, stream>>>(Wv, tWv, 2048, 2048);
  k_transpose<<<dim3(64, 64), tb, 0, stream>>>(Wo, tWo, 2048, 2048);
  k_wcat<<<6144, 256, 0, stream>>>(w1, a1, v1, g1, x_w, x_a, x_v, x_g, tWcat);
  k_wup<<<9216, 256, 0, stream>>>(w2, a2, v2, g2, tWup);

  // ---- TimeMix front ----
  k_ln1_mix<<<4096, 256, 0, stream>>>(x, att_shift, ln1w, ln1b, x_r, x_k, x_v,
                                      act2, bxr, bxk, bxv);
  gemm3<EP_B16><<<dim3(32, 16), 256, 0, stream>>>(
      bxr, 2048, tWr, 2048, 2048, 2048, nullptr, rbuf, nullptr);
  gemm3<EP_B16><<<dim3(32, 16), 256, 0, stream>>>(
      bxk, 2048, tWk, 2048, 2048, 2048, nullptr, khb, nullptr);
  gemm3<EP_B16><<<dim3(32, 16), 256, 0, stream>>>(
      bxv, 2048, tWv, 2048, 2048, 2048, nullptr, vraw, nullptr);
  gemm_bt<EP_HACT><<<dim3(32, 3), 256, 0, stream>>>(
      act2, 4096, tWcat, 4096, 288, 4096, 288, nullptr, Hact, nullptr, nullptr, nullptr);
  gemm_up128<<<dim3(32, 64), 256, 0, stream>>>(
      Hact, tWup, whb, abuf, vfb, gbuf, w0, a0, v0, vraw, v_first);
  k_post<<<4096, 256, 0, stream>>>(khb, abuf, aab, k_k, k_a);

  // ---- WKV scan ----
  k_scan<<<2048, 64, 0, stream>>>(rbuf, khb, vfb, whb, aab, bbb, wkv0,
                                  (unsigned short*)out, snew);
  k_gn<<<4096, 256, 0, stream>>>((const unsigned short*)out, rbuf, khb, vfb,
                                 gbuf, r_k, lnxw, lnxb, ywg);

  // ---- Wo projection (+x) -> x1 ----
  gemm3<EP_ADDF><<<dim3(32, 16), 256, 0, stream>>>(
      ywg, 2048, tWo, 2048, 2048, 2048, x1, nullptr, x);

  // ---- ChannelMix (two DFF halves) ----
  k_ln2_mix<<<4096, 256, 0, stream>>>(x1, ffn_shift, ln2w, ln2b, ffn_xk, xkf);
  k_transpose<<<dim3(256, 64), tb, 0, stream>>>(Wkf, tWkf, 2048, 8192);
  gemm8p<EP_RELU2><<<dim3(16, 16), 512, 0, stream>>>(
      xkf, 2048, tWkf, 2048, 2048, 4096, nullptr, kf, nullptr);
  k_transpose<<<dim3(64, 128), tb, 0, stream>>>(Wvf, tWvfh, 4096, 2048);
  gemm3<EP_ADDF><<<dim3(32, 16), 256, 0, stream>>>(
      kf, 4096, tWvfh, 4096, 4096, 2048, out, nullptr, x1);
  gemm8p<EP_RELU2><<<dim3(16, 16), 512, 0, stream>>>(
      xkf, 2048, tWkf + (size_t)4096 * 2048, 2048, 2048, 4096, nullptr, kf, nullptr);
  k_transpose<<<dim3(64, 128), tb, 0, stream>>>(Wvf + (size_t)4096 * 2048, tWvfh,
                                                4096, 2048);
  gemm3<EP_ADDF><<<dim3(32, 16), 256, 0, stream>>>(
      kf, 4096, tWvfh, 4096, 4096, 2048, out, nullptr, out);
}

// Round 15
// 1265.783 us; speedup vs baseline: 1.0267x; 1.0085x over previous
//
#include <hip/hip_runtime.h>
#include <cstdint>

// ---------------------------------------------------------------------------
// RWKV7 block (B=4,T=1024,C=2048,H=32,N=64,DFF=8192) for MI355X gfx950.
// R15: launch consolidation — k_transpose4 (4 square transposes in one
//      launch), k_prep (wcat+wup merged). All compute kernels = R14 (best).
// ---------------------------------------------------------------------------

typedef __attribute__((ext_vector_type(4))) float f32x4;
typedef __attribute__((ext_vector_type(8))) __bf16 bf16x8;
typedef __attribute__((ext_vector_type(8))) unsigned short us8;

#define DEV __device__ __forceinline__

DEV unsigned short f2b(float f) {
  union { float f; unsigned u; } v; v.f = f;
  unsigned r = v.u + 0x7fffu + ((v.u >> 16) & 1u);
  return (unsigned short)(r >> 16);
}
DEV float b2f(unsigned short u) {
  union { unsigned u; float f; } v; v.u = (unsigned)u << 16;
  return v.f;
}

DEV void gload16(const void* g, void* l) {
  void* gg = const_cast<void*>(g);
  __builtin_amdgcn_global_load_lds(
      (__attribute__((address_space(1))) unsigned int*)gg,
      (__attribute__((address_space(3))) unsigned int*)l, 16, 0, 0);
}

DEV float red8(float v) {  // sum over aligned 8-lane group
  v += __shfl_xor(v, 1);
  v += __shfl_xor(v, 2);
  v += __shfl_xor(v, 4);
  return v;
}

// ------------------------------ weight prep --------------------------------

// Four 2048x2048 f32->bf16 transposes in one launch (blockIdx.z selects).
__global__ void k_transpose4(const float* __restrict__ s0,
                             const float* __restrict__ s1,
                             const float* __restrict__ s2,
                             const float* __restrict__ s3,
                             unsigned short* __restrict__ d0,
                             unsigned short* __restrict__ d1,
                             unsigned short* __restrict__ d2,
                             unsigned short* __restrict__ d3) {
  __shared__ float tile[32][33];
  const int z = blockIdx.z;
  const float* src = z == 0 ? s0 : z == 1 ? s1 : z == 2 ? s2 : s3;
  unsigned short* dst = z == 0 ? d0 : z == 1 ? d1 : z == 2 ? d2 : d3;
  const int c0 = blockIdx.x * 32, r0 = blockIdx.y * 32;
  const int tx = threadIdx.x, ty = threadIdx.y;  // block (32,8)
  for (int i = ty; i < 32; i += 8)
    tile[i][tx] = src[(size_t)(r0 + i) * 2048 + c0 + tx];
  __syncthreads();
  for (int i = ty; i < 32; i += 8)
    dst[(size_t)(c0 + i) * 2048 + r0 + tx] = f2b(tile[tx][i]);
}

__global__ void k_transpose(const float* __restrict__ src,
                            unsigned short* __restrict__ dst, int R, int Cc) {
  __shared__ float tile[32][33];
  const int c0 = blockIdx.x * 32, r0 = blockIdx.y * 32;
  const int tx = threadIdx.x, ty = threadIdx.y;  // block (32,8)
  for (int i = ty; i < 32; i += 8)
    tile[i][tx] = src[(size_t)(r0 + i) * Cc + c0 + tx];
  __syncthreads();
  for (int i = ty; i < 32; i += 8)
    dst[(size_t)(c0 + i) * R + r0 + tx] = f2b(tile[tx][i]);
}

// Merged: Wcat^T [384][4096] (first 1572864 elems) + Wup^T [8192][288].
__global__ void k_prep(const float* __restrict__ w1, const float* __restrict__ a1,
                       const float* __restrict__ v1, const float* __restrict__ g1,
                       const float* __restrict__ xw, const float* __restrict__ xa,
                       const float* __restrict__ xv, const float* __restrict__ xg,
                       const float* __restrict__ w2, const float* __restrict__ a2,
                       const float* __restrict__ v2, const float* __restrict__ g2,
                       unsigned short* __restrict__ dcat,
                       unsigned short* __restrict__ dup) {
  int i = blockIdx.x * 256 + threadIdx.x;
  if (i < 384 * 4096) {
    const int j = i >> 12, c = i & 4095;
    float val = 0.f;
    if (j < 288) {
      const float* W; const float* mix; int jj, D;
      if (j < 64)       { W = w1; mix = xw; jj = j;       D = 64;  }
      else if (j < 128) { W = a1; mix = xa; jj = j - 64;  D = 64;  }
      else if (j < 160) { W = v1; mix = xv; jj = j - 128; D = 32;  }
      else              { W = g1; mix = xg; jj = j - 160; D = 128; }
      const int cc = c & 2047;
      val = W[(size_t)cc * D + jj];
      if (c >= 2048) val *= mix[cc];
    }
    dcat[i] = f2b(val);
    return;
  }
  i -= 384 * 4096;
  if (i >= 8192 * 288) return;
  const int n = i / 288, k = i - n * 288;
  const int p = n >> 11, j = n & 2047;
  float val = 0.f;
  if (p == 0)      { if (k < 64)              val = w2[(size_t)k * 2048 + j]; }
  else if (p == 1) { if (k >= 64 && k < 128)  val = a2[(size_t)(k - 64) * 2048 + j]; }
  else if (p == 2) { if (k >= 128 && k < 160) val = v2[(size_t)(k - 128) * 2048 + j]; }
  else             { if (k >= 160)            val = g2[(size_t)(k - 160) * 2048 + j]; }
  dup[i] = f2b(val);
}

// ------------------------------ LN + mix -----------------------------------

DEV void breduce2(float& a, float& b, float* rbuf) {
#pragma unroll
  for (int m = 1; m < 64; m <<= 1) { a += __shfl_xor(a, m); b += __shfl_xor(b, m); }
  const int wid = threadIdx.x >> 6, lane = threadIdx.x & 63;
  if (lane == 0) { rbuf[wid] = a; rbuf[4 + wid] = b; }
  __syncthreads();
  a = rbuf[0] + rbuf[1] + rbuf[2] + rbuf[3];
  b = rbuf[4] + rbuf[5] + rbuf[6] + rbuf[7];
  __syncthreads();
}

__global__ __launch_bounds__(256)
void k_ln1_mix(const float* __restrict__ x, const float* __restrict__ shift,
               const float* __restrict__ lw, const float* __restrict__ lb,
               const float* __restrict__ mr, const float* __restrict__ mk,
               const float* __restrict__ mv,
               unsigned short* __restrict__ A2, unsigned short* __restrict__ xrb,
               unsigned short* __restrict__ xkb, unsigned short* __restrict__ xvb) {
  __shared__ float rbuf[8];
  const int m = blockIdx.x, tid = threadIdx.x;
  const int b = m >> 10, t = m & 1023;
  const float* xt = x + (size_t)m * 2048 + tid * 8;
  const float* xp = (t > 0) ? (x + (size_t)(m - 1) * 2048 + tid * 8)
                            : (shift + (size_t)b * 2048 + tid * 8);
  float vt[8], vp[8];
  *(float4*)&vt[0] = *(const float4*)(xt);
  *(float4*)&vt[4] = *(const float4*)(xt + 4);
  *(float4*)&vp[0] = *(const float4*)(xp);
  *(float4*)&vp[4] = *(const float4*)(xp + 4);
  float st = 0.f, sp = 0.f;
#pragma unroll
  for (int i = 0; i < 8; ++i) { st += vt[i]; sp += vp[i]; }
  breduce2(st, sp, rbuf);
  const float mt_ = st * (1.f / 2048.f), mp_ = sp * (1.f / 2048.f);
  float qt = 0.f, qp = 0.f;
#pragma unroll
  for (int i = 0; i < 8; ++i) {
    float d0 = vt[i] - mt_; qt += d0 * d0;
    float d1 = vp[i] - mp_; qp += d1 * d1;
  }
  breduce2(qt, qp, rbuf);
  const float rt = rsqrtf(qt * (1.f / 2048.f) + 1e-5f);
  const float rp = rsqrtf(qp * (1.f / 2048.f) + 1e-5f);
  const bool lnp = (t > 0);
#pragma unroll
  for (int i = 0; i < 8; ++i) {
    const int c = tid * 8 + i;
    const float wv = lw[c], bv = lb[c];
    const float xn = (vt[i] - mt_) * rt * wv + bv;
    const float pn = lnp ? ((vp[i] - mp_) * rp * wv + bv) : vp[i];
    const float xx = pn - xn;
    A2[(size_t)m * 4096 + c] = f2b(xn);
    A2[(size_t)m * 4096 + 2048 + c] = f2b(xx);
    xrb[(size_t)m * 2048 + c] = f2b(xn + xx * mr[c]);
    xkb[(size_t)m * 2048 + c] = f2b(xn + xx * mk[c]);
    xvb[(size_t)m * 2048 + c] = f2b(xn + xx * mv[c]);
  }
}

__global__ __launch_bounds__(256)
void k_ln2_mix(const float* __restrict__ x1, const float* __restrict__ shift,
               const float* __restrict__ lw, const float* __restrict__ lb,
               const float* __restrict__ mk, unsigned short* __restrict__ xkf) {
  __shared__ float rbuf[8];
  const int m = blockIdx.x, tid = threadIdx.x;
  const int b = m >> 10, t = m & 1023;
  const float* xt = x1 + (size_t)m * 2048 + tid * 8;
  const float* xp = (t > 0) ? (x1 + (size_t)(m - 1) * 2048 + tid * 8)
                            : (shift + (size_t)b * 2048 + tid * 8);
  float vt[8], vp[8];
  *(float4*)&vt[0] = *(const float4*)(xt);
  *(float4*)&vt[4] = *(const float4*)(xt + 4);
  *(float4*)&vp[0] = *(const float4*)(xp);
  *(float4*)&vp[4] = *(const float4*)(xp + 4);
  float st = 0.f, sp = 0.f;
#pragma unroll
  for (int i = 0; i < 8; ++i) { st += vt[i]; sp += vp[i]; }
  breduce2(st, sp, rbuf);
  const float mt_ = st * (1.f / 2048.f), mp_ = sp * (1.f / 2048.f);
  float qt = 0.f, qp = 0.f;
#pragma unroll
  for (int i = 0; i < 8; ++i) {
    float d0 = vt[i] - mt_; qt += d0 * d0;
    float d1 = vp[i] - mp_; qp += d1 * d1;
  }
  breduce2(qt, qp, rbuf);
  const float rt = rsqrtf(qt * (1.f / 2048.f) + 1e-5f);
  const float rp = rsqrtf(qp * (1.f / 2048.f) + 1e-5f);
  const bool lnp = (t > 0);
#pragma unroll
  for (int i = 0; i < 8; ++i) {
    const int c = tid * 8 + i;
    const float wv = lw[c], bv = lb[c];
    const float xn = (vt[i] - mt_) * rt * wv + bv;
    const float pn = lnp ? ((vp[i] - mp_) * rp * wv + bv) : vp[i];
    xkf[(size_t)m * 2048 + c] = f2b(xn + (pn - xn) * mk[c]);
  }
}

// ------------------------------ epilogues ----------------------------------

constexpr int EP_F32 = 0, EP_B16 = 1, EP_RELU2 = 5, EP_ADDF = 6, EP_HACT = 7;

template <int EP>
DEV void ep_store(float acc, long row, long c, long ldc, float* Co,
                  unsigned short* Cob, const float* bias, const float* e0f,
                  const unsigned short* e0b) {
  const long idx = row * ldc + c;
  (void)bias; (void)e0b;
  if constexpr (EP == EP_F32) {
    Co[idx] = acc;
  } else if constexpr (EP == EP_B16) {
    Cob[idx] = f2b(acc);
  } else if constexpr (EP == EP_RELU2) {
    const float r = fmaxf(acc, 0.f);
    Cob[idx] = f2b(r * r);
  } else if constexpr (EP == EP_ADDF) {
    Co[idx] = acc + e0f[idx];
  } else if constexpr (EP == EP_HACT) {
    float vv = acc;
    if (c < 64) vv = tanhf(vv);                      // w path
    else if (c >= 160) vv = 1.f / (1.f + expf(-vv)); // g path
    Cob[idx] = f2b(vv);
  }
}

// ---------------- GEMM v1 (128x128 m97-style, odd shapes) ------------------

template <int EP>
__global__ __launch_bounds__(256)
void gemm_bt(const unsigned short* __restrict__ A, long lda,
             const unsigned short* __restrict__ Bt, long ldb, long N, long K,
             long ldc, float* __restrict__ Co, unsigned short* __restrict__ Cob,
             const float* __restrict__ bias, const float* __restrict__ e0f,
             const unsigned short* __restrict__ e0b) {
  __shared__ unsigned short As[4096];
  __shared__ unsigned short Bs[4096];
  const int tid = threadIdx.x;
  const int wid = tid >> 6, lane = tid & 63;
  const long row0 = (long)blockIdx.x * 128, col0 = (long)blockIdx.y * 128;
  const int wm = (wid >> 1) * 64, wn = (wid & 1) * 64;
  f32x4 acc[4][4] = {};
  const int sr = tid >> 2, sk = (tid & 3) * 8;
  const unsigned short* gA = A + (row0 + sr) * lda + sk;
  const unsigned short* gB = Bt + (col0 + sr) * ldb + sk;
  unsigned short* lA = As + wid * 512;
  unsigned short* lB = Bs + wid * 512;
  const int fr = lane & 15, fk = (lane >> 4) * 8;

  for (long kb = 0; kb < K; kb += 32) {
    gload16(gA + kb, lA);
    gload16(gA + kb + 64 * lda, lA + 2048);
    gload16(gB + kb, lB);
    gload16(gB + kb + 64 * ldb, lB + 2048);
    __syncthreads();
    bf16x8 af[4], bq[4];
#pragma unroll
    for (int mt = 0; mt < 4; ++mt)
      af[mt] = *(const bf16x8*)(As + (wm + mt * 16 + fr) * 32 + fk);
#pragma unroll
    for (int nt = 0; nt < 4; ++nt)
      bq[nt] = *(const bf16x8*)(Bs + (wn + nt * 16 + fr) * 32 + fk);
#pragma unroll
    for (int mt = 0; mt < 4; ++mt)
#pragma unroll
      for (int nt = 0; nt < 4; ++nt)
        acc[mt][nt] = __builtin_amdgcn_mfma_f32_16x16x32_bf16(
            af[mt], bq[nt], acc[mt][nt], 0, 0, 0);
    __syncthreads();
  }
  const int fq = lane >> 4;
#pragma unroll
  for (int mt = 0; mt < 4; ++mt) {
#pragma unroll
    for (int nt = 0; nt < 4; ++nt) {
      const long c = col0 + wn + nt * 16 + fr;
      if (c < N) {
        const long rb = row0 + wm + mt * 16 + fq * 4;
#pragma unroll
        for (int rg = 0; rg < 4; ++rg)
          ep_store<EP>(acc[mt][nt][rg], rb + rg, c, ldc, Co, Cob, bias, e0f, e0b);
      }
    }
  }
}

// ---------------- GEMM v3 (128x128, counted vmcnt, swizzled dbuf) ----------

template <int EP>
__global__ __launch_bounds__(256)
void gemm3(const unsigned short* __restrict__ A, long lda,
           const unsigned short* __restrict__ Bt, long ldb, long K, long ldc,
           float* __restrict__ Co, unsigned short* __restrict__ Cob,
           const float* __restrict__ e0f) {
  __shared__ unsigned short As[2][4096];
  __shared__ unsigned short Bs[2][4096];
  const int tid = threadIdx.x;
  const int wid = tid >> 6, lane = tid & 63;
  const long row0 = (long)blockIdx.x * 128, col0 = (long)blockIdx.y * 128;
  const int wm = (wid >> 1) * 64, wn = (wid & 1) * 64;
  f32x4 acc[4][4] = {};
  const int srow = tid >> 2;
  const int scol = 8 * ((tid & 3) ^ (srow & 3));
  const unsigned short* gA = A + (row0 + srow) * lda + scol;
  const unsigned short* gB = Bt + (col0 + srow) * ldb + scol;
  const int fr = lane & 15, fc = lane >> 4;

#define STAGE3(buf, kb)                                         \
  {                                                             \
    gload16(gA + (kb), &As[buf][0] + wid * 512);                \
    gload16(gA + (kb) + 64 * lda, &As[buf][2048] + wid * 512);  \
    gload16(gB + (kb), &Bs[buf][0] + wid * 512);                \
    gload16(gB + (kb) + 64 * ldb, &Bs[buf][2048] + wid * 512);  \
  }

  STAGE3(0, 0)
  const int NT = (int)(K >> 5);
  int cur = 0;
  for (int kt = 0; kt < NT; ++kt) {
    if (kt + 1 < NT) {
      STAGE3(cur ^ 1, (long)(kt + 1) * 32)
      asm volatile("s_waitcnt vmcnt(4)" ::: "memory");
    } else {
      asm volatile("s_waitcnt vmcnt(0)" ::: "memory");
    }
    __builtin_amdgcn_s_barrier();
    asm volatile("" ::: "memory");
    bf16x8 af[4], bq[4];
#pragma unroll
    for (int mt = 0; mt < 4; ++mt) {
      const int r = wm + mt * 16 + fr;
      af[mt] = *(const bf16x8*)(&As[cur][0] + r * 32 + ((fc ^ (r & 3)) * 8));
    }
#pragma unroll
    for (int nt = 0; nt < 4; ++nt) {
      const int r = wn + nt * 16 + fr;
      bq[nt] = *(const bf16x8*)(&Bs[cur][0] + r * 32 + ((fc ^ (r & 3)) * 8));
    }
    __builtin_amdgcn_s_setprio(1);
#pragma unroll
    for (int mt = 0; mt < 4; ++mt)
#pragma unroll
      for (int nt = 0; nt < 4; ++nt)
        acc[mt][nt] = __builtin_amdgcn_mfma_f32_16x16x32_bf16(
            af[mt], bq[nt], acc[mt][nt], 0, 0, 0);
    __builtin_amdgcn_s_setprio(0);
    asm volatile("" ::: "memory");
    __builtin_amdgcn_s_barrier();
    cur ^= 1;
  }
#undef STAGE3
  const int fq = lane >> 4;
#pragma unroll
  for (int mt = 0; mt < 4; ++mt) {
#pragma unroll
    for (int nt = 0; nt < 4; ++nt) {
      const long c = col0 + wn + nt * 16 + fr;
      const long rb = row0 + wm + mt * 16 + fq * 4;
#pragma unroll
      for (int rg = 0; rg < 4; ++rg)
        ep_store<EP>(acc[mt][nt][rg], rb + rg, c, ldc, Co, Cob, nullptr, e0f,
                     nullptr);
    }
  }
}

// ---------------- GEMM 8-phase 256x256 (FFN-up only) -----------------------

template <int EP>
__global__ __launch_bounds__(512)
void gemm8p(const unsigned short* __restrict__ A, long lda,
            const unsigned short* __restrict__ Bt, long ldb, long K, long ldc,
            float* __restrict__ Co, unsigned short* __restrict__ Cob,
            const float* __restrict__ e0f) {
  __shared__ unsigned short lds[65536];  // 128KB
  const int tid = threadIdx.x;
  const int wid = tid >> 6, lane = tid & 63;
  const long row0 = (long)blockIdx.x * 256, col0 = (long)blockIdx.y * 256;
  const int wrow = (wid >> 2) * 64;
  const int wcol = (wid & 3) * 32;
  const int fr = lane & 15, fc = lane >> 4;
  f32x4 acc[2][4][2][2] = {};

  const int sr0 = tid >> 3;
  int sce = (tid & 7) * 8;
  sce ^= ((sr0 >> 2) & 1) << 4;
  const unsigned short* gA = A + (row0 + sr0) * lda + sce;
  const unsigned short* gB = Bt + (col0 + sr0) * ldb + sce;

#define STG8(half, src, ld, kb, buf)                                     \
  {                                                                      \
    const unsigned short* s_ = (src) + (kb);                             \
    unsigned short* d_ = lds + (buf) * 32768 + (half) * 8192 + tid * 8;  \
    gload16(s_, d_);                                                     \
    gload16(s_ + 64 * (ld), d_ + 4096);                                  \
  }

  STG8(0, gA, lda, 0, 0)
  STG8(2, gB, ldb, 0, 0)
  STG8(1, gA + 128 * lda, lda, 0, 0)
  STG8(3, gB + 128 * ldb, ldb, 0, 0)
  asm volatile("s_waitcnt vmcnt(0)" ::: "memory");
  __builtin_amdgcn_s_barrier();

  const int NT = (int)(K >> 6);
  int cur = 0;

#define PHASE8(P, KT)                                                         \
  {                                                                           \
    constexpr int mh = (P) >> 1, nh = (P) & 1;                                \
    const int bb = cur * 32768;                                               \
    bf16x8 af[4][2], bq[2][2];                                                \
    _Pragma("unroll") for (int mt = 0; mt < 4; ++mt)                          \
      _Pragma("unroll") for (int ks = 0; ks < 2; ++ks) {                      \
        const int r = wrow + mt * 16 + fr;                                    \
        const int e = (ks * 32 + fc * 8) ^ (((r >> 2) & 1) << 4);             \
        af[mt][ks] = *(const bf16x8*)(lds + bb + mh * 8192 + r * 64 + e);     \
      }                                                                       \
    _Pragma("unroll") for (int nt = 0; nt < 2; ++nt)                          \
      _Pragma("unroll") for (int ks = 0; ks < 2; ++ks) {                      \
        const int r = wcol + nt * 16 + fr;                                    \
        const int e = (ks * 32 + fc * 8) ^ (((r >> 2) & 1) << 4);             \
        bq[nt][ks] =                                                          \
            *(const bf16x8*)(lds + bb + 16384 + nh * 8192 + r * 64 + e);      \
      }                                                                       \
    if ((KT) + 1 < NT) {                                                      \
      const long kb_ = (long)((KT) + 1) * 64;                                 \
      if constexpr ((P) == 0) STG8(0, gA, lda, kb_, cur ^ 1)                  \
      else if constexpr ((P) == 1) STG8(2, gB, ldb, kb_, cur ^ 1)             \
      else if constexpr ((P) == 2) STG8(1, gA + 128 * lda, lda, kb_, cur ^ 1) \
      else STG8(3, gB + 128 * ldb, ldb, kb_, cur ^ 1)                         \
    }                                                                         \
    if constexpr ((P) == 0) asm volatile("s_waitcnt vmcnt(2)" ::: "memory");  \
    if constexpr ((P) == 3) asm volatile("s_waitcnt vmcnt(4)" ::: "memory");  \
    __builtin_amdgcn_s_barrier();                                             \
    asm volatile("s_waitcnt lgkmcnt(0)" ::: "memory");                        \
    __builtin_amdgcn_s_setprio(1);                                            \
    _Pragma("unroll") for (int mt = 0; mt < 4; ++mt)                          \
      _Pragma("unroll") for (int nt = 0; nt < 2; ++nt)                        \
        _Pragma("unroll") for (int ks = 0; ks < 2; ++ks)                      \
          acc[mh][mt][nh][nt] = __builtin_amdgcn_mfma_f32_16x16x32_bf16(      \
              af[mt][ks], bq[nt][ks], acc[mh][mt][nh][nt], 0, 0, 0);          \
    __builtin_amdgcn_s_setprio(0);                                            \
    asm volatile("" ::: "memory");                                            \
    __builtin_amdgcn_s_barrier();                                             \
  }

  for (int kt = 0; kt < NT; ++kt) {
    PHASE8(0, kt)
    PHASE8(1, kt)
    PHASE8(2, kt)
    PHASE8(3, kt)
    cur ^= 1;
  }
#undef PHASE8
#undef STG8

  const int fq = lane >> 4;
#pragma unroll
  for (int mh = 0; mh < 2; ++mh)
#pragma unroll
    for (int mt = 0; mt < 4; ++mt)
#pragma unroll
      for (int nh = 0; nh < 2; ++nh)
#pragma unroll
        for (int nt = 0; nt < 2; ++nt) {
          const long c = col0 + nh * 128 + wcol + nt * 16 + fr;
          const long rb = row0 + mh * 128 + wrow + mt * 16 + fq * 4;
#pragma unroll
          for (int rg = 0; rg < 4; ++rg)
            ep_store<EP>(acc[mh][mt][nh][nt][rg], rb + rg, c, ldc, Co, Cob,
                         nullptr, e0f, nullptr);
        }
}

// ---------------- gemm_up128: Hact[4096][288] @ Wup^T[8192][288] -----------

__global__ __launch_bounds__(256)
void gemm_up128(const unsigned short* __restrict__ A,
                const unsigned short* __restrict__ Bt,
                float* __restrict__ whb, unsigned short* __restrict__ abuf,
                unsigned short* __restrict__ vfb, unsigned short* __restrict__ gbuf,
                const float* __restrict__ w0, const float* __restrict__ a0,
                const float* __restrict__ v0,
                const unsigned short* __restrict__ vraw,
                const float* __restrict__ vfirst) {
  __shared__ unsigned short As[2][4096];
  __shared__ unsigned short Bs[2][4096];
  const int tid = threadIdx.x;
  const int wid = tid >> 6, lane = tid & 63;
  const long row0 = (long)blockIdx.x * 128, col0 = (long)blockIdx.y * 128;
  const int wm = (wid >> 1) * 64, wn = (wid & 1) * 64;
  f32x4 acc[4][4] = {};
  const int srow = tid >> 2;
  const int scol = 8 * ((tid & 3) ^ (srow & 3));
  const unsigned short* gA = A + (row0 + srow) * 288 + scol;
  const unsigned short* gB = Bt + (col0 + srow) * 288 + scol;
  const int fr = lane & 15, fc = lane >> 4;

#define STAGEU(buf, kb)                                         \
  {                                                             \
    gload16(gA + (kb), &As[buf][0] + wid * 512);                \
    gload16(gA + (kb) + 64 * 288, &As[buf][2048] + wid * 512);  \
    gload16(gB + (kb), &Bs[buf][0] + wid * 512);                \
    gload16(gB + (kb) + 64 * 288, &Bs[buf][2048] + wid * 512);  \
  }

  STAGEU(0, 0)
  int cur = 0;
  for (int kt = 0; kt < 9; ++kt) {
    if (kt + 1 < 9) {
      STAGEU(cur ^ 1, (long)(kt + 1) * 32)
      asm volatile("s_waitcnt vmcnt(4)" ::: "memory");
    } else {
      asm volatile("s_waitcnt vmcnt(0)" ::: "memory");
    }
    __builtin_amdgcn_s_barrier();
    asm volatile("" ::: "memory");
    bf16x8 af[4], bq[4];
#pragma unroll
    for (int mt = 0; mt < 4; ++mt) {
      const int r = wm + mt * 16 + fr;
      af[mt] = *(const bf16x8*)(&As[cur][0] + r * 32 + ((fc ^ (r & 3)) * 8));
    }
#pragma unroll
    for (int nt = 0; nt < 4; ++nt) {
      const int r = wn + nt * 16 + fr;
      bq[nt] = *(const bf16x8*)(&Bs[cur][0] + r * 32 + ((fc ^ (r & 3)) * 8));
    }
    __builtin_amdgcn_s_setprio(1);
#pragma unroll
    for (int mt = 0; mt < 4; ++mt)
#pragma unroll
      for (int nt = 0; nt < 4; ++nt)
        acc[mt][nt] = __builtin_amdgcn_mfma_f32_16x16x32_bf16(
            af[mt], bq[nt], acc[mt][nt], 0, 0, 0);
    __builtin_amdgcn_s_setprio(0);
    asm volatile("" ::: "memory");
    __builtin_amdgcn_s_barrier();
    cur ^= 1;
  }
#undef STAGEU
  const int fq = lane >> 4;
  const int p = (int)(blockIdx.y >> 4);
#pragma unroll
  for (int mt = 0; mt < 4; ++mt) {
#pragma unroll
    for (int nt = 0; nt < 4; ++nt) {
      const long c = col0 + wn + nt * 16 + fr;
      const long cc = c & 2047;
      const long rb = row0 + wm + mt * 16 + fq * 4;
#pragma unroll
      for (int rg = 0; rg < 4; ++rg) {
        const float av = acc[mt][nt][rg];
        const long idx = (rb + rg) * 2048 + cc;
        if (p == 0) {
          const float wv = w0[cc] + av;
          const float sp = log1pf(expf(-wv));
          whb[idx] = expf(-expf(-sp - 0.5f));
        } else if (p == 1) {
          abuf[idx] = f2b(1.f / (1.f + expf(-(a0[cc] + av))));
        } else if (p == 2) {
          const float s = 1.f / (1.f + expf(-(v0[cc] + av)));
          const float vv = b2f(vraw[idx]);
          vfb[idx] = f2b(vv + (vfirst[idx] - vv) * s);
        } else {
          gbuf[idx] = f2b(av);  // g = sigmoid(xg@g1) @ g2 -- NO outer act
        }
      }
    }
  }
}

// ------------------------------ k_post -------------------------------------
__global__ __launch_bounds__(256)
void k_post(unsigned short* __restrict__ kio, unsigned short* __restrict__ abio,
            unsigned short* __restrict__ aao, const float* __restrict__ kkw,
            const float* __restrict__ kaw) {
  const int m = blockIdx.x, tid = threadIdx.x;
  const size_t base = (size_t)m * 2048 + tid * 8;
  us8 k8 = *(const us8*)(kio + base);
  us8 a8 = *(const us8*)(abio + base);
  float kk8[8], ka8[8];
  *(float4*)&kk8[0] = *(const float4*)(kkw + tid * 8);
  *(float4*)&kk8[4] = *(const float4*)(kkw + tid * 8 + 4);
  *(float4*)&ka8[0] = *(const float4*)(kaw + tid * 8);
  *(float4*)&ka8[4] = *(const float4*)(kaw + tid * 8 + 4);
  float kx[8], kv[8], av[8];
  float ss = 0.f;
#pragma unroll
  for (int i = 0; i < 8; ++i) {
    kv[i] = b2f(k8[i]); av[i] = b2f(a8[i]);
    kx[i] = kv[i] * kk8[i]; ss += kx[i] * kx[i];
  }
  ss = red8(ss);
  const float inv = 1.f / fmaxf(sqrtf(ss), 1e-12f);
  us8 kh8, aa8, bb8;
#pragma unroll
  for (int i = 0; i < 8; ++i) {
    const float kkn = kx[i] * inv;
    kh8[i] = f2b(kv[i] * (1.f + (av[i] - 1.f) * ka8[i]));
    aa8[i] = f2b(-kkn);
    bb8[i] = f2b(kkn * av[i]);
  }
  *(us8*)(kio + base) = kh8;
  *(us8*)(aao + base) = aa8;
  *(us8*)(abio + base) = bb8;
}

// ------------------------------ WKV scan (R11) ------------------------------

DEV float red16(float x) {  // all-lanes sum within each 16-lane row
  union { float f; int i; } a, r;
  a.f = x; r.i = __builtin_amdgcn_update_dpp(0, a.i, 0xB1, 0xf, 0xf, true);
  x += r.f;
  a.f = x; r.i = __builtin_amdgcn_update_dpp(0, a.i, 0x4E, 0xf, 0xf, true);
  x += r.f;
  a.f = x; r.i = __builtin_amdgcn_update_dpp(0, a.i, 0x124, 0xf, 0xf, true);
  x += r.f;
  a.f = x; r.i = __builtin_amdgcn_update_dpp(0, a.i, 0x128, 0xf, 0xf, true);
  x += r.f;
  return x;
}

DEV void cv4(const uint2 q, float* o) {
  union { unsigned u; float f; } t;
  t.u = q.x << 16;          o[0] = t.f;
  t.u = q.x & 0xffff0000u;  o[1] = t.f;
  t.u = q.y << 16;          o[2] = t.f;
  t.u = q.y & 0xffff0000u;  o[3] = t.f;
}

__global__ __launch_bounds__(64)
void k_scan(const unsigned short* __restrict__ rp,
            const unsigned short* __restrict__ kp,
            const unsigned short* __restrict__ vp,
            const float* __restrict__ wp,
            const unsigned short* __restrict__ ap,
            const unsigned short* __restrict__ bp,
            const float* __restrict__ s0, unsigned short* __restrict__ yout,
            float* __restrict__ snew) {
  __shared__ float4 slots[8][49];
  __shared__ unsigned short ylds[1024][4];
  const int lane = threadIdx.x;
  const int bh = blockIdx.x & 127;
  const int rq = blockIdx.x >> 7;
  const int b = bh >> 5, h = bh & 31;
  const int kg = lane & 15, rl = lane >> 4;
  const int v = rq * 4 + rl, ks = kg * 4;
  const size_t off_bh = (size_t)b * 1024 * 2048 + (size_t)h * 64;
  const int vfo = 768 + ((rq & 1) * 4 + rl) * 2;

  float S[4];
  *(float4*)&S[0] = *(const float4*)(s0 + (((size_t)bh * 64 + v) * 64 + ks));

  const char* gp = nullptr;
  size_t gstep = 0;
  if (lane < 49) {
    if (lane < 32) {
      const int arr = lane >> 3, sub = lane & 7;
      const unsigned short* base = arr == 0 ? rp : arr == 1 ? kp
                                 : arr == 2 ? ap : bp;
      gp = (const char*)(base + off_bh + sub * 8);
      gstep = 4096;
    } else if (lane < 48) {
      gp = (const char*)(wp + off_bh + (lane - 32) * 4);
      gstep = 8192;
    } else {
      gp = (const char*)(vp + off_bh + (rq & ~1) * 4);
      gstep = 4096;
    }
  }
#pragma unroll
  for (int s = 0; s < 8; ++s) {
    if (lane < 49) gload16(gp, &slots[s][0]);
    gp += gstep;
  }

  uint2 rA, kA, aA, bA, rB, kB, aB, bB;
  float4 wA, wB;
  unsigned short fA, fB;
  asm volatile("s_waitcnt vmcnt(7)" ::: "memory");
  {
    const char* nb = (const char*)&slots[0][0];
    rA = *(const uint2*)(nb + kg * 8);
    kA = *(const uint2*)(nb + 128 + kg * 8);
    aA = *(const uint2*)(nb + 256 + kg * 8);
    bA = *(const uint2*)(nb + 384 + kg * 8);
    wA = *(const float4*)(nb + 512 + kg * 16);
    fA = *(const unsigned short*)(nb + vfo);
  }

#define SSTEP(T, Cr, Ck, Ca, Cb, Cw, Cf, Nr, Nk, Na, Nb, Nw, Nf)             \
  {                                                                          \
    asm volatile("s_waitcnt lgkmcnt(0)" ::: "memory");                       \
    if (lane < 49) gload16(gp, &slots[(T) & 7][0]);                          \
    if ((T) < 1015) gp += gstep;                                             \
    asm volatile("s_waitcnt vmcnt(7)" ::: "memory");                         \
    const char* nb = (const char*)&slots[((T) + 1) & 7][0];                  \
    Nr = *(const uint2*)(nb + kg * 8);                                       \
    Nk = *(const uint2*)(nb + 128 + kg * 8);                                 \
    Na = *(const uint2*)(nb + 256 + kg * 8);                                 \
    Nb = *(const uint2*)(nb + 384 + kg * 8);                                 \
    Nw = *(const float4*)(nb + 512 + kg * 16);                               \
    Nf = *(const unsigned short*)(nb + vfo);                                 \
    float rr[4], kk[4], av[4], bv[4];                                        \
    cv4(Cr, rr); cv4(Ck, kk); cv4(Ca, av); cv4(Cb, bv);                      \
    const float vv = b2f(Cf);                                                \
    float sa = S[0] * av[0] + S[1] * av[1] + S[2] * av[2] + S[3] * av[3];    \
    sa = red16(sa);                                                          \
    float y;                                                                 \
    S[0] = S[0] * Cw.x + sa * bv[0] + vv * kk[0]; y  = S[0] * rr[0];         \
    S[1] = S[1] * Cw.y + sa * bv[1] + vv * kk[1]; y += S[1] * rr[1];         \
    S[2] = S[2] * Cw.z + sa * bv[2] + vv * kk[2]; y += S[2] * rr[2];         \
    S[3] = S[3] * Cw.w + sa * bv[3] + vv * kk[3]; y += S[3] * rr[3];         \
    y = red16(y);                                                            \
    if (kg == 0) ylds[T][rl] = f2b(y);                                       \
  }

  for (int tb = 0; tb < 1024; tb += 2) {
    SSTEP(tb + 0, rA, kA, aA, bA, wA, fA, rB, kB, aB, bB, wB, fB)
    SSTEP(tb + 1, rB, kB, aB, bB, wB, fB, rA, kA, aA, bA, wA, fA)
  }
#undef SSTEP

  *(float4*)(snew + (((size_t)bh * 64 + v) * 64 + ks)) = *(const float4*)&S[0];
  asm volatile("s_waitcnt lgkmcnt(0)" ::: "memory");
#pragma unroll 4
  for (int it = 0; it < 16; ++it) {
    const int t = lane + it * 64;
    const uint2 val = *(const uint2*)&ylds[t][0];
    *(uint2*)(yout + off_bh + (size_t)t * 2048 + rq * 4) = val;
  }
}

// ---------------------- GroupNorm + resid + gate ---------------------------

__global__ __launch_bounds__(256)
void k_gn(const unsigned short* __restrict__ y, const unsigned short* __restrict__ r,
          const unsigned short* __restrict__ kh, const unsigned short* __restrict__ vf,
          const unsigned short* __restrict__ g, const float* __restrict__ rk,
          const float* __restrict__ lw, const float* __restrict__ lb,
          unsigned short* __restrict__ ywg) {
  const int m = blockIdx.x, tid = threadIdx.x;
  const size_t base = (size_t)m * 2048 + tid * 8;
  us8 y8 = *(const us8*)(y + base);
  us8 r8 = *(const us8*)(r + base);
  us8 k8 = *(const us8*)(kh + base);
  us8 v8 = *(const us8*)(vf + base);
  us8 g8 = *(const us8*)(g + base);
  float yv[8];
  float rkv[8];
  *(float4*)&rkv[0] = *(const float4*)(rk + tid * 8);
  *(float4*)&rkv[4] = *(const float4*)(rk + tid * 8 + 4);
  float sy = 0.f, sd = 0.f;
#pragma unroll
  for (int i = 0; i < 8; ++i) {
    yv[i] = b2f(y8[i]);
    sy += yv[i];
    sd += b2f(r8[i]) * b2f(k8[i]) * rkv[i];
  }
  sy = red8(sy);
  sd = red8(sd);
  const float mu = sy * (1.f / 64.f);
  float sq = 0.f;
#pragma unroll
  for (int i = 0; i < 8; ++i) { const float d = yv[i] - mu; sq += d * d; }
  sq = red8(sq);
  const float rstd = rsqrtf(sq * (1.f / 64.f) + 64e-5f);
  us8 o8;
#pragma unroll
  for (int i = 0; i < 8; ++i) {
    const int c = tid * 8 + i;
    const float gn = (yv[i] - mu) * rstd * lw[c] + lb[c];
    o8[i] = f2b((gn + sd * b2f(v8[i])) * b2f(g8[i]));
  }
  *(us8*)(ywg + base) = o8;
}

// ------------------------------ launch -------------------------------------

extern "C" void kernel_launch(void* const* d_in, const int* in_sizes, int n_in,
                              void* d_out, int out_size, void* d_ws,
                              size_t ws_size, hipStream_t stream) {
  (void)in_sizes; (void)n_in; (void)out_size; (void)ws_size;
  const float* x         = (const float*)d_in[0];
  const float* v_first   = (const float*)d_in[1];
  const float* att_shift = (const float*)d_in[2];
  const float* ffn_shift = (const float*)d_in[3];
  const float* wkv0      = (const float*)d_in[4];
  const float* ln1w = (const float*)d_in[5];
  const float* ln1b = (const float*)d_in[6];
  const float* ln2w = (const float*)d_in[7];
  const float* ln2b = (const float*)d_in[8];
  const float* x_r = (const float*)d_in[9];
  const float* x_w = (const float*)d_in[10];
  const float* x_k = (const float*)d_in[11];
  const float* x_v = (const float*)d_in[12];
  const float* x_a = (const float*)d_in[13];
  const float* x_g = (const float*)d_in[14];
  const float* Wr = (const float*)d_in[15];
  const float* Wk = (const float*)d_in[16];
  const float* Wv = (const float*)d_in[17];
  const float* Wo = (const float*)d_in[18];
  const float* w0 = (const float*)d_in[19];
  const float* w1 = (const float*)d_in[20];
  const float* w2 = (const float*)d_in[21];
  const float* v0 = (const float*)d_in[22];
  const float* v1 = (const float*)d_in[23];
  const float* v2 = (const float*)d_in[24];
  const float* a0 = (const float*)d_in[25];
  const float* a1 = (const float*)d_in[26];
  const float* a2 = (const float*)d_in[27];
  const float* g1 = (const float*)d_in[28];
  const float* g2 = (const float*)d_in[29];
  const float* k_k = (const float*)d_in[30];
  const float* k_a = (const float*)d_in[31];
  const float* r_k = (const float*)d_in[32];
  const float* lnxw = (const float*)d_in[33];
  const float* lnxb = (const float*)d_in[34];
  const float* ffn_xk = (const float*)d_in[35];
  const float* Wkf = (const float*)d_in[36];
  const float* Wvf = (const float*)d_in[37];

  char* ws = (char*)d_ws;
  constexpr size_t OFF_TWR   = 0;
  constexpr size_t OFF_TWK   = 8388608;
  constexpr size_t OFF_TWV   = 16777216;
  constexpr size_t OFF_TWO   = 25165824;
  constexpr size_t OFF_TWCAT = 34734080;
  constexpr size_t OFF_HACT  = 37879808;
  constexpr size_t OFF_GBUF  = 40239104;
  constexpr size_t OFF_WH    = 57016320;
  constexpr size_t OFF_R     = 90570752;
  constexpr size_t OFF_KH    = 107347968;
  constexpr size_t OFF_VF    = 124125184;
  constexpr size_t OFF_AA    = 140902400;
  constexpr size_t OFF_BB    = 157679616;
  constexpr size_t OFF_TWUP  = 174456832;  // [8192][288] bf16, 4.7MB

  unsigned short* tWr = (unsigned short*)(ws + OFF_TWR);
  unsigned short* tWk = (unsigned short*)(ws + OFF_TWK);
  unsigned short* tWv = (unsigned short*)(ws + OFF_TWV);
  unsigned short* tWo = (unsigned short*)(ws + OFF_TWO);
  unsigned short* tWcat = (unsigned short*)(ws + OFF_TWCAT);
  unsigned short* Hact  = (unsigned short*)(ws + OFF_HACT);
  unsigned short* gbuf  = (unsigned short*)(ws + OFF_GBUF);
  unsigned short* tWvfh = (unsigned short*)(ws + OFF_GBUF);
  unsigned short* act2  = (unsigned short*)(ws + OFF_WH);
  float*          whb   = (float*)(ws + OFF_WH);
  unsigned short* ywg   = (unsigned short*)(ws + OFF_WH);
  unsigned short* kf    = (unsigned short*)(ws + OFF_WH);
  unsigned short* bxr   = (unsigned short*)(ws + OFF_AA);
  unsigned short* bxk   = (unsigned short*)(ws + OFF_BB);
  unsigned short* bxv   = (unsigned short*)(ws + OFF_VF);
  unsigned short* rbuf  = (unsigned short*)(ws + OFF_R);
  unsigned short* khb   = (unsigned short*)(ws + OFF_KH);
  unsigned short* vfb   = (unsigned short*)(ws + OFF_VF);
  unsigned short* aab   = (unsigned short*)(ws + OFF_AA);
  unsigned short* bbb   = (unsigned short*)(ws + OFF_BB);
  unsigned short* vraw  = (unsigned short*)(ws + OFF_AA);
  unsigned short* abuf  = (unsigned short*)(ws + OFF_BB);
  float*          x1    = (float*)(ws + OFF_R);
  unsigned short* xkf   = (unsigned short*)(ws + OFF_VF);
  unsigned short* tWkf  = (unsigned short*)(ws + OFF_AA);
  unsigned short* tWup  = (unsigned short*)(ws + OFF_TWUP);
  float* out = (float*)d_out;
  float* snew = out + 8388608;

  const dim3 tb(32, 8);
  // ---- weight prep (merged launches) ----
  k_transpose4<<<dim3(64, 64, 4), tb, 0, stream>>>(Wr, Wk, Wv, Wo,
                                                   tWr, tWk, tWv, tWo);
  k_prep<<<15360, 256, 0, stream>>>(w1, a1, v1, g1, x_w, x_a, x_v, x_g,
                                    w2, a2, v2, g2, tWcat, tWup);

  // ---- TimeMix front ----
  k_ln1_mix<<<4096, 256, 0, stream>>>(x, att_shift, ln1w, ln1b, x_r, x_k, x_v,
                                      act2, bxr, bxk, bxv);
  gemm3<EP_B16><<<dim3(32, 16), 256, 0, stream>>>(
      bxr, 2048, tWr, 2048, 2048, 2048, nullptr, rbuf, nullptr);
  gemm3<EP_B16><<<dim3(32, 16), 256, 0, stream>>>(
      bxk, 2048, tWk, 2048, 2048, 2048, nullptr, khb, nullptr);
  gemm3<EP_B16><<<dim3(32, 16), 256, 0, stream>>>(
      bxv, 2048, tWv, 2048, 2048, 2048, nullptr, vraw, nullptr);
  gemm_bt<EP_HACT><<<dim3(32, 3), 256, 0, stream>>>(
      act2, 4096, tWcat, 4096, 288, 4096, 288, nullptr, Hact, nullptr, nullptr, nullptr);
  gemm_up128<<<dim3(32, 64), 256, 0, stream>>>(
      Hact, tWup, whb, abuf, vfb, gbuf, w0, a0, v0, vraw, v_first);
  k_post<<<4096, 256, 0, stream>>>(khb, abuf, aab, k_k, k_a);

  // ---- WKV scan ----
  k_scan<<<2048, 64, 0, stream>>>(rbuf, khb, vfb, whb, aab, bbb, wkv0,
                                  (unsigned short*)out, snew);
  k_gn<<<4096, 256, 0, stream>>>((const unsigned short*)out, rbuf, khb, vfb,
                                 gbuf, r_k, lnxw, lnxb, ywg);

  // ---- Wo projection (+x) -> x1 ----
  gemm3<EP_ADDF><<<dim3(32, 16), 256, 0, stream>>>(
      ywg, 2048, tWo, 2048, 2048, 2048, x1, nullptr, x);

  // ---- ChannelMix (two DFF halves) ----
  k_ln2_mix<<<4096, 256, 0, stream>>>(x1, ffn_shift, ln2w, ln2b, ffn_xk, xkf);
  k_transpose<<<dim3(256, 64), tb, 0, stream>>>(Wkf, tWkf, 2048, 8192);
  gemm8p<EP_RELU2><<<dim3(16, 16), 512, 0, stream>>>(
      xkf, 2048, tWkf, 2048, 2048, 4096, nullptr, kf, nullptr);
  k_transpose<<<dim3(64, 128), tb, 0, stream>>>(Wvf, tWvfh, 4096, 2048);
  gemm3<EP_ADDF><<<dim3(32, 16), 256, 0, stream>>>(
      kf, 4096, tWvfh, 4096, 4096, 2048, out, nullptr, x1);
  gemm8p<EP_RELU2><<<dim3(16, 16), 512, 0, stream>>>(
      xkf, 2048, tWkf + (size_t)4096 * 2048, 2048, 2048, 4096, nullptr, kf, nullptr);
  k_transpose<<<dim3(64, 128), tb, 0, stream>>>(Wvf + (size_t)4096 * 2048, tWvfh,
                                                4096, 2048);
  gemm3<EP_ADDF><<<dim3(32, 16), 256, 0, stream>>>(
      kf, 4096, tWvfh, 4096, 4096, 2048, out, nullptr, out);
}

// Round 16
// 1230.502 us; speedup vs baseline: 1.0561x; 1.0287x over previous
//
#include <hip/hip_runtime.h>
#include <cstdint>

// ---------------------------------------------------------------------------
// RWKV7 block (B=4,T=1024,C=2048,H=32,N=64,DFF=8192) for MI355X gfx950.
// R16: QKV GEMMs merged into one launch (gemm3_qkv, blockIdx.z selects);
//      Wcat GEMM moved from gemm_bt to the gemm3 schedule with N-masked
//      epilogue (gemm3h). All other kernels = R15 (best, 1266us).
// ---------------------------------------------------------------------------

typedef __attribute__((ext_vector_type(4))) float f32x4;
typedef __attribute__((ext_vector_type(8))) __bf16 bf16x8;
typedef __attribute__((ext_vector_type(8))) unsigned short us8;

#define DEV __device__ __forceinline__

DEV unsigned short f2b(float f) {
  union { float f; unsigned u; } v; v.f = f;
  unsigned r = v.u + 0x7fffu + ((v.u >> 16) & 1u);
  return (unsigned short)(r >> 16);
}
DEV float b2f(unsigned short u) {
  union { unsigned u; float f; } v; v.u = (unsigned)u << 16;
  return v.f;
}

DEV void gload16(const void* g, void* l) {
  void* gg = const_cast<void*>(g);
  __builtin_amdgcn_global_load_lds(
      (__attribute__((address_space(1))) unsigned int*)gg,
      (__attribute__((address_space(3))) unsigned int*)l, 16, 0, 0);
}

DEV float red8(float v) {  // sum over aligned 8-lane group
  v += __shfl_xor(v, 1);
  v += __shfl_xor(v, 2);
  v += __shfl_xor(v, 4);
  return v;
}

// ------------------------------ weight prep --------------------------------

__global__ void k_transpose4(const float* __restrict__ s0,
                             const float* __restrict__ s1,
                             const float* __restrict__ s2,
                             const float* __restrict__ s3,
                             unsigned short* __restrict__ d0,
                             unsigned short* __restrict__ d1,
                             unsigned short* __restrict__ d2,
                             unsigned short* __restrict__ d3) {
  __shared__ float tile[32][33];
  const int z = blockIdx.z;
  const float* src = z == 0 ? s0 : z == 1 ? s1 : z == 2 ? s2 : s3;
  unsigned short* dst = z == 0 ? d0 : z == 1 ? d1 : z == 2 ? d2 : d3;
  const int c0 = blockIdx.x * 32, r0 = blockIdx.y * 32;
  const int tx = threadIdx.x, ty = threadIdx.y;  // block (32,8)
  for (int i = ty; i < 32; i += 8)
    tile[i][tx] = src[(size_t)(r0 + i) * 2048 + c0 + tx];
  __syncthreads();
  for (int i = ty; i < 32; i += 8)
    dst[(size_t)(c0 + i) * 2048 + r0 + tx] = f2b(tile[tx][i]);
}

__global__ void k_transpose(const float* __restrict__ src,
                            unsigned short* __restrict__ dst, int R, int Cc) {
  __shared__ float tile[32][33];
  const int c0 = blockIdx.x * 32, r0 = blockIdx.y * 32;
  const int tx = threadIdx.x, ty = threadIdx.y;  // block (32,8)
  for (int i = ty; i < 32; i += 8)
    tile[i][tx] = src[(size_t)(r0 + i) * Cc + c0 + tx];
  __syncthreads();
  for (int i = ty; i < 32; i += 8)
    dst[(size_t)(c0 + i) * R + r0 + tx] = f2b(tile[tx][i]);
}

// Merged: Wcat^T [384][4096] + Wup^T [8192][288].
__global__ void k_prep(const float* __restrict__ w1, const float* __restrict__ a1,
                       const float* __restrict__ v1, const float* __restrict__ g1,
                       const float* __restrict__ xw, const float* __restrict__ xa,
                       const float* __restrict__ xv, const float* __restrict__ xg,
                       const float* __restrict__ w2, const float* __restrict__ a2,
                       const float* __restrict__ v2, const float* __restrict__ g2,
                       unsigned short* __restrict__ dcat,
                       unsigned short* __restrict__ dup) {
  int i = blockIdx.x * 256 + threadIdx.x;
  if (i < 384 * 4096) {
    const int j = i >> 12, c = i & 4095;
    float val = 0.f;
    if (j < 288) {
      const float* W; const float* mix; int jj, D;
      if (j < 64)       { W = w1; mix = xw; jj = j;       D = 64;  }
      else if (j < 128) { W = a1; mix = xa; jj = j - 64;  D = 64;  }
      else if (j < 160) { W = v1; mix = xv; jj = j - 128; D = 32;  }
      else              { W = g1; mix = xg; jj = j - 160; D = 128; }
      const int cc = c & 2047;
      val = W[(size_t)cc * D + jj];
      if (c >= 2048) val *= mix[cc];
    }
    dcat[i] = f2b(val);
    return;
  }
  i -= 384 * 4096;
  if (i >= 8192 * 288) return;
  const int n = i / 288, k = i - n * 288;
  const int p = n >> 11, j = n & 2047;
  float val = 0.f;
  if (p == 0)      { if (k < 64)              val = w2[(size_t)k * 2048 + j]; }
  else if (p == 1) { if (k >= 64 && k < 128)  val = a2[(size_t)(k - 64) * 2048 + j]; }
  else if (p == 2) { if (k >= 128 && k < 160) val = v2[(size_t)(k - 128) * 2048 + j]; }
  else             { if (k >= 160)            val = g2[(size_t)(k - 160) * 2048 + j]; }
  dup[i] = f2b(val);
}

// ------------------------------ LN + mix -----------------------------------

DEV void breduce2(float& a, float& b, float* rbuf) {
#pragma unroll
  for (int m = 1; m < 64; m <<= 1) { a += __shfl_xor(a, m); b += __shfl_xor(b, m); }
  const int wid = threadIdx.x >> 6, lane = threadIdx.x & 63;
  if (lane == 0) { rbuf[wid] = a; rbuf[4 + wid] = b; }
  __syncthreads();
  a = rbuf[0] + rbuf[1] + rbuf[2] + rbuf[3];
  b = rbuf[4] + rbuf[5] + rbuf[6] + rbuf[7];
  __syncthreads();
}

__global__ __launch_bounds__(256)
void k_ln1_mix(const float* __restrict__ x, const float* __restrict__ shift,
               const float* __restrict__ lw, const float* __restrict__ lb,
               const float* __restrict__ mr, const float* __restrict__ mk,
               const float* __restrict__ mv,
               unsigned short* __restrict__ A2, unsigned short* __restrict__ xrb,
               unsigned short* __restrict__ xkb, unsigned short* __restrict__ xvb) {
  __shared__ float rbuf[8];
  const int m = blockIdx.x, tid = threadIdx.x;
  const int b = m >> 10, t = m & 1023;
  const float* xt = x + (size_t)m * 2048 + tid * 8;
  const float* xp = (t > 0) ? (x + (size_t)(m - 1) * 2048 + tid * 8)
                            : (shift + (size_t)b * 2048 + tid * 8);
  float vt[8], vp[8];
  *(float4*)&vt[0] = *(const float4*)(xt);
  *(float4*)&vt[4] = *(const float4*)(xt + 4);
  *(float4*)&vp[0] = *(const float4*)(xp);
  *(float4*)&vp[4] = *(const float4*)(xp + 4);
  float st = 0.f, sp = 0.f;
#pragma unroll
  for (int i = 0; i < 8; ++i) { st += vt[i]; sp += vp[i]; }
  breduce2(st, sp, rbuf);
  const float mt_ = st * (1.f / 2048.f), mp_ = sp * (1.f / 2048.f);
  float qt = 0.f, qp = 0.f;
#pragma unroll
  for (int i = 0; i < 8; ++i) {
    float d0 = vt[i] - mt_; qt += d0 * d0;
    float d1 = vp[i] - mp_; qp += d1 * d1;
  }
  breduce2(qt, qp, rbuf);
  const float rt = rsqrtf(qt * (1.f / 2048.f) + 1e-5f);
  const float rp = rsqrtf(qp * (1.f / 2048.f) + 1e-5f);
  const bool lnp = (t > 0);
#pragma unroll
  for (int i = 0; i < 8; ++i) {
    const int c = tid * 8 + i;
    const float wv = lw[c], bv = lb[c];
    const float xn = (vt[i] - mt_) * rt * wv + bv;
    const float pn = lnp ? ((vp[i] - mp_) * rp * wv + bv) : vp[i];
    const float xx = pn - xn;
    A2[(size_t)m * 4096 + c] = f2b(xn);
    A2[(size_t)m * 4096 + 2048 + c] = f2b(xx);
    xrb[(size_t)m * 2048 + c] = f2b(xn + xx * mr[c]);
    xkb[(size_t)m * 2048 + c] = f2b(xn + xx * mk[c]);
    xvb[(size_t)m * 2048 + c] = f2b(xn + xx * mv[c]);
  }
}

__global__ __launch_bounds__(256)
void k_ln2_mix(const float* __restrict__ x1, const float* __restrict__ shift,
               const float* __restrict__ lw, const float* __restrict__ lb,
               const float* __restrict__ mk, unsigned short* __restrict__ xkf) {
  __shared__ float rbuf[8];
  const int m = blockIdx.x, tid = threadIdx.x;
  const int b = m >> 10, t = m & 1023;
  const float* xt = x1 + (size_t)m * 2048 + tid * 8;
  const float* xp = (t > 0) ? (x1 + (size_t)(m - 1) * 2048 + tid * 8)
                            : (shift + (size_t)b * 2048 + tid * 8);
  float vt[8], vp[8];
  *(float4*)&vt[0] = *(const float4*)(xt);
  *(float4*)&vt[4] = *(const float4*)(xt + 4);
  *(float4*)&vp[0] = *(const float4*)(xp);
  *(float4*)&vp[4] = *(const float4*)(xp + 4);
  float st = 0.f, sp = 0.f;
#pragma unroll
  for (int i = 0; i < 8; ++i) { st += vt[i]; sp += vp[i]; }
  breduce2(st, sp, rbuf);
  const float mt_ = st * (1.f / 2048.f), mp_ = sp * (1.f / 2048.f);
  float qt = 0.f, qp = 0.f;
#pragma unroll
  for (int i = 0; i < 8; ++i) {
    float d0 = vt[i] - mt_; qt += d0 * d0;
    float d1 = vp[i] - mp_; qp += d1 * d1;
  }
  breduce2(qt, qp, rbuf);
  const float rt = rsqrtf(qt * (1.f / 2048.f) + 1e-5f);
  const float rp = rsqrtf(qp * (1.f / 2048.f) + 1e-5f);
  const bool lnp = (t > 0);
#pragma unroll
  for (int i = 0; i < 8; ++i) {
    const int c = tid * 8 + i;
    const float wv = lw[c], bv = lb[c];
    const float xn = (vt[i] - mt_) * rt * wv + bv;
    const float pn = lnp ? ((vp[i] - mp_) * rp * wv + bv) : vp[i];
    xkf[(size_t)m * 2048 + c] = f2b(xn + (pn - xn) * mk[c]);
  }
}

// ------------------------------ epilogues ----------------------------------

constexpr int EP_F32 = 0, EP_B16 = 1, EP_RELU2 = 5, EP_ADDF = 6;

template <int EP>
DEV void ep_store(float acc, long row, long c, long ldc, float* Co,
                  unsigned short* Cob, const float* bias, const float* e0f,
                  const unsigned short* e0b) {
  const long idx = row * ldc + c;
  (void)bias; (void)e0b;
  if constexpr (EP == EP_F32) {
    Co[idx] = acc;
  } else if constexpr (EP == EP_B16) {
    Cob[idx] = f2b(acc);
  } else if constexpr (EP == EP_RELU2) {
    const float r = fmaxf(acc, 0.f);
    Cob[idx] = f2b(r * r);
  } else if constexpr (EP == EP_ADDF) {
    Co[idx] = acc + e0f[idx];
  }
}

// ---------------- GEMM v3 (128x128, counted vmcnt, swizzled dbuf) ----------

template <int EP>
__global__ __launch_bounds__(256)
void gemm3(const unsigned short* __restrict__ A, long lda,
           const unsigned short* __restrict__ Bt, long ldb, long K, long ldc,
           float* __restrict__ Co, unsigned short* __restrict__ Cob,
           const float* __restrict__ e0f) {
  __shared__ unsigned short As[2][4096];
  __shared__ unsigned short Bs[2][4096];
  const int tid = threadIdx.x;
  const int wid = tid >> 6, lane = tid & 63;
  const long row0 = (long)blockIdx.x * 128, col0 = (long)blockIdx.y * 128;
  const int wm = (wid >> 1) * 64, wn = (wid & 1) * 64;
  f32x4 acc[4][4] = {};
  const int srow = tid >> 2;
  const int scol = 8 * ((tid & 3) ^ (srow & 3));
  const unsigned short* gA = A + (row0 + srow) * lda + scol;
  const unsigned short* gB = Bt + (col0 + srow) * ldb + scol;
  const int fr = lane & 15, fc = lane >> 4;

#define STAGE3(buf, kb)                                         \
  {                                                             \
    gload16(gA + (kb), &As[buf][0] + wid * 512);                \
    gload16(gA + (kb) + 64 * lda, &As[buf][2048] + wid * 512);  \
    gload16(gB + (kb), &Bs[buf][0] + wid * 512);                \
    gload16(gB + (kb) + 64 * ldb, &Bs[buf][2048] + wid * 512);  \
  }

  STAGE3(0, 0)
  const int NT = (int)(K >> 5);
  int cur = 0;
  for (int kt = 0; kt < NT; ++kt) {
    if (kt + 1 < NT) {
      STAGE3(cur ^ 1, (long)(kt + 1) * 32)
      asm volatile("s_waitcnt vmcnt(4)" ::: "memory");
    } else {
      asm volatile("s_waitcnt vmcnt(0)" ::: "memory");
    }
    __builtin_amdgcn_s_barrier();
    asm volatile("" ::: "memory");
    bf16x8 af[4], bq[4];
#pragma unroll
    for (int mt = 0; mt < 4; ++mt) {
      const int r = wm + mt * 16 + fr;
      af[mt] = *(const bf16x8*)(&As[cur][0] + r * 32 + ((fc ^ (r & 3)) * 8));
    }
#pragma unroll
    for (int nt = 0; nt < 4; ++nt) {
      const int r = wn + nt * 16 + fr;
      bq[nt] = *(const bf16x8*)(&Bs[cur][0] + r * 32 + ((fc ^ (r & 3)) * 8));
    }
    __builtin_amdgcn_s_setprio(1);
#pragma unroll
    for (int mt = 0; mt < 4; ++mt)
#pragma unroll
      for (int nt = 0; nt < 4; ++nt)
        acc[mt][nt] = __builtin_amdgcn_mfma_f32_16x16x32_bf16(
            af[mt], bq[nt], acc[mt][nt], 0, 0, 0);
    __builtin_amdgcn_s_setprio(0);
    asm volatile("" ::: "memory");
    __builtin_amdgcn_s_barrier();
    cur ^= 1;
  }
#undef STAGE3
  const int fq = lane >> 4;
#pragma unroll
  for (int mt = 0; mt < 4; ++mt) {
#pragma unroll
    for (int nt = 0; nt < 4; ++nt) {
      const long c = col0 + wn + nt * 16 + fr;
      const long rb = row0 + wm + mt * 16 + fq * 4;
#pragma unroll
      for (int rg = 0; rg < 4; ++rg)
        ep_store<EP>(acc[mt][nt][rg], rb + rg, c, ldc, Co, Cob, nullptr, e0f,
                     nullptr);
    }
  }
}

// ---- gemm3_qkv: three C=2048^2 GEMMs in one launch (z selects A/B/C) ------

__global__ __launch_bounds__(256)
void gemm3_qkv(const unsigned short* __restrict__ A0,
               const unsigned short* __restrict__ A1,
               const unsigned short* __restrict__ A2p,
               const unsigned short* __restrict__ B0,
               const unsigned short* __restrict__ B1,
               const unsigned short* __restrict__ B2,
               unsigned short* __restrict__ C0,
               unsigned short* __restrict__ C1,
               unsigned short* __restrict__ C2) {
  const int z = blockIdx.z;
  const unsigned short* A = z == 0 ? A0 : z == 1 ? A1 : A2p;
  const unsigned short* Bt = z == 0 ? B0 : z == 1 ? B1 : B2;
  unsigned short* Cob = z == 0 ? C0 : z == 1 ? C1 : C2;
  __shared__ unsigned short As[2][4096];
  __shared__ unsigned short Bs[2][4096];
  const int tid = threadIdx.x;
  const int wid = tid >> 6, lane = tid & 63;
  const long row0 = (long)blockIdx.x * 128, col0 = (long)blockIdx.y * 128;
  const int wm = (wid >> 1) * 64, wn = (wid & 1) * 64;
  f32x4 acc[4][4] = {};
  const int srow = tid >> 2;
  const int scol = 8 * ((tid & 3) ^ (srow & 3));
  const unsigned short* gA = A + (row0 + srow) * 2048 + scol;
  const unsigned short* gB = Bt + (col0 + srow) * 2048 + scol;
  const int fr = lane & 15, fc = lane >> 4;

#define STAGEQ(buf, kb)                                          \
  {                                                              \
    gload16(gA + (kb), &As[buf][0] + wid * 512);                 \
    gload16(gA + (kb) + 64 * 2048, &As[buf][2048] + wid * 512);  \
    gload16(gB + (kb), &Bs[buf][0] + wid * 512);                 \
    gload16(gB + (kb) + 64 * 2048, &Bs[buf][2048] + wid * 512);  \
  }

  STAGEQ(0, 0)
  int cur = 0;
  for (int kt = 0; kt < 64; ++kt) {
    if (kt + 1 < 64) {
      STAGEQ(cur ^ 1, (long)(kt + 1) * 32)
      asm volatile("s_waitcnt vmcnt(4)" ::: "memory");
    } else {
      asm volatile("s_waitcnt vmcnt(0)" ::: "memory");
    }
    __builtin_amdgcn_s_barrier();
    asm volatile("" ::: "memory");
    bf16x8 af[4], bq[4];
#pragma unroll
    for (int mt = 0; mt < 4; ++mt) {
      const int r = wm + mt * 16 + fr;
      af[mt] = *(const bf16x8*)(&As[cur][0] + r * 32 + ((fc ^ (r & 3)) * 8));
    }
#pragma unroll
    for (int nt = 0; nt < 4; ++nt) {
      const int r = wn + nt * 16 + fr;
      bq[nt] = *(const bf16x8*)(&Bs[cur][0] + r * 32 + ((fc ^ (r & 3)) * 8));
    }
    __builtin_amdgcn_s_setprio(1);
#pragma unroll
    for (int mt = 0; mt < 4; ++mt)
#pragma unroll
      for (int nt = 0; nt < 4; ++nt)
        acc[mt][nt] = __builtin_amdgcn_mfma_f32_16x16x32_bf16(
            af[mt], bq[nt], acc[mt][nt], 0, 0, 0);
    __builtin_amdgcn_s_setprio(0);
    asm volatile("" ::: "memory");
    __builtin_amdgcn_s_barrier();
    cur ^= 1;
  }
#undef STAGEQ
  const int fq = lane >> 4;
#pragma unroll
  for (int mt = 0; mt < 4; ++mt) {
#pragma unroll
    for (int nt = 0; nt < 4; ++nt) {
      const long c = col0 + wn + nt * 16 + fr;
      const long rb = row0 + wm + mt * 16 + fq * 4;
#pragma unroll
      for (int rg = 0; rg < 4; ++rg)
        Cob[(rb + rg) * 2048 + c] = f2b(acc[mt][nt][rg]);
    }
  }
}

// ---- gemm3h: Wcat GEMM on gemm3 schedule, N=288-masked HACT epilogue ------
// A = act2 [4096][4096], Bt = tWcat [384][4096] (rows 288.. zero-padded).

__global__ __launch_bounds__(256)
void gemm3h(const unsigned short* __restrict__ A,
            const unsigned short* __restrict__ Bt,
            unsigned short* __restrict__ Hact) {
  __shared__ unsigned short As[2][4096];
  __shared__ unsigned short Bs[2][4096];
  const int tid = threadIdx.x;
  const int wid = tid >> 6, lane = tid & 63;
  const long row0 = (long)blockIdx.x * 128, col0 = (long)blockIdx.y * 128;
  const int wm = (wid >> 1) * 64, wn = (wid & 1) * 64;
  f32x4 acc[4][4] = {};
  const int srow = tid >> 2;
  const int scol = 8 * ((tid & 3) ^ (srow & 3));
  const unsigned short* gA = A + (row0 + srow) * 4096 + scol;
  const unsigned short* gB = Bt + (col0 + srow) * 4096 + scol;
  const int fr = lane & 15, fc = lane >> 4;

#define STAGEH(buf, kb)                                          \
  {                                                              \
    gload16(gA + (kb), &As[buf][0] + wid * 512);                 \
    gload16(gA + (kb) + 64 * 4096, &As[buf][2048] + wid * 512);  \
    gload16(gB + (kb), &Bs[buf][0] + wid * 512);                 \
    gload16(gB + (kb) + 64 * 4096, &Bs[buf][2048] + wid * 512);  \
  }

  STAGEH(0, 0)
  int cur = 0;
  for (int kt = 0; kt < 128; ++kt) {
    if (kt + 1 < 128) {
      STAGEH(cur ^ 1, (long)(kt + 1) * 32)
      asm volatile("s_waitcnt vmcnt(4)" ::: "memory");
    } else {
      asm volatile("s_waitcnt vmcnt(0)" ::: "memory");
    }
    __builtin_amdgcn_s_barrier();
    asm volatile("" ::: "memory");
    bf16x8 af[4], bq[4];
#pragma unroll
    for (int mt = 0; mt < 4; ++mt) {
      const int r = wm + mt * 16 + fr;
      af[mt] = *(const bf16x8*)(&As[cur][0] + r * 32 + ((fc ^ (r & 3)) * 8));
    }
#pragma unroll
    for (int nt = 0; nt < 4; ++nt) {
      const int r = wn + nt * 16 + fr;
      bq[nt] = *(const bf16x8*)(&Bs[cur][0] + r * 32 + ((fc ^ (r & 3)) * 8));
    }
    __builtin_amdgcn_s_setprio(1);
#pragma unroll
    for (int mt = 0; mt < 4; ++mt)
#pragma unroll
      for (int nt = 0; nt < 4; ++nt)
        acc[mt][nt] = __builtin_amdgcn_mfma_f32_16x16x32_bf16(
            af[mt], bq[nt], acc[mt][nt], 0, 0, 0);
    __builtin_amdgcn_s_setprio(0);
    asm volatile("" ::: "memory");
    __builtin_amdgcn_s_barrier();
    cur ^= 1;
  }
#undef STAGEH
  const int fq = lane >> 4;
#pragma unroll
  for (int mt = 0; mt < 4; ++mt) {
#pragma unroll
    for (int nt = 0; nt < 4; ++nt) {
      const long c = col0 + wn + nt * 16 + fr;
      if (c < 288) {
        const long rb = row0 + wm + mt * 16 + fq * 4;
#pragma unroll
        for (int rg = 0; rg < 4; ++rg) {
          float vv = acc[mt][nt][rg];
          if (c < 64) vv = tanhf(vv);
          else if (c >= 160) vv = 1.f / (1.f + expf(-vv));
          Hact[(rb + rg) * 288 + c] = f2b(vv);
        }
      }
    }
  }
}

// ---------------- GEMM 8-phase 256x256 (FFN-up only) -----------------------

template <int EP>
__global__ __launch_bounds__(512)
void gemm8p(const unsigned short* __restrict__ A, long lda,
            const unsigned short* __restrict__ Bt, long ldb, long K, long ldc,
            float* __restrict__ Co, unsigned short* __restrict__ Cob,
            const float* __restrict__ e0f) {
  __shared__ unsigned short lds[65536];  // 128KB
  const int tid = threadIdx.x;
  const int wid = tid >> 6, lane = tid & 63;
  const long row0 = (long)blockIdx.x * 256, col0 = (long)blockIdx.y * 256;
  const int wrow = (wid >> 2) * 64;
  const int wcol = (wid & 3) * 32;
  const int fr = lane & 15, fc = lane >> 4;
  f32x4 acc[2][4][2][2] = {};

  const int sr0 = tid >> 3;
  int sce = (tid & 7) * 8;
  sce ^= ((sr0 >> 2) & 1) << 4;
  const unsigned short* gA = A + (row0 + sr0) * lda + sce;
  const unsigned short* gB = Bt + (col0 + sr0) * ldb + sce;

#define STG8(half, src, ld, kb, buf)                                     \
  {                                                                      \
    const unsigned short* s_ = (src) + (kb);                             \
    unsigned short* d_ = lds + (buf) * 32768 + (half) * 8192 + tid * 8;  \
    gload16(s_, d_);                                                     \
    gload16(s_ + 64 * (ld), d_ + 4096);                                  \
  }

  STG8(0, gA, lda, 0, 0)
  STG8(2, gB, ldb, 0, 0)
  STG8(1, gA + 128 * lda, lda, 0, 0)
  STG8(3, gB + 128 * ldb, ldb, 0, 0)
  asm volatile("s_waitcnt vmcnt(0)" ::: "memory");
  __builtin_amdgcn_s_barrier();

  const int NT = (int)(K >> 6);
  int cur = 0;

#define PHASE8(P, KT)                                                         \
  {                                                                           \
    constexpr int mh = (P) >> 1, nh = (P) & 1;                                \
    const int bb = cur * 32768;                                               \
    bf16x8 af[4][2], bq[2][2];                                                \
    _Pragma("unroll") for (int mt = 0; mt < 4; ++mt)                          \
      _Pragma("unroll") for (int ks = 0; ks < 2; ++ks) {                      \
        const int r = wrow + mt * 16 + fr;                                    \
        const int e = (ks * 32 + fc * 8) ^ (((r >> 2) & 1) << 4);             \
        af[mt][ks] = *(const bf16x8*)(lds + bb + mh * 8192 + r * 64 + e);     \
      }                                                                       \
    _Pragma("unroll") for (int nt = 0; nt < 2; ++nt)                          \
      _Pragma("unroll") for (int ks = 0; ks < 2; ++ks) {                      \
        const int r = wcol + nt * 16 + fr;                                    \
        const int e = (ks * 32 + fc * 8) ^ (((r >> 2) & 1) << 4);             \
        bq[nt][ks] =                                                          \
            *(const bf16x8*)(lds + bb + 16384 + nh * 8192 + r * 64 + e);      \
      }                                                                       \
    if ((KT) + 1 < NT) {                                                      \
      const long kb_ = (long)((KT) + 1) * 64;                                 \
      if constexpr ((P) == 0) STG8(0, gA, lda, kb_, cur ^ 1)                  \
      else if constexpr ((P) == 1) STG8(2, gB, ldb, kb_, cur ^ 1)             \
      else if constexpr ((P) == 2) STG8(1, gA + 128 * lda, lda, kb_, cur ^ 1) \
      else STG8(3, gB + 128 * ldb, ldb, kb_, cur ^ 1)                         \
    }                                                                         \
    if constexpr ((P) == 0) asm volatile("s_waitcnt vmcnt(2)" ::: "memory");  \
    if constexpr ((P) == 3) asm volatile("s_waitcnt vmcnt(4)" ::: "memory");  \
    __builtin_amdgcn_s_barrier();                                             \
    asm volatile("s_waitcnt lgkmcnt(0)" ::: "memory");                        \
    __builtin_amdgcn_s_setprio(1);                                            \
    _Pragma("unroll") for (int mt = 0; mt < 4; ++mt)                          \
      _Pragma("unroll") for (int nt = 0; nt < 2; ++nt)                        \
        _Pragma("unroll") for (int ks = 0; ks < 2; ++ks)                      \
          acc[mh][mt][nh][nt] = __builtin_amdgcn_mfma_f32_16x16x32_bf16(      \
              af[mt][ks], bq[nt][ks], acc[mh][mt][nh][nt], 0, 0, 0);          \
    __builtin_amdgcn_s_setprio(0);                                            \
    asm volatile("" ::: "memory");                                            \
    __builtin_amdgcn_s_barrier();                                             \
  }

  for (int kt = 0; kt < NT; ++kt) {
    PHASE8(0, kt)
    PHASE8(1, kt)
    PHASE8(2, kt)
    PHASE8(3, kt)
    cur ^= 1;
  }
#undef PHASE8
#undef STG8

  const int fq = lane >> 4;
#pragma unroll
  for (int mh = 0; mh < 2; ++mh)
#pragma unroll
    for (int mt = 0; mt < 4; ++mt)
#pragma unroll
      for (int nh = 0; nh < 2; ++nh)
#pragma unroll
        for (int nt = 0; nt < 2; ++nt) {
          const long c = col0 + nh * 128 + wcol + nt * 16 + fr;
          const long rb = row0 + mh * 128 + wrow + mt * 16 + fq * 4;
#pragma unroll
          for (int rg = 0; rg < 4; ++rg)
            ep_store<EP>(acc[mh][mt][nh][nt][rg], rb + rg, c, ldc, Co, Cob,
                         nullptr, e0f, nullptr);
        }
}

// ---------------- gemm_up128: Hact[4096][288] @ Wup^T[8192][288] -----------

__global__ __launch_bounds__(256)
void gemm_up128(const unsigned short* __restrict__ A,
                const unsigned short* __restrict__ Bt,
                float* __restrict__ whb, unsigned short* __restrict__ abuf,
                unsigned short* __restrict__ vfb, unsigned short* __restrict__ gbuf,
                const float* __restrict__ w0, const float* __restrict__ a0,
                const float* __restrict__ v0,
                const unsigned short* __restrict__ vraw,
                const float* __restrict__ vfirst) {
  __shared__ unsigned short As[2][4096];
  __shared__ unsigned short Bs[2][4096];
  const int tid = threadIdx.x;
  const int wid = tid >> 6, lane = tid & 63;
  const long row0 = (long)blockIdx.x * 128, col0 = (long)blockIdx.y * 128;
  const int wm = (wid >> 1) * 64, wn = (wid & 1) * 64;
  f32x4 acc[4][4] = {};
  const int srow = tid >> 2;
  const int scol = 8 * ((tid & 3) ^ (srow & 3));
  const unsigned short* gA = A + (row0 + srow) * 288 + scol;
  const unsigned short* gB = Bt + (col0 + srow) * 288 + scol;
  const int fr = lane & 15, fc = lane >> 4;

#define STAGEU(buf, kb)                                         \
  {                                                             \
    gload16(gA + (kb), &As[buf][0] + wid * 512);                \
    gload16(gA + (kb) + 64 * 288, &As[buf][2048] + wid * 512);  \
    gload16(gB + (kb), &Bs[buf][0] + wid * 512);                \
    gload16(gB + (kb) + 64 * 288, &Bs[buf][2048] + wid * 512);  \
  }

  STAGEU(0, 0)
  int cur = 0;
  for (int kt = 0; kt < 9; ++kt) {
    if (kt + 1 < 9) {
      STAGEU(cur ^ 1, (long)(kt + 1) * 32)
      asm volatile("s_waitcnt vmcnt(4)" ::: "memory");
    } else {
      asm volatile("s_waitcnt vmcnt(0)" ::: "memory");
    }
    __builtin_amdgcn_s_barrier();
    asm volatile("" ::: "memory");
    bf16x8 af[4], bq[4];
#pragma unroll
    for (int mt = 0; mt < 4; ++mt) {
      const int r = wm + mt * 16 + fr;
      af[mt] = *(const bf16x8*)(&As[cur][0] + r * 32 + ((fc ^ (r & 3)) * 8));
    }
#pragma unroll
    for (int nt = 0; nt < 4; ++nt) {
      const int r = wn + nt * 16 + fr;
      bq[nt] = *(const bf16x8*)(&Bs[cur][0] + r * 32 + ((fc ^ (r & 3)) * 8));
    }
    __builtin_amdgcn_s_setprio(1);
#pragma unroll
    for (int mt = 0; mt < 4; ++mt)
#pragma unroll
      for (int nt = 0; nt < 4; ++nt)
        acc[mt][nt] = __builtin_amdgcn_mfma_f32_16x16x32_bf16(
            af[mt], bq[nt], acc[mt][nt], 0, 0, 0);
    __builtin_amdgcn_s_setprio(0);
    asm volatile("" ::: "memory");
    __builtin_amdgcn_s_barrier();
    cur ^= 1;
  }
#undef STAGEU
  const int fq = lane >> 4;
  const int p = (int)(blockIdx.y >> 4);
#pragma unroll
  for (int mt = 0; mt < 4; ++mt) {
#pragma unroll
    for (int nt = 0; nt < 4; ++nt) {
      const long c = col0 + wn + nt * 16 + fr;
      const long cc = c & 2047;
      const long rb = row0 + wm + mt * 16 + fq * 4;
#pragma unroll
      for (int rg = 0; rg < 4; ++rg) {
        const float av = acc[mt][nt][rg];
        const long idx = (rb + rg) * 2048 + cc;
        if (p == 0) {
          const float wv = w0[cc] + av;
          const float sp = log1pf(expf(-wv));
          whb[idx] = expf(-expf(-sp - 0.5f));
        } else if (p == 1) {
          abuf[idx] = f2b(1.f / (1.f + expf(-(a0[cc] + av))));
        } else if (p == 2) {
          const float s = 1.f / (1.f + expf(-(v0[cc] + av)));
          const float vv = b2f(vraw[idx]);
          vfb[idx] = f2b(vv + (vfirst[idx] - vv) * s);
        } else {
          gbuf[idx] = f2b(av);  // g = sigmoid(xg@g1) @ g2 -- NO outer act
        }
      }
    }
  }
}

// ------------------------------ k_post -------------------------------------
__global__ __launch_bounds__(256)
void k_post(unsigned short* __restrict__ kio, unsigned short* __restrict__ abio,
            unsigned short* __restrict__ aao, const float* __restrict__ kkw,
            const float* __restrict__ kaw) {
  const int m = blockIdx.x, tid = threadIdx.x;
  const size_t base = (size_t)m * 2048 + tid * 8;
  us8 k8 = *(const us8*)(kio + base);
  us8 a8 = *(const us8*)(abio + base);
  float kk8[8], ka8[8];
  *(float4*)&kk8[0] = *(const float4*)(kkw + tid * 8);
  *(float4*)&kk8[4] = *(const float4*)(kkw + tid * 8 + 4);
  *(float4*)&ka8[0] = *(const float4*)(kaw + tid * 8);
  *(float4*)&ka8[4] = *(const float4*)(kaw + tid * 8 + 4);
  float kx[8], kv[8], av[8];
  float ss = 0.f;
#pragma unroll
  for (int i = 0; i < 8; ++i) {
    kv[i] = b2f(k8[i]); av[i] = b2f(a8[i]);
    kx[i] = kv[i] * kk8[i]; ss += kx[i] * kx[i];
  }
  ss = red8(ss);
  const float inv = 1.f / fmaxf(sqrtf(ss), 1e-12f);
  us8 kh8, aa8, bb8;
#pragma unroll
  for (int i = 0; i < 8; ++i) {
    const float kkn = kx[i] * inv;
    kh8[i] = f2b(kv[i] * (1.f + (av[i] - 1.f) * ka8[i]));
    aa8[i] = f2b(-kkn);
    bb8[i] = f2b(kkn * av[i]);
  }
  *(us8*)(kio + base) = kh8;
  *(us8*)(aao + base) = aa8;
  *(us8*)(abio + base) = bb8;
}

// ------------------------------ WKV scan (R11) ------------------------------

DEV float red16(float x) {  // all-lanes sum within each 16-lane row
  union { float f; int i; } a, r;
  a.f = x; r.i = __builtin_amdgcn_update_dpp(0, a.i, 0xB1, 0xf, 0xf, true);
  x += r.f;
  a.f = x; r.i = __builtin_amdgcn_update_dpp(0, a.i, 0x4E, 0xf, 0xf, true);
  x += r.f;
  a.f = x; r.i = __builtin_amdgcn_update_dpp(0, a.i, 0x124, 0xf, 0xf, true);
  x += r.f;
  a.f = x; r.i = __builtin_amdgcn_update_dpp(0, a.i, 0x128, 0xf, 0xf, true);
  x += r.f;
  return x;
}

DEV void cv4(const uint2 q, float* o) {
  union { unsigned u; float f; } t;
  t.u = q.x << 16;          o[0] = t.f;
  t.u = q.x & 0xffff0000u;  o[1] = t.f;
  t.u = q.y << 16;          o[2] = t.f;
  t.u = q.y & 0xffff0000u;  o[3] = t.f;
}

__global__ __launch_bounds__(64)
void k_scan(const unsigned short* __restrict__ rp,
            const unsigned short* __restrict__ kp,
            const unsigned short* __restrict__ vp,
            const float* __restrict__ wp,
            const unsigned short* __restrict__ ap,
            const unsigned short* __restrict__ bp,
            const float* __restrict__ s0, unsigned short* __restrict__ yout,
            float* __restrict__ snew) {
  __shared__ float4 slots[8][49];
  __shared__ unsigned short ylds[1024][4];
  const int lane = threadIdx.x;
  const int bh = blockIdx.x & 127;
  const int rq = blockIdx.x >> 7;
  const int b = bh >> 5, h = bh & 31;
  const int kg = lane & 15, rl = lane >> 4;
  const int v = rq * 4 + rl, ks = kg * 4;
  const size_t off_bh = (size_t)b * 1024 * 2048 + (size_t)h * 64;
  const int vfo = 768 + ((rq & 1) * 4 + rl) * 2;

  float S[4];
  *(float4*)&S[0] = *(const float4*)(s0 + (((size_t)bh * 64 + v) * 64 + ks));

  const char* gp = nullptr;
  size_t gstep = 0;
  if (lane < 49) {
    if (lane < 32) {
      const int arr = lane >> 3, sub = lane & 7;
      const unsigned short* base = arr == 0 ? rp : arr == 1 ? kp
                                 : arr == 2 ? ap : bp;
      gp = (const char*)(base + off_bh + sub * 8);
      gstep = 4096;
    } else if (lane < 48) {
      gp = (const char*)(wp + off_bh + (lane - 32) * 4);
      gstep = 8192;
    } else {
      gp = (const char*)(vp + off_bh + (rq & ~1) * 4);
      gstep = 4096;
    }
  }
#pragma unroll
  for (int s = 0; s < 8; ++s) {
    if (lane < 49) gload16(gp, &slots[s][0]);
    gp += gstep;
  }

  uint2 rA, kA, aA, bA, rB, kB, aB, bB;
  float4 wA, wB;
  unsigned short fA, fB;
  asm volatile("s_waitcnt vmcnt(7)" ::: "memory");
  {
    const char* nb = (const char*)&slots[0][0];
    rA = *(const uint2*)(nb + kg * 8);
    kA = *(const uint2*)(nb + 128 + kg * 8);
    aA = *(const uint2*)(nb + 256 + kg * 8);
    bA = *(const uint2*)(nb + 384 + kg * 8);
    wA = *(const float4*)(nb + 512 + kg * 16);
    fA = *(const unsigned short*)(nb + vfo);
  }

#define SSTEP(T, Cr, Ck, Ca, Cb, Cw, Cf, Nr, Nk, Na, Nb, Nw, Nf)             \
  {                                                                          \
    asm volatile("s_waitcnt lgkmcnt(0)" ::: "memory");                       \
    if (lane < 49) gload16(gp, &slots[(T) & 7][0]);                          \
    if ((T) < 1015) gp += gstep;                                             \
    asm volatile("s_waitcnt vmcnt(7)" ::: "memory");                         \
    const char* nb = (const char*)&slots[((T) + 1) & 7][0];                  \
    Nr = *(const uint2*)(nb + kg * 8);                                       \
    Nk = *(const uint2*)(nb + 128 + kg * 8);                                 \
    Na = *(const uint2*)(nb + 256 + kg * 8);                                 \
    Nb = *(const uint2*)(nb + 384 + kg * 8);                                 \
    Nw = *(const float4*)(nb + 512 + kg * 16);                               \
    Nf = *(const unsigned short*)(nb + vfo);                                 \
    float rr[4], kk[4], av[4], bv[4];                                        \
    cv4(Cr, rr); cv4(Ck, kk); cv4(Ca, av); cv4(Cb, bv);                      \
    const float vv = b2f(Cf);                                                \
    float sa = S[0] * av[0] + S[1] * av[1] + S[2] * av[2] + S[3] * av[3];    \
    sa = red16(sa);                                                          \
    float y;                                                                 \
    S[0] = S[0] * Cw.x + sa * bv[0] + vv * kk[0]; y  = S[0] * rr[0];         \
    S[1] = S[1] * Cw.y + sa * bv[1] + vv * kk[1]; y += S[1] * rr[1];         \
    S[2] = S[2] * Cw.z + sa * bv[2] + vv * kk[2]; y += S[2] * rr[2];         \
    S[3] = S[3] * Cw.w + sa * bv[3] + vv * kk[3]; y += S[3] * rr[3];         \
    y = red16(y);                                                            \
    if (kg == 0) ylds[T][rl] = f2b(y);                                       \
  }

  for (int tb = 0; tb < 1024; tb += 2) {
    SSTEP(tb + 0, rA, kA, aA, bA, wA, fA, rB, kB, aB, bB, wB, fB)
    SSTEP(tb + 1, rB, kB, aB, bB, wB, fB, rA, kA, aA, bA, wA, fA)
  }
#undef SSTEP

  *(float4*)(snew + (((size_t)bh * 64 + v) * 64 + ks)) = *(const float4*)&S[0];
  asm volatile("s_waitcnt lgkmcnt(0)" ::: "memory");
#pragma unroll 4
  for (int it = 0; it < 16; ++it) {
    const int t = lane + it * 64;
    const uint2 val = *(const uint2*)&ylds[t][0];
    *(uint2*)(yout + off_bh + (size_t)t * 2048 + rq * 4) = val;
  }
}

// ---------------------- GroupNorm + resid + gate ---------------------------

__global__ __launch_bounds__(256)
void k_gn(const unsigned short* __restrict__ y, const unsigned short* __restrict__ r,
          const unsigned short* __restrict__ kh, const unsigned short* __restrict__ vf,
          const unsigned short* __restrict__ g, const float* __restrict__ rk,
          const float* __restrict__ lw, const float* __restrict__ lb,
          unsigned short* __restrict__ ywg) {
  const int m = blockIdx.x, tid = threadIdx.x;
  const size_t base = (size_t)m * 2048 + tid * 8;
  us8 y8 = *(const us8*)(y + base);
  us8 r8 = *(const us8*)(r + base);
  us8 k8 = *(const us8*)(kh + base);
  us8 v8 = *(const us8*)(vf + base);
  us8 g8 = *(const us8*)(g + base);
  float yv[8];
  float rkv[8];
  *(float4*)&rkv[0] = *(const float4*)(rk + tid * 8);
  *(float4*)&rkv[4] = *(const float4*)(rk + tid * 8 + 4);
  float sy = 0.f, sd = 0.f;
#pragma unroll
  for (int i = 0; i < 8; ++i) {
    yv[i] = b2f(y8[i]);
    sy += yv[i];
    sd += b2f(r8[i]) * b2f(k8[i]) * rkv[i];
  }
  sy = red8(sy);
  sd = red8(sd);
  const float mu = sy * (1.f / 64.f);
  float sq = 0.f;
#pragma unroll
  for (int i = 0; i < 8; ++i) { const float d = yv[i] - mu; sq += d * d; }
  sq = red8(sq);
  const float rstd = rsqrtf(sq * (1.f / 64.f) + 64e-5f);
  us8 o8;
#pragma unroll
  for (int i = 0; i < 8; ++i) {
    const int c = tid * 8 + i;
    const float gn = (yv[i] - mu) * rstd * lw[c] + lb[c];
    o8[i] = f2b((gn + sd * b2f(v8[i])) * b2f(g8[i]));
  }
  *(us8*)(ywg + base) = o8;
}

// ------------------------------ launch -------------------------------------

extern "C" void kernel_launch(void* const* d_in, const int* in_sizes, int n_in,
                              void* d_out, int out_size, void* d_ws,
                              size_t ws_size, hipStream_t stream) {
  (void)in_sizes; (void)n_in; (void)out_size; (void)ws_size;
  const float* x         = (const float*)d_in[0];
  const float* v_first   = (const float*)d_in[1];
  const float* att_shift = (const float*)d_in[2];
  const float* ffn_shift = (const float*)d_in[3];
  const float* wkv0      = (const float*)d_in[4];
  const float* ln1w = (const float*)d_in[5];
  const float* ln1b = (const float*)d_in[6];
  const float* ln2w = (const float*)d_in[7];
  const float* ln2b = (const float*)d_in[8];
  const float* x_r = (const float*)d_in[9];
  const float* x_w = (const float*)d_in[10];
  const float* x_k = (const float*)d_in[11];
  const float* x_v = (const float*)d_in[12];
  const float* x_a = (const float*)d_in[13];
  const float* x_g = (const float*)d_in[14];
  const float* Wr = (const float*)d_in[15];
  const float* Wk = (const float*)d_in[16];
  const float* Wv = (const float*)d_in[17];
  const float* Wo = (const float*)d_in[18];
  const float* w0 = (const float*)d_in[19];
  const float* w1 = (const float*)d_in[20];
  const float* w2 = (const float*)d_in[21];
  const float* v0 = (const float*)d_in[22];
  const float* v1 = (const float*)d_in[23];
  const float* v2 = (const float*)d_in[24];
  const float* a0 = (const float*)d_in[25];
  const float* a1 = (const float*)d_in[26];
  const float* a2 = (const float*)d_in[27];
  const float* g1 = (const float*)d_in[28];
  const float* g2 = (const float*)d_in[29];
  const float* k_k = (const float*)d_in[30];
  const float* k_a = (const float*)d_in[31];
  const float* r_k = (const float*)d_in[32];
  const float* lnxw = (const float*)d_in[33];
  const float* lnxb = (const float*)d_in[34];
  const float* ffn_xk = (const float*)d_in[35];
  const float* Wkf = (const float*)d_in[36];
  const float* Wvf = (const float*)d_in[37];

  char* ws = (char*)d_ws;
  constexpr size_t OFF_TWR   = 0;
  constexpr size_t OFF_TWK   = 8388608;
  constexpr size_t OFF_TWV   = 16777216;
  constexpr size_t OFF_TWO   = 25165824;
  constexpr size_t OFF_TWCAT = 34734080;
  constexpr size_t OFF_HACT  = 37879808;
  constexpr size_t OFF_GBUF  = 40239104;
  constexpr size_t OFF_WH    = 57016320;
  constexpr size_t OFF_R     = 90570752;
  constexpr size_t OFF_KH    = 107347968;
  constexpr size_t OFF_VF    = 124125184;
  constexpr size_t OFF_AA    = 140902400;
  constexpr size_t OFF_BB    = 157679616;
  constexpr size_t OFF_TWUP  = 174456832;  // [8192][288] bf16, 4.7MB

  unsigned short* tWr = (unsigned short*)(ws + OFF_TWR);
  unsigned short* tWk = (unsigned short*)(ws + OFF_TWK);
  unsigned short* tWv = (unsigned short*)(ws + OFF_TWV);
  unsigned short* tWo = (unsigned short*)(ws + OFF_TWO);
  unsigned short* tWcat = (unsigned short*)(ws + OFF_TWCAT);
  unsigned short* Hact  = (unsigned short*)(ws + OFF_HACT);
  unsigned short* gbuf  = (unsigned short*)(ws + OFF_GBUF);
  unsigned short* tWvfh = (unsigned short*)(ws + OFF_GBUF);
  unsigned short* act2  = (unsigned short*)(ws + OFF_WH);
  float*          whb   = (float*)(ws + OFF_WH);
  unsigned short* ywg   = (unsigned short*)(ws + OFF_WH);
  unsigned short* kf    = (unsigned short*)(ws + OFF_WH);
  unsigned short* bxr   = (unsigned short*)(ws + OFF_AA);
  unsigned short* bxk   = (unsigned short*)(ws + OFF_BB);
  unsigned short* bxv   = (unsigned short*)(ws + OFF_VF);
  unsigned short* rbuf  = (unsigned short*)(ws + OFF_R);
  unsigned short* khb   = (unsigned short*)(ws + OFF_KH);
  unsigned short* vfb   = (unsigned short*)(ws + OFF_VF);
  unsigned short* aab   = (unsigned short*)(ws + OFF_AA);
  unsigned short* bbb   = (unsigned short*)(ws + OFF_BB);
  unsigned short* vraw  = (unsigned short*)(ws + OFF_AA);
  unsigned short* abuf  = (unsigned short*)(ws + OFF_BB);
  float*          x1    = (float*)(ws + OFF_R);
  unsigned short* xkf   = (unsigned short*)(ws + OFF_VF);
  unsigned short* tWkf  = (unsigned short*)(ws + OFF_AA);
  unsigned short* tWup  = (unsigned short*)(ws + OFF_TWUP);
  float* out = (float*)d_out;
  float* snew = out + 8388608;

  const dim3 tb(32, 8);
  // ---- weight prep (merged launches) ----
  k_transpose4<<<dim3(64, 64, 4), tb, 0, stream>>>(Wr, Wk, Wv, Wo,
                                                   tWr, tWk, tWv, tWo);
  k_prep<<<15360, 256, 0, stream>>>(w1, a1, v1, g1, x_w, x_a, x_v, x_g,
                                    w2, a2, v2, g2, tWcat, tWup);

  // ---- TimeMix front ----
  k_ln1_mix<<<4096, 256, 0, stream>>>(x, att_shift, ln1w, ln1b, x_r, x_k, x_v,
                                      act2, bxr, bxk, bxv);
  gemm3_qkv<<<dim3(32, 16, 3), 256, 0, stream>>>(bxr, bxk, bxv, tWr, tWk, tWv,
                                                 rbuf, khb, vraw);
  gemm3h<<<dim3(32, 3), 256, 0, stream>>>(act2, tWcat, Hact);
  gemm_up128<<<dim3(32, 64), 256, 0, stream>>>(
      Hact, tWup, whb, abuf, vfb, gbuf, w0, a0, v0, vraw, v_first);
  k_post<<<4096, 256, 0, stream>>>(khb, abuf, aab, k_k, k_a);

  // ---- WKV scan ----
  k_scan<<<2048, 64, 0, stream>>>(rbuf, khb, vfb, whb, aab, bbb, wkv0,
                                  (unsigned short*)out, snew);
  k_gn<<<4096, 256, 0, stream>>>((const unsigned short*)out, rbuf, khb, vfb,
                                 gbuf, r_k, lnxw, lnxb, ywg);

  // ---- Wo projection (+x) -> x1 ----
  gemm3<EP_ADDF><<<dim3(32, 16), 256, 0, stream>>>(
      ywg, 2048, tWo, 2048, 2048, 2048, x1, nullptr, x);

  // ---- ChannelMix (two DFF halves) ----
  k_ln2_mix<<<4096, 256, 0, stream>>>(x1, ffn_shift, ln2w, ln2b, ffn_xk, xkf);
  k_transpose<<<dim3(256, 64), tb, 0, stream>>>(Wkf, tWkf, 2048, 8192);
  gemm8p<EP_RELU2><<<dim3(16, 16), 512, 0, stream>>>(
      xkf, 2048, tWkf, 2048, 2048, 4096, nullptr, kf, nullptr);
  k_transpose<<<dim3(64, 128), tb, 0, stream>>>(Wvf, tWvfh, 4096, 2048);
  gemm3<EP_ADDF><<<dim3(32, 16), 256, 0, stream>>>(
      kf, 4096, tWvfh, 4096, 4096, 2048, out, nullptr, x1);
  gemm8p<EP_RELU2><<<dim3(16, 16), 512, 0, stream>>>(
      xkf, 2048, tWkf + (size_t)4096 * 2048, 2048, 2048, 4096, nullptr, kf, nullptr);
  k_transpose<<<dim3(64, 128), tb, 0, stream>>>(Wvf + (size_t)4096 * 2048, tWvfh,
                                                4096, 2048);
  gemm3<EP_ADDF><<<dim3(32, 16), 256, 0, stream>>>(
      kf, 4096, tWvfh, 4096, 4096, 2048, out, nullptr, out);
}